// Round 1
// 777.470 us; speedup vs baseline: 1.0798x; 1.0798x over previous
//
#include <hip/hip_runtime.h>
#include <math.h>

typedef _Float16 __attribute__((ext_vector_type(8))) half8_t;
typedef _Float16 __attribute__((ext_vector_type(4))) half4_t;
typedef _Float16 __attribute__((ext_vector_type(2))) half2_t;
typedef float    __attribute__((ext_vector_type(4))) float4_t;

// ---------------------------------------------------------------------------
// Kernel 1: fused conv1(VALU) + conv2(MFMA) + maxpool4.
// Block = 16x16 output tile. conv1 -> LDS halo [18][18][32] as fp16 hi/lo,
// PS=40 pad (2-way-free banks for b128 frag reads). conv2 = implicit GEMM
// M=256,K=288,N=32 via mfma_f32_16x16x32_f16, 3-term fp16 split.
// D-frag layout makes the 4x4 pool thread-local (wave=pooled row, fr=pooled col).
// ---------------------------------------------------------------------------
__global__ __launch_bounds__(256, 2)
void k_conv12(const float* __restrict__ img, const float* __restrict__ w1,
              const float* __restrict__ b1, const _Float16* __restrict__ B2h,
              const _Float16* __restrict__ B2l, const float* __restrict__ b2,
              _Float16* __restrict__ P1h, _Float16* __restrict__ P1l)
{
    __shared__ float    simg[3 * 20 * 24];   // input halo-2, rows padded to 24
    __shared__ _Float16 C1h[324 * 40];       // conv1 halo-1 [pos=18*18][PS=40]
    __shared__ _Float16 C1l[324 * 40];

    const int t  = threadIdx.x;
    const int bt = blockIdx.x;
    const int b  = blockIdx.y;
    const int ty = bt >> 3, tx = bt & 7;
    const int oy = ty * 16, ox = tx * 16;

    for (int i = t; i < 1440; i += 256) {
        const int ci = i / 480, r = i - ci * 480;
        const int yy = r / 24, xx = r - yy * 24;
        const int gy = oy - 2 + yy, gx = ox - 2 + xx;
        float v = 0.f;
        if ((unsigned)gy < 128u && (unsigned)gx < 128u)
            v = img[((b * 3 + ci) * 128 + gy) * 128 + gx];
        simg[i] = v;
    }
    __syncthreads();

    const int wv   = __builtin_amdgcn_readfirstlane(t >> 6);
    const int lane = t & 63;

    // ---- conv1: 32 channels over 4 passes, 2 ch per wave per pass ----
    #pragma unroll 1
    for (int p = 0; p < 4; ++p) {
        const int chb = p * 8 + wv * 2;
        float w1r[2][27];
        #pragma unroll
        for (int j = 0; j < 2; ++j)
            #pragma unroll
            for (int q = 0; q < 27; ++q)
                w1r[j][q] = w1[(chb + j) * 27 + q];
        const float bb0 = b1[chb], bb1 = b1[chb + 1];

        #pragma unroll 1
        for (int it = 0; it < 2; ++it) {
            const int s = lane + it * 64;
            if (s < 90) {
                const int yy = s / 5;
                const int x0 = (s - yy * 5) * 4;
                float a0[4] = {0.f, 0.f, 0.f, 0.f};
                float a1[4] = {0.f, 0.f, 0.f, 0.f};
                #pragma unroll
                for (int ci = 0; ci < 3; ++ci)
                    #pragma unroll
                    for (int dy = 0; dy < 3; ++dy) {
                        const float* rp = &simg[(ci * 20 + yy + dy) * 24 + x0];
                        const float4 v4 = *(const float4*)rp;
                        const float2 v2 = *(const float2*)(rp + 4);
                        const float in6[6] = {v4.x, v4.y, v4.z, v4.w, v2.x, v2.y};
                        const int wb = ci * 9 + dy * 3;
                        #pragma unroll
                        for (int c = 0; c < 4; ++c) {
                            a0[c] = fmaf(w1r[0][wb],     in6[c],     a0[c]);
                            a0[c] = fmaf(w1r[0][wb + 1], in6[c + 1], a0[c]);
                            a0[c] = fmaf(w1r[0][wb + 2], in6[c + 2], a0[c]);
                            a1[c] = fmaf(w1r[1][wb],     in6[c],     a1[c]);
                            a1[c] = fmaf(w1r[1][wb + 1], in6[c + 1], a1[c]);
                            a1[c] = fmaf(w1r[1][wb + 2], in6[c + 2], a1[c]);
                        }
                    }
                const int gy   = oy - 1 + yy;
                const bool iny = (unsigned)gy < 128u;
                #pragma unroll
                for (int c = 0; c < 4; ++c) {
                    const int x = x0 + c;
                    if (x < 18) {
                        const bool ok = iny && (unsigned)(ox - 1 + x) < 128u;
                        const float v0 = ok ? fmaxf(a0[c] + bb0, 0.f) : 0.f;
                        const float v1 = ok ? fmaxf(a1[c] + bb1, 0.f) : 0.f;
                        const int pos = yy * 18 + x;
                        const _Float16 h0 = (_Float16)v0, h1 = (_Float16)v1;
                        half2_t hh = {h0, h1};
                        half2_t ll = {(_Float16)(v0 - (float)h0),
                                      (_Float16)(v1 - (float)h1)};
                        *(half2_t*)(&C1h[pos * 40 + chb]) = hh;
                        *(half2_t*)(&C1l[pos * 40 + chb]) = ll;
                    }
                }
            }
        }
    }
    __syncthreads();

    // ---- conv2: implicit-GEMM MFMA, wave wv owns my rows wv*4..wv*4+3 ----
    const int fr = lane >> 4;
    const int ml = lane & 15;

    float4_t acc[4][2];
    #pragma unroll
    for (int i = 0; i < 4; ++i)
        #pragma unroll
        for (int nt = 0; nt < 2; ++nt)
            acc[i][nt] = (float4_t){0.f, 0.f, 0.f, 0.f};

    #pragma unroll 1
    for (int tap = 0; tap < 9; ++tap) {
        const int dy = tap / 3, dx = tap - dy * 3;
        half8_t bh[2], bl[2];
        #pragma unroll
        for (int nt = 0; nt < 2; ++nt) {
            const int bo = ((tap * 2 + nt) * 64 + lane) * 8;
            bh[nt] = *(const half8_t*)(B2h + bo);
            bl[nt] = *(const half8_t*)(B2l + bo);
        }
        half8_t ah[4], al[4];
        #pragma unroll
        for (int i = 0; i < 4; ++i) {
            const int pos = (wv * 4 + i + dy) * 18 + ml + dx;
            ah[i] = *(const half8_t*)(&C1h[pos * 40 + fr * 8]);
            al[i] = *(const half8_t*)(&C1l[pos * 40 + fr * 8]);
        }
        #pragma unroll
        for (int nt = 0; nt < 2; ++nt)
            #pragma unroll
            for (int i = 0; i < 4; ++i)
                acc[i][nt] = __builtin_amdgcn_mfma_f32_16x16x32_f16(ah[i], bh[nt], acc[i][nt], 0, 0, 0);
        #pragma unroll
        for (int nt = 0; nt < 2; ++nt)
            #pragma unroll
            for (int i = 0; i < 4; ++i)
                acc[i][nt] = __builtin_amdgcn_mfma_f32_16x16x32_f16(al[i], bh[nt], acc[i][nt], 0, 0, 0);
        #pragma unroll
        for (int nt = 0; nt < 2; ++nt)
            #pragma unroll
            for (int i = 0; i < 4; ++i)
                acc[i][nt] = __builtin_amdgcn_mfma_f32_16x16x32_f16(ah[i], bl[nt], acc[i][nt], 0, 0, 0);
    }

    // ---- maxpool4 (fully thread-local) + bias + relu + hi/lo store ----
    // acc[i][nt][r] = conv2 out at my=wv*4+i, mx=fr*4+r, oc=nt*16+ml
    const int py = ty * 4 + wv;
    const int px = tx * 4 + fr;
    #pragma unroll
    for (int nt = 0; nt < 2; ++nt) {
        float m = -1e30f;
        #pragma unroll
        for (int i = 0; i < 4; ++i)
            #pragma unroll
            for (int r = 0; r < 4; ++r)
                m = fmaxf(m, acc[i][nt][r]);
        const int oc = nt * 16 + ml;
        const float v = fmaxf(m + b2[oc], 0.f);
        const _Float16 h = (_Float16)v;
        const int base = ((b * 32 + py) * 32 + px) * 32 + oc;
        P1h[base] = h;
        P1l[base] = (_Float16)(v - (float)h);
    }
}

// ---------------------------------------------------------------------------
// Weight repack: fp16 hi/lo MFMA-fragment packs for w2..w6.
// Frag order: Bh[((c*NT + ntg)*64 + lane)*8 + j], element B[k][n]:
//   n = ntg*16 + (lane&15), k = c*32 + (lane>>4)*8 + j, k = tap*CIN + ci.
// ---------------------------------------------------------------------------
__global__ void k_wrepackm(const float* __restrict__ w2, const float* __restrict__ w3,
                           const float* __restrict__ w4, const float* __restrict__ w5,
                           const float* __restrict__ w6,
                           _Float16* __restrict__ Bh, _Float16* __restrict__ Bl)
{
    int idx = blockIdx.x * 256 + threadIdx.x;
    const float* w; int CIN, COUT, off;
    if (idx < 9216)        { w = w2; CIN = 32;  COUT = 32;  off = 0; }
    else if (idx < 27648)  { idx -= 9216;   w = w3; CIN = 32;  COUT = 64;  off = 9216; }
    else if (idx < 64512)  { idx -= 27648;  w = w4; CIN = 64;  COUT = 64;  off = 27648; }
    else if (idx < 138240) { idx -= 64512;  w = w5; CIN = 64;  COUT = 128; off = 64512; }
    else if (idx < 285696) { idx -= 138240; w = w6; CIN = 128; COUT = 128; off = 138240; }
    else return;
    const int NT  = COUT / 16;
    const int c   = idx / (NT * 512);
    const int r   = idx - c * NT * 512;
    const int ntg = r >> 9;
    const int rr  = r & 511;
    const int lane = rr >> 3, j = rr & 7;
    const int k   = c * 32 + (lane >> 4) * 8 + j;
    const int tap = k / CIN, ci = k - tap * CIN;
    const int oc  = ntg * 16 + (lane & 15);
    const float v = w[(oc * CIN + ci) * 9 + tap];
    const _Float16 h = (_Float16)v;
    Bh[off + idx] = h;
    Bl[off + idx] = (_Float16)(v - (float)h);
}

// ---------------------------------------------------------------------------
// MFMA implicit-GEMM conv3x3, fp16x4 split (fp32-accurate).
// BM=128, BN=64 per block; 4 waves, wave = 2 m-tiles x 4 n-tiles.
// ---------------------------------------------------------------------------
template<int CIN, int COUT, int HW, bool OUTF32>
__global__ __launch_bounds__(256, 2)
void k_mgemm(const _Float16* __restrict__ inh, const _Float16* __restrict__ inl,
             const _Float16* __restrict__ Bh, const _Float16* __restrict__ Bl,
             const float* __restrict__ bias,
             _Float16* __restrict__ outh, _Float16* __restrict__ outl,
             float* __restrict__ outf)
{
    constexpr int NCH = CIN * 9 / 32;
    constexpr int NT  = COUT / 16;
    constexpr int LOG = (HW == 32) ? 5 : 4;
    constexpr int PS  = 40;
    __shared__ _Float16 Ash[128 * PS];
    __shared__ _Float16 Asl[128 * PS];

    const int t    = threadIdx.x;
    const int wv   = t >> 6;
    const int lane = t & 63;
    const int m0   = blockIdx.x * 128;
    const int nb   = blockIdx.y;

    int sm[2], sg[2], sb[2], sy[2], sx[2];
    #pragma unroll
    for (int j = 0; j < 2; ++j) {
        const int q = t + 256 * j;
        sm[j] = q >> 2;
        sg[j] = q & 3;
        const int m  = m0 + sm[j];
        const int yx = m & (HW * HW - 1);
        sb[j] = m >> (2 * LOG);
        sy[j] = yx >> LOG;
        sx[j] = yx & (HW - 1);
    }

    const int mt0 = wv * 2;
    const int fr  = lane >> 4;
    const int ml  = lane & 15;

    float4_t acc[2][4];
    #pragma unroll
    for (int mt = 0; mt < 2; ++mt)
        #pragma unroll
        for (int tn = 0; tn < 4; ++tn)
            acc[mt][tn] = (float4_t){0.f, 0.f, 0.f, 0.f};

    #pragma unroll 1
    for (int ch = 0; ch < NCH; ++ch) {
        const int kb  = ch * 32;
        const int tap = kb / CIN;
        const int c0  = kb - tap * CIN;
        const int dy  = tap / 3 - 1, dx = tap - (tap / 3) * 3 - 1;

        if (ch) __syncthreads();
        #pragma unroll
        for (int j = 0; j < 2; ++j) {
            const int iy = sy[j] + dy, ix = sx[j] + dx;
            half8_t vh = {0, 0, 0, 0, 0, 0, 0, 0};
            half8_t vl = {0, 0, 0, 0, 0, 0, 0, 0};
            if ((unsigned)iy < (unsigned)HW && (unsigned)ix < (unsigned)HW) {
                const int o = ((sb[j] * HW + iy) * HW + ix) * CIN + c0 + sg[j] * 8;
                vh = *(const half8_t*)(inh + o);
                vl = *(const half8_t*)(inl + o);
            }
            *(half8_t*)(&Ash[sm[j] * PS + sg[j] * 8]) = vh;
            *(half8_t*)(&Asl[sm[j] * PS + sg[j] * 8]) = vl;
        }
        __syncthreads();

        half8_t ah[2], al[2];
        #pragma unroll
        for (int mt = 0; mt < 2; ++mt) {
            const int mr = (mt0 + mt) * 16 + ml;
            ah[mt] = *(const half8_t*)(&Ash[mr * PS + fr * 8]);
            al[mt] = *(const half8_t*)(&Asl[mr * PS + fr * 8]);
        }
        half8_t bh[4], bl[4];
        #pragma unroll
        for (int tn = 0; tn < 4; ++tn) {
            const int bo = ((ch * NT + nb * 4 + tn) * 64 + lane) * 8;
            bh[tn] = *(const half8_t*)(Bh + bo);
            bl[tn] = *(const half8_t*)(Bl + bo);
        }
        #pragma unroll
        for (int tn = 0; tn < 4; ++tn)
            #pragma unroll
            for (int mt = 0; mt < 2; ++mt)
                acc[mt][tn] = __builtin_amdgcn_mfma_f32_16x16x32_f16(ah[mt], bh[tn], acc[mt][tn], 0, 0, 0);
        #pragma unroll
        for (int tn = 0; tn < 4; ++tn)
            #pragma unroll
            for (int mt = 0; mt < 2; ++mt)
                acc[mt][tn] = __builtin_amdgcn_mfma_f32_16x16x32_f16(al[mt], bh[tn], acc[mt][tn], 0, 0, 0);
        #pragma unroll
        for (int tn = 0; tn < 4; ++tn)
            #pragma unroll
            for (int mt = 0; mt < 2; ++mt)
                acc[mt][tn] = __builtin_amdgcn_mfma_f32_16x16x32_f16(ah[mt], bl[tn], acc[mt][tn], 0, 0, 0);
        #pragma unroll
        for (int tn = 0; tn < 4; ++tn)
            #pragma unroll
            for (int mt = 0; mt < 2; ++mt)
                acc[mt][tn] = __builtin_amdgcn_mfma_f32_16x16x32_f16(al[mt], bl[tn], acc[mt][tn], 0, 0, 0);
    }

    // epilogue: C/D frag col=lane&15, row=(lane>>4)*4+reg  [guide m89/m91]
    #pragma unroll
    for (int mt = 0; mt < 2; ++mt)
        #pragma unroll
        for (int tn = 0; tn < 4; ++tn) {
            const int oc = nb * 64 + tn * 16 + ml;
            const float bv = bias[oc];
            #pragma unroll
            for (int r = 0; r < 4; ++r) {
                const int m = m0 + (mt0 + mt) * 16 + fr * 4 + r;
                const float v = fmaxf(acc[mt][tn][r] + bv, 0.f);
                if (OUTF32) {
                    outf[m * COUT + oc] = v;
                } else {
                    const _Float16 h = (_Float16)v;
                    outh[m * COUT + oc] = h;
                    outl[m * COUT + oc] = (_Float16)(v - (float)h);
                }
            }
        }
}

// ---------------------------------------------------------------------------
// 2x2 maxpool on dual fp16 planes, NHWC [128][32][32][64] -> [128][16][16][64]
// ---------------------------------------------------------------------------
__global__ __launch_bounds__(256)
void k_pool2h(const _Float16* __restrict__ inh, const _Float16* __restrict__ inl,
              _Float16* __restrict__ outh, _Float16* __restrict__ outl)
{
    const int g = blockIdx.x * 256 + threadIdx.x;
    const int c4 = g & 15, xo = (g >> 4) & 15, yo = (g >> 8) & 15, b = g >> 12;
    const int base = ((b * 32 + yo * 2) * 32 + xo * 2) * 64 + c4 * 4;
    const int offs[4] = {0, 64, 2048, 2112};
    float mx[4] = {-1e30f, -1e30f, -1e30f, -1e30f};
    #pragma unroll
    for (int cnd = 0; cnd < 4; ++cnd) {
        const half4_t h = *(const half4_t*)(inh + base + offs[cnd]);
        const half4_t l = *(const half4_t*)(inl + base + offs[cnd]);
        #pragma unroll
        for (int e = 0; e < 4; ++e)
            mx[e] = fmaxf(mx[e], (float)h[e] + (float)l[e]);
    }
    half4_t oh, ol;
    #pragma unroll
    for (int e = 0; e < 4; ++e) {
        const _Float16 h = (_Float16)mx[e];
        oh[e] = h;
        ol[e] = (_Float16)(mx[e] - (float)h);
    }
    const int ob = ((b * 16 + yo) * 16 + xo) * 64 + c4 * 4;
    *(half4_t*)(outh + ob) = oh;
    *(half4_t*)(outl + ob) = ol;
}

// ---------------------------------------------------------------------------
// Split-K FC partial (fp32): A[128 x K] @ B[K x 512] -> part[ky][128][512]
// ---------------------------------------------------------------------------
template<int LDA, int KCHUNK, int TN, bool PERM>
__global__ __launch_bounds__(256, 2)
void k_fc_partial(const float* __restrict__ A, const float* __restrict__ Bw,
                  float* __restrict__ part)
{
    constexpr int BN = 16 * TN;
    constexpr int SA = 140;
    constexpr int SB = (BN == 128) ? 140 : 68;
    __shared__ __align__(16) float As[32 * SA];
    __shared__ __align__(16) float Bs[32 * SB];
    const int t  = threadIdx.x;
    const int tm = t >> 4, tn = t & 15;
    const int n0 = blockIdx.x * BN;
    const int k0 = blockIdx.y * KCHUNK;

    float acc[8][TN];
    #pragma unroll
    for (int r = 0; r < 8; ++r)
        #pragma unroll
        for (int c = 0; c < TN; ++c) acc[r][c] = 0.f;

    #pragma unroll 1
    for (int ks = 0; ks < KCHUNK / 32; ++ks) {
        if (ks) __syncthreads();
        const int kb = k0 + ks * 32;
        for (int i = t; i < 4096; i += 256) {
            const int m = i >> 5, kk = i & 31;
            As[kk * SA + m + ((m >> 5) << 2)] = A[m * LDA + kb + kk];
        }
        for (int i = t; i < 32 * BN; i += 256) {
            const int kk = i / BN, n = i - kk * BN;
            const int krow = kb + kk;
            const int kref = PERM ? ((krow & 127) * 256 + (krow >> 7)) : krow;
            Bs[kk * SB + n + ((n >> 5) << 2)] = Bw[kref * 512 + n0 + n];
        }
        __syncthreads();
        #pragma unroll 2
        for (int kk = 0; kk < 32; ++kk) {
            const float* ap = &As[kk * SA + tm * 8 + ((tm >> 2) << 2)];
            const float* bp = &Bs[kk * SB + tn * TN + (((tn * TN) >> 5) << 2)];
            float a[8], bb[TN];
            #pragma unroll
            for (int q = 0; q < 8; q += 4) {
                const float4 v = *(const float4*)(ap + q);
                a[q] = v.x; a[q + 1] = v.y; a[q + 2] = v.z; a[q + 3] = v.w;
            }
            #pragma unroll
            for (int q = 0; q < TN; q += 4) {
                const float4 v = *(const float4*)(bp + q);
                bb[q] = v.x; bb[q + 1] = v.y; bb[q + 2] = v.z; bb[q + 3] = v.w;
            }
            #pragma unroll
            for (int r = 0; r < 8; ++r)
                #pragma unroll
                for (int c = 0; c < TN; ++c)
                    acc[r][c] = fmaf(a[r], bb[c], acc[r][c]);
        }
    }

    const long pb = (long)blockIdx.y * 65536;
    #pragma unroll
    for (int r = 0; r < 8; ++r)
        #pragma unroll
        for (int c = 0; c < TN; ++c)
            part[pb + (tm * 8 + r) * 512 + n0 + tn * TN + c] = acc[r][c];
}

template<int NS>
__global__ __launch_bounds__(256)
void k_fc_reduce(const float* __restrict__ part, const float* __restrict__ bias,
                 float* __restrict__ H)
{
    const int f = (blockIdx.x * 256 + threadIdx.x) * 4;
    const int m = f >> 9, n = f & 511;
    float s0 = 0.f, s1 = 0.f, s2 = 0.f, s3 = 0.f;
    #pragma unroll 4
    for (int q = 0; q < NS; ++q) {
        const float* p = &part[(q * 128 + m) * 512 + n];
        s0 += p[0]; s1 += p[1]; s2 += p[2]; s3 += p[3];
    }
    H[f]     = fmaxf(s0 + bias[n],     0.f);
    H[f + 1] = fmaxf(s1 + bias[n + 1], 0.f);
    H[f + 2] = fmaxf(s2 + bias[n + 2], 0.f);
    H[f + 3] = fmaxf(s3 + bias[n + 3], 0.f);
}

// ---------------------------------------------------------------------------
// Final: FC3 + sampling + patch gather
// ---------------------------------------------------------------------------
__device__ __forceinline__ float softplusf(float x) {
    return (x > 20.f) ? x : log1pf(expf(x));
}
__device__ __forceinline__ float sigmoidf_(float x) {
    return 1.f / (1.f + expf(-x));
}

__global__ __launch_bounds__(256)
void k_final(const float* __restrict__ H2, const float* __restrict__ wl3,
             const float* __restrict__ bl3, const float* __restrict__ noise,
             const float* __restrict__ img, float* __restrict__ outp)
{
    __shared__ float h2[512];
    __shared__ float red[144];
    __shared__ float prep[36];
    __shared__ int ptsh[12], ptsw[12];
    const int b = blockIdx.x, t = threadIdx.x;

    h2[t]       = H2[b * 512 + t];
    h2[t + 256] = H2[b * 512 + 256 + t];
    __syncthreads();

    if (t < 144) {
        const int n = t >> 2, q = t & 3;
        float s = 0.f;
        for (int k = q * 128; k < q * 128 + 128; ++k)
            s = fmaf(h2[k], wl3[k * 36 + n], s);
        red[t] = s;
    }
    __syncthreads();
    if (t < 36)
        prep[t] = red[t * 4] + red[t * 4 + 1] + red[t * 4 + 2] + red[t * 4 + 3] + bl3[t];
    __syncthreads();

    if (t < 12) {
        const float m0 = prep[t * 3], m1 = prep[t * 3 + 1], sv = prep[t * 3 + 2];
        const float sig = softplusf(sv + 2.0f) * 128.f + 1e-7f;
        const float n0 = noise[(b * 12 + t) * 2], n1 = noise[(b * 12 + t) * 2 + 1];
        const float sa0 = m0 + sig * n0;
        const float sa1 = m1 + sig * n1;
        int p0 = (int)rintf(sigmoidf_(sa0) * 111.f);
        int p1 = (int)rintf(sigmoidf_(sa1) * 111.f);
        p0 = min(max(p0, 0), 111);
        p1 = min(max(p1, 0), 111);
        const int RM = 1179648;
        outp[RM        + (b * 12 + t) * 2 + 0] = m0;
        outp[RM        + (b * 12 + t) * 2 + 1] = m1;
        outp[RM + 3072 + (b * 12 + t) * 2 + 0] = sig;
        outp[RM + 3072 + (b * 12 + t) * 2 + 1] = sig;
        outp[RM + 6144 + (b * 12 + t) * 2 + 0] = sa0;
        outp[RM + 6144 + (b * 12 + t) * 2 + 1] = sa1;
        ptsh[t] = p0;
        ptsw[t] = p1;
    }
    __syncthreads();

    for (int i = t; i < 9216; i += 256) {
        const int g  = i / 768, r = i - g * 768;
        const int c  = r >> 8, r2 = r & 255;
        const int y  = r2 >> 4, x = r2 & 15;
        outp[b * 9216 + i] = img[((b * 3 + c) * 128 + ptsh[g] + y) * 128 + (ptsw[g] + x)];
    }
}

// ---------------------------------------------------------------------------
extern "C" void kernel_launch(void* const* d_in, const int* in_sizes, int n_in,
                              void* d_out, int out_size, void* d_ws, size_t ws_size,
                              hipStream_t stream)
{
    const float* img  = (const float*)d_in[0];
    const float* nois = (const float*)d_in[1];
    const float* w1 = (const float*)d_in[2];  const float* b1 = (const float*)d_in[3];
    const float* w2 = (const float*)d_in[4];  const float* b2 = (const float*)d_in[5];
    const float* w3 = (const float*)d_in[6];  const float* b3 = (const float*)d_in[7];
    const float* w4 = (const float*)d_in[8];  const float* b4 = (const float*)d_in[9];
    const float* w5 = (const float*)d_in[10]; const float* b5 = (const float*)d_in[11];
    const float* w6 = (const float*)d_in[12]; const float* b6 = (const float*)d_in[13];
    const float* wl1 = (const float*)d_in[14]; const float* bl1 = (const float*)d_in[15];
    const float* wl2 = (const float*)d_in[16]; const float* bl2 = (const float*)d_in[17];
    const float* wl3 = (const float*)d_in[18]; const float* bl3 = (const float*)d_in[19];
    float* out = (float*)d_out;
    float* ws  = (float*)d_ws;

    // workspace (float units). Activation regions span [0 .. 20971520).
    // Weight packs live ABOVE all activations.
    _Float16* P1h = (_Float16*)(ws);               // [128*32*32*32] halves
    _Float16* P1l = (_Float16*)(ws + 2097152);
    _Float16* A3h = (_Float16*)(ws + 4194304);     // [128*32*32*64]
    _Float16* A3l = (_Float16*)(ws + 8388608);
    _Float16* A4h = (_Float16*)(ws + 12582912);    // [128*32*32*64]
    _Float16* A4l = (_Float16*)(ws + 16777216);    // ..20971520
    _Float16* P2h = (_Float16*)(ws);               // [128*16*16*64] (P1 dead)
    _Float16* P2l = (_Float16*)(ws + 1048576);
    _Float16* A5h = (_Float16*)(ws + 4194304);     // [128*16*16*128] (A3 dead)
    _Float16* A5l = (_Float16*)(ws + 6291456);
    float* A6  = ws + 8388608;                     // [128*16*16*128] fp32 (A3 dead)
    float* FP1 = ws + 12582912;                    // [64][128][512] (A4h dead)
    float* H1  = ws + 16777216;                    // [128][512]     (A4l dead)
    float* FP2 = ws + 16842752;                    // [16][128][512]
    float* H2  = ws + 17891328;                    // [128][512]
    _Float16* Bh = (_Float16*)(ws + 20971520);     // 285696 halves (w2..w6)
    _Float16* Bl = (_Float16*)(ws + 21114368);     // ends 21257216 fl = 85 MB

    hipLaunchKernelGGL(k_wrepackm, dim3(1116), dim3(256), 0, stream,
                       w2, w3, w4, w5, w6, Bh, Bl);

    // conv1+conv2+pool4: grid = 8x8 tiles x 128 batch
    hipLaunchKernelGGL(k_conv12, dim3(64, 128), dim3(256), 0, stream,
                       img, w1, b1, Bh + 0, Bl + 0, b2, P1h, P1l);
    // conv3: M=131072, K=288, COUT=64
    hipLaunchKernelGGL((k_mgemm<32, 64, 32, false>), dim3(1024, 1), dim3(256), 0, stream,
                       P1h, P1l, Bh + 9216, Bl + 9216, b3, A3h, A3l, nullptr);
    // conv4: K=576
    hipLaunchKernelGGL((k_mgemm<64, 64, 32, false>), dim3(1024, 1), dim3(256), 0, stream,
                       A3h, A3l, Bh + 27648, Bl + 27648, b4, A4h, A4l, nullptr);
    hipLaunchKernelGGL(k_pool2h, dim3(2048), dim3(256), 0, stream, A4h, A4l, P2h, P2l);
    // conv5: M=32768, K=576, COUT=128
    hipLaunchKernelGGL((k_mgemm<64, 128, 16, false>), dim3(256, 2), dim3(256), 0, stream,
                       P2h, P2l, Bh + 64512, Bl + 64512, b5, A5h, A5l, nullptr);
    // conv6: K=1152, fp32 out for FC1
    hipLaunchKernelGGL((k_mgemm<128, 128, 16, true>), dim3(256, 2), dim3(256), 0, stream,
                       A5h, A5l, Bh + 138240, Bl + 138240, b6, nullptr, nullptr, A6);
    hipLaunchKernelGGL((k_fc_partial<32768, 512, 4, true>), dim3(8, 64), dim3(256), 0, stream,
                       A6, wl1, FP1);
    hipLaunchKernelGGL(k_fc_reduce<64>, dim3(64), dim3(256), 0, stream, FP1, bl1, H1);
    hipLaunchKernelGGL((k_fc_partial<512, 32, 4, false>), dim3(8, 16), dim3(256), 0, stream,
                       H1, wl2, FP2);
    hipLaunchKernelGGL(k_fc_reduce<16>, dim3(64), dim3(256), 0, stream, FP2, bl2, H2);
    hipLaunchKernelGGL(k_final, dim3(128), dim3(256), 0, stream,
                       H2, wl3, bl3, nois, img, out);
}

// Round 2
// 757.005 us; speedup vs baseline: 1.1090x; 1.0270x over previous
//
#include <hip/hip_runtime.h>
#include <math.h>

typedef _Float16 __attribute__((ext_vector_type(8))) half8_t;
typedef _Float16 __attribute__((ext_vector_type(4))) half4_t;
typedef _Float16 __attribute__((ext_vector_type(2))) half2_t;
typedef float    __attribute__((ext_vector_type(4))) float4_t;

// ---------------------------------------------------------------------------
// Kernel 1: fused conv1(VALU) + conv2(MFMA) + maxpool4.
// Block = 16x16 output tile. conv1 -> LDS halo as fp16 hi/lo in
// [slot=ch-oct][pos=18*18][j=ch&7] layout (16B per (slot,pos)):
//   * conv2 A-frag read = b128 at (fr*POSP+pos)*16, lane stride 1 in pos
//     -> canonical conflict-free pattern.
//   * writes XOR-swizzled with ((pos>>3)&7)<<3 (half units) both sides,
//     spreading conv1's stride-4-pos writes off banks {0,8,16,24}.
// LDS 47.4 KB -> 3 blocks/CU.
// conv2 = implicit GEMM M=256,K=288,N=32 via mfma_f32_16x16x32_f16,
// 3-term fp16 hi/lo split. D-frag layout makes the 4x4 pool thread-local.
// ---------------------------------------------------------------------------
#define POSP 325

__device__ __forceinline__ int c1idx(int slot, int pos) {
    return ((slot * POSP + pos) * 8) ^ (((pos >> 3) & 7) << 3);
}

__global__ __launch_bounds__(256, 3)
void k_conv12(const float* __restrict__ img, const float* __restrict__ w1,
              const float* __restrict__ b1, const _Float16* __restrict__ B2h,
              const _Float16* __restrict__ B2l, const float* __restrict__ b2,
              _Float16* __restrict__ P1h, _Float16* __restrict__ P1l)
{
    __shared__ float simg[3 * 20 * 24];                      // input halo-2
    __shared__ __align__(16) _Float16 C1h[4 * POSP * 8];     // [slot][pos][j]
    __shared__ __align__(16) _Float16 C1l[4 * POSP * 8];

    const int t  = threadIdx.x;
    const int bt = blockIdx.x;
    const int b  = blockIdx.y;
    const int ty = bt >> 3, tx = bt & 7;
    const int oy = ty * 16, ox = tx * 16;

    for (int i = t; i < 1440; i += 256) {
        const int ci = i / 480, r = i - ci * 480;
        const int yy = r / 24, xx = r - yy * 24;
        const int gy = oy - 2 + yy, gx = ox - 2 + xx;
        float v = 0.f;
        if ((unsigned)gy < 128u && (unsigned)gx < 128u)
            v = img[((b * 3 + ci) * 128 + gy) * 128 + gx];
        simg[i] = v;
    }
    __syncthreads();

    const int wv   = __builtin_amdgcn_readfirstlane(t >> 6);
    const int lane = t & 63;

    // ---- conv1: 32 channels over 4 passes (slot=p), 2 ch per wave (j=wv*2) --
    #pragma unroll 1
    for (int p = 0; p < 4; ++p) {
        const int chb = p * 8 + wv * 2;
        float w1r[2][27];
        #pragma unroll
        for (int j = 0; j < 2; ++j)
            #pragma unroll
            for (int q = 0; q < 27; ++q)
                w1r[j][q] = w1[(chb + j) * 27 + q];
        const float bb0 = b1[chb], bb1 = b1[chb + 1];

        #pragma unroll 1
        for (int it = 0; it < 2; ++it) {
            const int s = lane + it * 64;
            if (s < 90) {
                const int yy = s / 5;
                const int x0 = (s - yy * 5) * 4;
                float a0[4] = {0.f, 0.f, 0.f, 0.f};
                float a1[4] = {0.f, 0.f, 0.f, 0.f};
                #pragma unroll
                for (int ci = 0; ci < 3; ++ci)
                    #pragma unroll
                    for (int dy = 0; dy < 3; ++dy) {
                        const float* rp = &simg[(ci * 20 + yy + dy) * 24 + x0];
                        const float4 v4 = *(const float4*)rp;
                        const float2 v2 = *(const float2*)(rp + 4);
                        const float in6[6] = {v4.x, v4.y, v4.z, v4.w, v2.x, v2.y};
                        const int wb = ci * 9 + dy * 3;
                        #pragma unroll
                        for (int c = 0; c < 4; ++c) {
                            a0[c] = fmaf(w1r[0][wb],     in6[c],     a0[c]);
                            a0[c] = fmaf(w1r[0][wb + 1], in6[c + 1], a0[c]);
                            a0[c] = fmaf(w1r[0][wb + 2], in6[c + 2], a0[c]);
                            a1[c] = fmaf(w1r[1][wb],     in6[c],     a1[c]);
                            a1[c] = fmaf(w1r[1][wb + 1], in6[c + 1], a1[c]);
                            a1[c] = fmaf(w1r[1][wb + 2], in6[c + 2], a1[c]);
                        }
                    }
                const int gy   = oy - 1 + yy;
                const bool iny = (unsigned)gy < 128u;
                #pragma unroll
                for (int c = 0; c < 4; ++c) {
                    const int x = x0 + c;
                    if (x < 18) {
                        const bool ok = iny && (unsigned)(ox - 1 + x) < 128u;
                        const float v0 = ok ? fmaxf(a0[c] + bb0, 0.f) : 0.f;
                        const float v1 = ok ? fmaxf(a1[c] + bb1, 0.f) : 0.f;
                        const int pos = yy * 18 + x;
                        const int wi  = c1idx(p, pos) + wv * 2;
                        const _Float16 h0 = (_Float16)v0, h1 = (_Float16)v1;
                        half2_t hh = {h0, h1};
                        half2_t ll = {(_Float16)(v0 - (float)h0),
                                      (_Float16)(v1 - (float)h1)};
                        *(half2_t*)(&C1h[wi]) = hh;
                        *(half2_t*)(&C1l[wi]) = ll;
                    }
                }
            }
        }
    }
    __syncthreads();

    // ---- conv2: implicit-GEMM MFMA, wave wv owns my rows wv*4..wv*4+3 ----
    const int fr = lane >> 4;
    const int ml = lane & 15;

    float4_t acc[4][2];
    #pragma unroll
    for (int i = 0; i < 4; ++i)
        #pragma unroll
        for (int nt = 0; nt < 2; ++nt)
            acc[i][nt] = (float4_t){0.f, 0.f, 0.f, 0.f};

    #pragma unroll 1
    for (int tap = 0; tap < 9; ++tap) {
        const int dy = tap / 3, dx = tap - dy * 3;
        half8_t bh[2], bl[2];
        #pragma unroll
        for (int nt = 0; nt < 2; ++nt) {
            const int bo = ((tap * 2 + nt) * 64 + lane) * 8;
            bh[nt] = *(const half8_t*)(B2h + bo);
            bl[nt] = *(const half8_t*)(B2l + bo);
        }
        half8_t ah[4], al[4];
        #pragma unroll
        for (int i = 0; i < 4; ++i) {
            const int pos = (wv * 4 + i + dy) * 18 + ml + dx;
            const int ri  = c1idx(fr, pos);
            ah[i] = *(const half8_t*)(&C1h[ri]);
            al[i] = *(const half8_t*)(&C1l[ri]);
        }
        #pragma unroll
        for (int nt = 0; nt < 2; ++nt)
            #pragma unroll
            for (int i = 0; i < 4; ++i)
                acc[i][nt] = __builtin_amdgcn_mfma_f32_16x16x32_f16(ah[i], bh[nt], acc[i][nt], 0, 0, 0);
        #pragma unroll
        for (int nt = 0; nt < 2; ++nt)
            #pragma unroll
            for (int i = 0; i < 4; ++i)
                acc[i][nt] = __builtin_amdgcn_mfma_f32_16x16x32_f16(al[i], bh[nt], acc[i][nt], 0, 0, 0);
        #pragma unroll
        for (int nt = 0; nt < 2; ++nt)
            #pragma unroll
            for (int i = 0; i < 4; ++i)
                acc[i][nt] = __builtin_amdgcn_mfma_f32_16x16x32_f16(ah[i], bl[nt], acc[i][nt], 0, 0, 0);
    }

    // ---- maxpool4 (fully thread-local) + bias + relu + hi/lo store ----
    // acc[i][nt][r] = conv2 out at my=wv*4+i, mx=fr*4+r, oc=nt*16+ml
    const int py = ty * 4 + wv;
    const int px = tx * 4 + fr;
    #pragma unroll
    for (int nt = 0; nt < 2; ++nt) {
        float m = -1e30f;
        #pragma unroll
        for (int i = 0; i < 4; ++i)
            #pragma unroll
            for (int r = 0; r < 4; ++r)
                m = fmaxf(m, acc[i][nt][r]);
        const int oc = nt * 16 + ml;
        const float v = fmaxf(m + b2[oc], 0.f);
        const _Float16 h = (_Float16)v;
        const int base = ((b * 32 + py) * 32 + px) * 32 + oc;
        P1h[base] = h;
        P1l[base] = (_Float16)(v - (float)h);
    }
}

// ---------------------------------------------------------------------------
// Weight repack: fp16 hi/lo MFMA-fragment packs for w2..w6.
// Frag order: Bh[((c*NT + ntg)*64 + lane)*8 + j], element B[k][n]:
//   n = ntg*16 + (lane&15), k = c*32 + (lane>>4)*8 + j, k = tap*CIN + ci.
// ---------------------------------------------------------------------------
__global__ void k_wrepackm(const float* __restrict__ w2, const float* __restrict__ w3,
                           const float* __restrict__ w4, const float* __restrict__ w5,
                           const float* __restrict__ w6,
                           _Float16* __restrict__ Bh, _Float16* __restrict__ Bl)
{
    int idx = blockIdx.x * 256 + threadIdx.x;
    const float* w; int CIN, COUT, off;
    if (idx < 9216)        { w = w2; CIN = 32;  COUT = 32;  off = 0; }
    else if (idx < 27648)  { idx -= 9216;   w = w3; CIN = 32;  COUT = 64;  off = 9216; }
    else if (idx < 64512)  { idx -= 27648;  w = w4; CIN = 64;  COUT = 64;  off = 27648; }
    else if (idx < 138240) { idx -= 64512;  w = w5; CIN = 64;  COUT = 128; off = 64512; }
    else if (idx < 285696) { idx -= 138240; w = w6; CIN = 128; COUT = 128; off = 138240; }
    else return;
    const int NT  = COUT / 16;
    const int c   = idx / (NT * 512);
    const int r   = idx - c * NT * 512;
    const int ntg = r >> 9;
    const int rr  = r & 511;
    const int lane = rr >> 3, j = rr & 7;
    const int k   = c * 32 + (lane >> 4) * 8 + j;
    const int tap = k / CIN, ci = k - tap * CIN;
    const int oc  = ntg * 16 + (lane & 15);
    const float v = w[(oc * CIN + ci) * 9 + tap];
    const _Float16 h = (_Float16)v;
    Bh[off + idx] = h;
    Bl[off + idx] = (_Float16)(v - (float)h);
}

// ---------------------------------------------------------------------------
// MFMA implicit-GEMM conv3x3, fp16x3 split (fp32-class: ll term <= 2^-22 rel).
// BM=128, BN=64 per block; 4 waves, wave = 2 m-tiles x 4 n-tiles.
// ---------------------------------------------------------------------------
template<int CIN, int COUT, int HW, bool OUTF32>
__global__ __launch_bounds__(256, 2)
void k_mgemm(const _Float16* __restrict__ inh, const _Float16* __restrict__ inl,
             const _Float16* __restrict__ Bh, const _Float16* __restrict__ Bl,
             const float* __restrict__ bias,
             _Float16* __restrict__ outh, _Float16* __restrict__ outl,
             float* __restrict__ outf)
{
    constexpr int NCH = CIN * 9 / 32;
    constexpr int NT  = COUT / 16;
    constexpr int LOG = (HW == 32) ? 5 : 4;
    constexpr int PS  = 40;
    __shared__ _Float16 Ash[128 * PS];
    __shared__ _Float16 Asl[128 * PS];

    const int t    = threadIdx.x;
    const int wv   = t >> 6;
    const int lane = t & 63;
    const int m0   = blockIdx.x * 128;
    const int nb   = blockIdx.y;

    int sm[2], sg[2], sb[2], sy[2], sx[2];
    #pragma unroll
    for (int j = 0; j < 2; ++j) {
        const int q = t + 256 * j;
        sm[j] = q >> 2;
        sg[j] = q & 3;
        const int m  = m0 + sm[j];
        const int yx = m & (HW * HW - 1);
        sb[j] = m >> (2 * LOG);
        sy[j] = yx >> LOG;
        sx[j] = yx & (HW - 1);
    }

    const int mt0 = wv * 2;
    const int fr  = lane >> 4;
    const int ml  = lane & 15;

    float4_t acc[2][4];
    #pragma unroll
    for (int mt = 0; mt < 2; ++mt)
        #pragma unroll
        for (int tn = 0; tn < 4; ++tn)
            acc[mt][tn] = (float4_t){0.f, 0.f, 0.f, 0.f};

    #pragma unroll 1
    for (int ch = 0; ch < NCH; ++ch) {
        const int kb  = ch * 32;
        const int tap = kb / CIN;
        const int c0  = kb - tap * CIN;
        const int dy  = tap / 3 - 1, dx = tap - (tap / 3) * 3 - 1;

        if (ch) __syncthreads();
        #pragma unroll
        for (int j = 0; j < 2; ++j) {
            const int iy = sy[j] + dy, ix = sx[j] + dx;
            half8_t vh = {0, 0, 0, 0, 0, 0, 0, 0};
            half8_t vl = {0, 0, 0, 0, 0, 0, 0, 0};
            if ((unsigned)iy < (unsigned)HW && (unsigned)ix < (unsigned)HW) {
                const int o = ((sb[j] * HW + iy) * HW + ix) * CIN + c0 + sg[j] * 8;
                vh = *(const half8_t*)(inh + o);
                vl = *(const half8_t*)(inl + o);
            }
            *(half8_t*)(&Ash[sm[j] * PS + sg[j] * 8]) = vh;
            *(half8_t*)(&Asl[sm[j] * PS + sg[j] * 8]) = vl;
        }
        __syncthreads();

        half8_t ah[2], al[2];
        #pragma unroll
        for (int mt = 0; mt < 2; ++mt) {
            const int mr = (mt0 + mt) * 16 + ml;
            ah[mt] = *(const half8_t*)(&Ash[mr * PS + fr * 8]);
            al[mt] = *(const half8_t*)(&Asl[mr * PS + fr * 8]);
        }
        half8_t bh[4], bl[4];
        #pragma unroll
        for (int tn = 0; tn < 4; ++tn) {
            const int bo = ((ch * NT + nb * 4 + tn) * 64 + lane) * 8;
            bh[tn] = *(const half8_t*)(Bh + bo);
            bl[tn] = *(const half8_t*)(Bl + bo);
        }
        #pragma unroll
        for (int tn = 0; tn < 4; ++tn)
            #pragma unroll
            for (int mt = 0; mt < 2; ++mt)
                acc[mt][tn] = __builtin_amdgcn_mfma_f32_16x16x32_f16(ah[mt], bh[tn], acc[mt][tn], 0, 0, 0);
        #pragma unroll
        for (int tn = 0; tn < 4; ++tn)
            #pragma unroll
            for (int mt = 0; mt < 2; ++mt)
                acc[mt][tn] = __builtin_amdgcn_mfma_f32_16x16x32_f16(al[mt], bh[tn], acc[mt][tn], 0, 0, 0);
        #pragma unroll
        for (int tn = 0; tn < 4; ++tn)
            #pragma unroll
            for (int mt = 0; mt < 2; ++mt)
                acc[mt][tn] = __builtin_amdgcn_mfma_f32_16x16x32_f16(ah[mt], bl[tn], acc[mt][tn], 0, 0, 0);
        // (al,bl) term dropped: <= 2^-22 relative contribution.
    }

    // epilogue: C/D frag col=lane&15, row=(lane>>4)*4+reg  [guide m89/m91]
    #pragma unroll
    for (int mt = 0; mt < 2; ++mt)
        #pragma unroll
        for (int tn = 0; tn < 4; ++tn) {
            const int oc = nb * 64 + tn * 16 + ml;
            const float bv = bias[oc];
            #pragma unroll
            for (int r = 0; r < 4; ++r) {
                const int m = m0 + (mt0 + mt) * 16 + fr * 4 + r;
                const float v = fmaxf(acc[mt][tn][r] + bv, 0.f);
                if (OUTF32) {
                    outf[m * COUT + oc] = v;
                } else {
                    const _Float16 h = (_Float16)v;
                    outh[m * COUT + oc] = h;
                    outl[m * COUT + oc] = (_Float16)(v - (float)h);
                }
            }
        }
}

// ---------------------------------------------------------------------------
// 2x2 maxpool on dual fp16 planes, NHWC [128][32][32][64] -> [128][16][16][64]
// ---------------------------------------------------------------------------
__global__ __launch_bounds__(256)
void k_pool2h(const _Float16* __restrict__ inh, const _Float16* __restrict__ inl,
              _Float16* __restrict__ outh, _Float16* __restrict__ outl)
{
    const int g = blockIdx.x * 256 + threadIdx.x;
    const int c4 = g & 15, xo = (g >> 4) & 15, yo = (g >> 8) & 15, b = g >> 12;
    const int base = ((b * 32 + yo * 2) * 32 + xo * 2) * 64 + c4 * 4;
    const int offs[4] = {0, 64, 2048, 2112};
    float mx[4] = {-1e30f, -1e30f, -1e30f, -1e30f};
    #pragma unroll
    for (int cnd = 0; cnd < 4; ++cnd) {
        const half4_t h = *(const half4_t*)(inh + base + offs[cnd]);
        const half4_t l = *(const half4_t*)(inl + base + offs[cnd]);
        #pragma unroll
        for (int e = 0; e < 4; ++e)
            mx[e] = fmaxf(mx[e], (float)h[e] + (float)l[e]);
    }
    half4_t oh, ol;
    #pragma unroll
    for (int e = 0; e < 4; ++e) {
        const _Float16 h = (_Float16)mx[e];
        oh[e] = h;
        ol[e] = (_Float16)(mx[e] - (float)h);
    }
    const int ob = ((b * 16 + yo) * 16 + xo) * 64 + c4 * 4;
    *(half4_t*)(outh + ob) = oh;
    *(half4_t*)(outl + ob) = ol;
}

// ---------------------------------------------------------------------------
// Split-K FC partial (fp32): A[128 x K] @ B[K x 512] -> part[ky][128][512]
// ---------------------------------------------------------------------------
template<int LDA, int KCHUNK, int TN, bool PERM>
__global__ __launch_bounds__(256, 2)
void k_fc_partial(const float* __restrict__ A, const float* __restrict__ Bw,
                  float* __restrict__ part)
{
    constexpr int BN = 16 * TN;
    constexpr int SA = 140;
    constexpr int SB = (BN == 128) ? 140 : 68;
    __shared__ __align__(16) float As[32 * SA];
    __shared__ __align__(16) float Bs[32 * SB];
    const int t  = threadIdx.x;
    const int tm = t >> 4, tn = t & 15;
    const int n0 = blockIdx.x * BN;
    const int k0 = blockIdx.y * KCHUNK;

    float acc[8][TN];
    #pragma unroll
    for (int r = 0; r < 8; ++r)
        #pragma unroll
        for (int c = 0; c < TN; ++c) acc[r][c] = 0.f;

    #pragma unroll 1
    for (int ks = 0; ks < KCHUNK / 32; ++ks) {
        if (ks) __syncthreads();
        const int kb = k0 + ks * 32;
        for (int i = t; i < 4096; i += 256) {
            const int m = i >> 5, kk = i & 31;
            As[kk * SA + m + ((m >> 5) << 2)] = A[m * LDA + kb + kk];
        }
        for (int i = t; i < 32 * BN; i += 256) {
            const int kk = i / BN, n = i - kk * BN;
            const int krow = kb + kk;
            const int kref = PERM ? ((krow & 127) * 256 + (krow >> 7)) : krow;
            Bs[kk * SB + n + ((n >> 5) << 2)] = Bw[kref * 512 + n0 + n];
        }
        __syncthreads();
        #pragma unroll 2
        for (int kk = 0; kk < 32; ++kk) {
            const float* ap = &As[kk * SA + tm * 8 + ((tm >> 2) << 2)];
            const float* bp = &Bs[kk * SB + tn * TN + (((tn * TN) >> 5) << 2)];
            float a[8], bb[TN];
            #pragma unroll
            for (int q = 0; q < 8; q += 4) {
                const float4 v = *(const float4*)(ap + q);
                a[q] = v.x; a[q + 1] = v.y; a[q + 2] = v.z; a[q + 3] = v.w;
            }
            #pragma unroll
            for (int q = 0; q < TN; q += 4) {
                const float4 v = *(const float4*)(bp + q);
                bb[q] = v.x; bb[q + 1] = v.y; bb[q + 2] = v.z; bb[q + 3] = v.w;
            }
            #pragma unroll
            for (int r = 0; r < 8; ++r)
                #pragma unroll
                for (int c = 0; c < TN; ++c)
                    acc[r][c] = fmaf(a[r], bb[c], acc[r][c]);
        }
    }

    const long pb = (long)blockIdx.y * 65536;
    #pragma unroll
    for (int r = 0; r < 8; ++r)
        #pragma unroll
        for (int c = 0; c < TN; ++c)
            part[pb + (tm * 8 + r) * 512 + n0 + tn * TN + c] = acc[r][c];
}

template<int NS>
__global__ __launch_bounds__(256)
void k_fc_reduce(const float* __restrict__ part, const float* __restrict__ bias,
                 float* __restrict__ H)
{
    const int f = (blockIdx.x * 256 + threadIdx.x) * 4;
    const int m = f >> 9, n = f & 511;
    float s0 = 0.f, s1 = 0.f, s2 = 0.f, s3 = 0.f;
    #pragma unroll 4
    for (int q = 0; q < NS; ++q) {
        const float* p = &part[(q * 128 + m) * 512 + n];
        s0 += p[0]; s1 += p[1]; s2 += p[2]; s3 += p[3];
    }
    H[f]     = fmaxf(s0 + bias[n],     0.f);
    H[f + 1] = fmaxf(s1 + bias[n + 1], 0.f);
    H[f + 2] = fmaxf(s2 + bias[n + 2], 0.f);
    H[f + 3] = fmaxf(s3 + bias[n + 3], 0.f);
}

// ---------------------------------------------------------------------------
// Final: FC3 + sampling + patch gather
// ---------------------------------------------------------------------------
__device__ __forceinline__ float softplusf(float x) {
    return (x > 20.f) ? x : log1pf(expf(x));
}
__device__ __forceinline__ float sigmoidf_(float x) {
    return 1.f / (1.f + expf(-x));
}

__global__ __launch_bounds__(256)
void k_final(const float* __restrict__ H2, const float* __restrict__ wl3,
             const float* __restrict__ bl3, const float* __restrict__ noise,
             const float* __restrict__ img, float* __restrict__ outp)
{
    __shared__ float h2[512];
    __shared__ float red[144];
    __shared__ float prep[36];
    __shared__ int ptsh[12], ptsw[12];
    const int b = blockIdx.x, t = threadIdx.x;

    h2[t]       = H2[b * 512 + t];
    h2[t + 256] = H2[b * 512 + 256 + t];
    __syncthreads();

    if (t < 144) {
        const int n = t >> 2, q = t & 3;
        float s = 0.f;
        for (int k = q * 128; k < q * 128 + 128; ++k)
            s = fmaf(h2[k], wl3[k * 36 + n], s);
        red[t] = s;
    }
    __syncthreads();
    if (t < 36)
        prep[t] = red[t * 4] + red[t * 4 + 1] + red[t * 4 + 2] + red[t * 4 + 3] + bl3[t];
    __syncthreads();

    if (t < 12) {
        const float m0 = prep[t * 3], m1 = prep[t * 3 + 1], sv = prep[t * 3 + 2];
        const float sig = softplusf(sv + 2.0f) * 128.f + 1e-7f;
        const float n0 = noise[(b * 12 + t) * 2], n1 = noise[(b * 12 + t) * 2 + 1];
        const float sa0 = m0 + sig * n0;
        const float sa1 = m1 + sig * n1;
        int p0 = (int)rintf(sigmoidf_(sa0) * 111.f);
        int p1 = (int)rintf(sigmoidf_(sa1) * 111.f);
        p0 = min(max(p0, 0), 111);
        p1 = min(max(p1, 0), 111);
        const int RM = 1179648;
        outp[RM        + (b * 12 + t) * 2 + 0] = m0;
        outp[RM        + (b * 12 + t) * 2 + 1] = m1;
        outp[RM + 3072 + (b * 12 + t) * 2 + 0] = sig;
        outp[RM + 3072 + (b * 12 + t) * 2 + 1] = sig;
        outp[RM + 6144 + (b * 12 + t) * 2 + 0] = sa0;
        outp[RM + 6144 + (b * 12 + t) * 2 + 1] = sa1;
        ptsh[t] = p0;
        ptsw[t] = p1;
    }
    __syncthreads();

    for (int i = t; i < 9216; i += 256) {
        const int g  = i / 768, r = i - g * 768;
        const int c  = r >> 8, r2 = r & 255;
        const int y  = r2 >> 4, x = r2 & 15;
        outp[b * 9216 + i] = img[((b * 3 + c) * 128 + ptsh[g] + y) * 128 + (ptsw[g] + x)];
    }
}

// ---------------------------------------------------------------------------
extern "C" void kernel_launch(void* const* d_in, const int* in_sizes, int n_in,
                              void* d_out, int out_size, void* d_ws, size_t ws_size,
                              hipStream_t stream)
{
    const float* img  = (const float*)d_in[0];
    const float* nois = (const float*)d_in[1];
    const float* w1 = (const float*)d_in[2];  const float* b1 = (const float*)d_in[3];
    const float* w2 = (const float*)d_in[4];  const float* b2 = (const float*)d_in[5];
    const float* w3 = (const float*)d_in[6];  const float* b3 = (const float*)d_in[7];
    const float* w4 = (const float*)d_in[8];  const float* b4 = (const float*)d_in[9];
    const float* w5 = (const float*)d_in[10]; const float* b5 = (const float*)d_in[11];
    const float* w6 = (const float*)d_in[12]; const float* b6 = (const float*)d_in[13];
    const float* wl1 = (const float*)d_in[14]; const float* bl1 = (const float*)d_in[15];
    const float* wl2 = (const float*)d_in[16]; const float* bl2 = (const float*)d_in[17];
    const float* wl3 = (const float*)d_in[18]; const float* bl3 = (const float*)d_in[19];
    float* out = (float*)d_out;
    float* ws  = (float*)d_ws;

    // workspace (float units). Activation regions span [0 .. 20971520).
    // Weight packs live ABOVE all activations.
    _Float16* P1h = (_Float16*)(ws);               // [128*32*32*32] halves
    _Float16* P1l = (_Float16*)(ws + 2097152);
    _Float16* A3h = (_Float16*)(ws + 4194304);     // [128*32*32*64]
    _Float16* A3l = (_Float16*)(ws + 8388608);
    _Float16* A4h = (_Float16*)(ws + 12582912);    // [128*32*32*64]
    _Float16* A4l = (_Float16*)(ws + 16777216);    // ..20971520
    _Float16* P2h = (_Float16*)(ws);               // [128*16*16*64] (P1 dead)
    _Float16* P2l = (_Float16*)(ws + 1048576);
    _Float16* A5h = (_Float16*)(ws + 4194304);     // [128*16*16*128] (A3 dead)
    _Float16* A5l = (_Float16*)(ws + 6291456);
    float* A6  = ws + 8388608;                     // [128*16*16*128] fp32 (A3 dead)
    float* FP1 = ws + 12582912;                    // [64][128][512] (A4h dead)
    float* H1  = ws + 16777216;                    // [128][512]     (A4l dead)
    float* FP2 = ws + 16842752;                    // [16][128][512]
    float* H2  = ws + 17891328;                    // [128][512]
    _Float16* Bh = (_Float16*)(ws + 20971520);     // 285696 halves (w2..w6)
    _Float16* Bl = (_Float16*)(ws + 21114368);     // ends 21257216 fl = 85 MB

    hipLaunchKernelGGL(k_wrepackm, dim3(1116), dim3(256), 0, stream,
                       w2, w3, w4, w5, w6, Bh, Bl);

    // conv1+conv2+pool4: grid = 8x8 tiles x 128 batch
    hipLaunchKernelGGL(k_conv12, dim3(64, 128), dim3(256), 0, stream,
                       img, w1, b1, Bh + 0, Bl + 0, b2, P1h, P1l);
    // conv3: M=131072, K=288, COUT=64
    hipLaunchKernelGGL((k_mgemm<32, 64, 32, false>), dim3(1024, 1), dim3(256), 0, stream,
                       P1h, P1l, Bh + 9216, Bl + 9216, b3, A3h, A3l, nullptr);
    // conv4: K=576
    hipLaunchKernelGGL((k_mgemm<64, 64, 32, false>), dim3(1024, 1), dim3(256), 0, stream,
                       A3h, A3l, Bh + 27648, Bl + 27648, b4, A4h, A4l, nullptr);
    hipLaunchKernelGGL(k_pool2h, dim3(2048), dim3(256), 0, stream, A4h, A4l, P2h, P2l);
    // conv5: M=32768, K=576, COUT=128
    hipLaunchKernelGGL((k_mgemm<64, 128, 16, false>), dim3(256, 2), dim3(256), 0, stream,
                       P2h, P2l, Bh + 64512, Bl + 64512, b5, A5h, A5l, nullptr);
    // conv6: K=1152, fp32 out for FC1
    hipLaunchKernelGGL((k_mgemm<128, 128, 16, true>), dim3(256, 2), dim3(256), 0, stream,
                       A5h, A5l, Bh + 138240, Bl + 138240, b6, nullptr, nullptr, A6);
    hipLaunchKernelGGL((k_fc_partial<32768, 512, 4, true>), dim3(8, 64), dim3(256), 0, stream,
                       A6, wl1, FP1);
    hipLaunchKernelGGL(k_fc_reduce<64>, dim3(64), dim3(256), 0, stream, FP1, bl1, H1);
    hipLaunchKernelGGL((k_fc_partial<512, 32, 4, false>), dim3(8, 16), dim3(256), 0, stream,
                       H1, wl2, FP2);
    hipLaunchKernelGGL(k_fc_reduce<16>, dim3(64), dim3(256), 0, stream, FP2, bl2, H2);
    hipLaunchKernelGGL(k_final, dim3(128), dim3(256), 0, stream,
                       H2, wl3, bl3, nois, img, out);
}

// Round 3
// 669.567 us; speedup vs baseline: 1.2539x; 1.1306x over previous
//
#include <hip/hip_runtime.h>
#include <math.h>

typedef _Float16 __attribute__((ext_vector_type(8))) half8_t;
typedef _Float16 __attribute__((ext_vector_type(4))) half4_t;
typedef _Float16 __attribute__((ext_vector_type(2))) half2_t;
typedef float    __attribute__((ext_vector_type(4))) float4_t;

// ---------------------------------------------------------------------------
// Kernel 1: fused conv1(VALU) + conv2(MFMA) + maxpool4.
// Block = 16x16 output tile.
// conv1: simg halo [3][20][25] (stride 25 ~ conflict-light); each lane loads
//   its 54-float window ONCE into registers, then 4 channel passes run against
//   registers (weights wave-uniform -> scalar loads). Output -> LDS C1 in
//   [slot=ch-oct][pos][j] fp16 hi/lo, POSP=328 (mult of 8 => XOR swizzle
//   bijective per aligned 8-block; R2's POSP=325 collided -> absmax 16).
// conv2: implicit GEMM M=256,K=288,N=32 via mfma_f32_16x16x32_f16, 3-term
//   fp16 hi/lo split. D-frag layout makes the 4x4 maxpool thread-local.
// ---------------------------------------------------------------------------
#define POSP 328

__device__ __forceinline__ int c1idx(int slot, int pos) {
    return ((slot * POSP + pos) * 8) ^ (((pos >> 3) & 7) << 3);
}

__global__ __launch_bounds__(256, 3)
void k_conv12(const float* __restrict__ img, const float* __restrict__ w1,
              const float* __restrict__ b1, const _Float16* __restrict__ B2h,
              const _Float16* __restrict__ B2l, const float* __restrict__ b2,
              _Float16* __restrict__ P1h, _Float16* __restrict__ P1l)
{
    __shared__ float simg[3 * 20 * 25];                      // input halo-2
    __shared__ __align__(16) _Float16 C1h[4 * POSP * 8];     // [slot][pos][j]
    __shared__ __align__(16) _Float16 C1l[4 * POSP * 8];

    const int t  = threadIdx.x;
    const int bt = blockIdx.x;
    const int b  = blockIdx.y;
    const int ty = bt >> 3, tx = bt & 7;
    const int oy = ty * 16, ox = tx * 16;

    for (int i = t; i < 1500; i += 256) {
        const int ci = i / 500, r = i - ci * 500;
        const int yy = r / 25, xx = r - yy * 25;
        const int gy = oy - 2 + yy, gx = ox - 2 + xx;
        float v = 0.f;
        if ((unsigned)gy < 128u && (unsigned)gx < 128u)
            v = img[((b * 3 + ci) * 128 + gy) * 128 + gx];
        simg[i] = v;
    }
    __syncthreads();

    const int wv   = __builtin_amdgcn_readfirstlane(t >> 6);
    const int lane = t & 63;

    // ---- conv1: window-in-registers, 4 channel passes over it ----
    #pragma unroll 1
    for (int it = 0; it < 2; ++it) {
        const int s   = lane + it * 64;
        const bool act = s < 90;
        const int ss  = act ? s : 0;
        const int yy  = ss / 5;
        const int x0  = (ss - yy * 5) * 4;

        // 3ci x 3rows x 6cols window, loaded once
        float win[3][3][6];
        #pragma unroll
        for (int ci = 0; ci < 3; ++ci)
            #pragma unroll
            for (int r = 0; r < 3; ++r) {
                const float* rp = &simg[(ci * 20 + yy + r) * 25 + x0];
                #pragma unroll
                for (int k = 0; k < 6; ++k)
                    win[ci][r][k] = rp[k];
            }

        const int gy   = oy - 1 + yy;
        const bool iny = (unsigned)gy < 128u;
        const int pos0 = yy * 18 + x0;

        #pragma unroll 1
        for (int p = 0; p < 4; ++p) {
            const int chb = p * 8 + wv * 2;     // wave-uniform
            float w1r[2][27];
            #pragma unroll
            for (int j = 0; j < 2; ++j)
                #pragma unroll
                for (int q = 0; q < 27; ++q)
                    w1r[j][q] = w1[(chb + j) * 27 + q];
            const float bb0 = b1[chb], bb1 = b1[chb + 1];

            float a0[4] = {0.f, 0.f, 0.f, 0.f};
            float a1[4] = {0.f, 0.f, 0.f, 0.f};
            #pragma unroll
            for (int ci = 0; ci < 3; ++ci)
                #pragma unroll
                for (int dy = 0; dy < 3; ++dy) {
                    const int wb = ci * 9 + dy * 3;
                    #pragma unroll
                    for (int c = 0; c < 4; ++c) {
                        a0[c] = fmaf(w1r[0][wb],     win[ci][dy][c],     a0[c]);
                        a0[c] = fmaf(w1r[0][wb + 1], win[ci][dy][c + 1], a0[c]);
                        a0[c] = fmaf(w1r[0][wb + 2], win[ci][dy][c + 2], a0[c]);
                        a1[c] = fmaf(w1r[1][wb],     win[ci][dy][c],     a1[c]);
                        a1[c] = fmaf(w1r[1][wb + 1], win[ci][dy][c + 1], a1[c]);
                        a1[c] = fmaf(w1r[1][wb + 2], win[ci][dy][c + 2], a1[c]);
                    }
                }

            if (act) {
                #pragma unroll
                for (int c = 0; c < 4; ++c) {
                    const int x = x0 + c;
                    if (x < 18) {
                        const bool ok = iny && (unsigned)(ox - 1 + x) < 128u;
                        const float v0 = ok ? fmaxf(a0[c] + bb0, 0.f) : 0.f;
                        const float v1 = ok ? fmaxf(a1[c] + bb1, 0.f) : 0.f;
                        const int wi  = c1idx(p, pos0 + c) + wv * 2;
                        const _Float16 h0 = (_Float16)v0, h1 = (_Float16)v1;
                        half2_t hh = {h0, h1};
                        half2_t ll = {(_Float16)(v0 - (float)h0),
                                      (_Float16)(v1 - (float)h1)};
                        *(half2_t*)(&C1h[wi]) = hh;
                        *(half2_t*)(&C1l[wi]) = ll;
                    }
                }
            }
        }
    }
    __syncthreads();

    // ---- conv2: implicit-GEMM MFMA, wave wv owns my rows wv*4..wv*4+3 ----
    const int fr = lane >> 4;
    const int ml = lane & 15;

    float4_t acc[4][2];
    #pragma unroll
    for (int i = 0; i < 4; ++i)
        #pragma unroll
        for (int nt = 0; nt < 2; ++nt)
            acc[i][nt] = (float4_t){0.f, 0.f, 0.f, 0.f};

    #pragma unroll 1
    for (int tap = 0; tap < 9; ++tap) {
        const int dy = tap / 3, dx = tap - dy * 3;
        half8_t bh[2], bl[2];
        #pragma unroll
        for (int nt = 0; nt < 2; ++nt) {
            const int bo = ((tap * 2 + nt) * 64 + lane) * 8;
            bh[nt] = *(const half8_t*)(B2h + bo);
            bl[nt] = *(const half8_t*)(B2l + bo);
        }
        half8_t ah[4], al[4];
        #pragma unroll
        for (int i = 0; i < 4; ++i) {
            const int pos = (wv * 4 + i + dy) * 18 + ml + dx;
            const int ri  = c1idx(fr, pos);
            ah[i] = *(const half8_t*)(&C1h[ri]);
            al[i] = *(const half8_t*)(&C1l[ri]);
        }
        #pragma unroll
        for (int nt = 0; nt < 2; ++nt)
            #pragma unroll
            for (int i = 0; i < 4; ++i)
                acc[i][nt] = __builtin_amdgcn_mfma_f32_16x16x32_f16(ah[i], bh[nt], acc[i][nt], 0, 0, 0);
        #pragma unroll
        for (int nt = 0; nt < 2; ++nt)
            #pragma unroll
            for (int i = 0; i < 4; ++i)
                acc[i][nt] = __builtin_amdgcn_mfma_f32_16x16x32_f16(al[i], bh[nt], acc[i][nt], 0, 0, 0);
        #pragma unroll
        for (int nt = 0; nt < 2; ++nt)
            #pragma unroll
            for (int i = 0; i < 4; ++i)
                acc[i][nt] = __builtin_amdgcn_mfma_f32_16x16x32_f16(ah[i], bl[nt], acc[i][nt], 0, 0, 0);
    }

    // ---- maxpool4 (fully thread-local) + bias + relu + hi/lo store ----
    // acc[i][nt][r] = conv2 out at my=wv*4+i, mx=fr*4+r, oc=nt*16+ml
    const int py = ty * 4 + wv;
    const int px = tx * 4 + fr;
    #pragma unroll
    for (int nt = 0; nt < 2; ++nt) {
        float m = -1e30f;
        #pragma unroll
        for (int i = 0; i < 4; ++i)
            #pragma unroll
            for (int r = 0; r < 4; ++r)
                m = fmaxf(m, acc[i][nt][r]);
        const int oc = nt * 16 + ml;
        const float v = fmaxf(m + b2[oc], 0.f);
        const _Float16 h = (_Float16)v;
        const int base = ((b * 32 + py) * 32 + px) * 32 + oc;
        P1h[base] = h;
        P1l[base] = (_Float16)(v - (float)h);
    }
}

// ---------------------------------------------------------------------------
// Weight repack: fp16 hi/lo MFMA-fragment packs for w2..w6.
// Frag order: Bh[((c*NT + ntg)*64 + lane)*8 + j], element B[k][n]:
//   n = ntg*16 + (lane&15), k = c*32 + (lane>>4)*8 + j, k = tap*CIN + ci.
// ---------------------------------------------------------------------------
__global__ void k_wrepackm(const float* __restrict__ w2, const float* __restrict__ w3,
                           const float* __restrict__ w4, const float* __restrict__ w5,
                           const float* __restrict__ w6,
                           _Float16* __restrict__ Bh, _Float16* __restrict__ Bl)
{
    int idx = blockIdx.x * 256 + threadIdx.x;
    const float* w; int CIN, COUT, off;
    if (idx < 9216)        { w = w2; CIN = 32;  COUT = 32;  off = 0; }
    else if (idx < 27648)  { idx -= 9216;   w = w3; CIN = 32;  COUT = 64;  off = 9216; }
    else if (idx < 64512)  { idx -= 27648;  w = w4; CIN = 64;  COUT = 64;  off = 27648; }
    else if (idx < 138240) { idx -= 64512;  w = w5; CIN = 64;  COUT = 128; off = 64512; }
    else if (idx < 285696) { idx -= 138240; w = w6; CIN = 128; COUT = 128; off = 138240; }
    else return;
    const int NT  = COUT / 16;
    const int c   = idx / (NT * 512);
    const int r   = idx - c * NT * 512;
    const int ntg = r >> 9;
    const int rr  = r & 511;
    const int lane = rr >> 3, j = rr & 7;
    const int k   = c * 32 + (lane >> 4) * 8 + j;
    const int tap = k / CIN, ci = k - tap * CIN;
    const int oc  = ntg * 16 + (lane & 15);
    const float v = w[(oc * CIN + ci) * 9 + tap];
    const _Float16 h = (_Float16)v;
    Bh[off + idx] = h;
    Bl[off + idx] = (_Float16)(v - (float)h);
}

// ---------------------------------------------------------------------------
// MFMA implicit-GEMM conv3x3, fp16x3 split (fp32-class: ll term <= 2^-22 rel).
// BM=128, BN=64 per block; 4 waves, wave = 2 m-tiles x 4 n-tiles.
// ---------------------------------------------------------------------------
template<int CIN, int COUT, int HW, bool OUTF32>
__global__ __launch_bounds__(256, 2)
void k_mgemm(const _Float16* __restrict__ inh, const _Float16* __restrict__ inl,
             const _Float16* __restrict__ Bh, const _Float16* __restrict__ Bl,
             const float* __restrict__ bias,
             _Float16* __restrict__ outh, _Float16* __restrict__ outl,
             float* __restrict__ outf)
{
    constexpr int NCH = CIN * 9 / 32;
    constexpr int NT  = COUT / 16;
    constexpr int LOG = (HW == 32) ? 5 : 4;
    constexpr int PS  = 40;
    __shared__ _Float16 Ash[128 * PS];
    __shared__ _Float16 Asl[128 * PS];

    const int t    = threadIdx.x;
    const int wv   = t >> 6;
    const int lane = t & 63;
    const int m0   = blockIdx.x * 128;
    const int nb   = blockIdx.y;

    int sm[2], sg[2], sb[2], sy[2], sx[2];
    #pragma unroll
    for (int j = 0; j < 2; ++j) {
        const int q = t + 256 * j;
        sm[j] = q >> 2;
        sg[j] = q & 3;
        const int m  = m0 + sm[j];
        const int yx = m & (HW * HW - 1);
        sb[j] = m >> (2 * LOG);
        sy[j] = yx >> LOG;
        sx[j] = yx & (HW - 1);
    }

    const int mt0 = wv * 2;
    const int fr  = lane >> 4;
    const int ml  = lane & 15;

    float4_t acc[2][4];
    #pragma unroll
    for (int mt = 0; mt < 2; ++mt)
        #pragma unroll
        for (int tn = 0; tn < 4; ++tn)
            acc[mt][tn] = (float4_t){0.f, 0.f, 0.f, 0.f};

    #pragma unroll 1
    for (int ch = 0; ch < NCH; ++ch) {
        const int kb  = ch * 32;
        const int tap = kb / CIN;
        const int c0  = kb - tap * CIN;
        const int dy  = tap / 3 - 1, dx = tap - (tap / 3) * 3 - 1;

        if (ch) __syncthreads();
        #pragma unroll
        for (int j = 0; j < 2; ++j) {
            const int iy = sy[j] + dy, ix = sx[j] + dx;
            half8_t vh = {0, 0, 0, 0, 0, 0, 0, 0};
            half8_t vl = {0, 0, 0, 0, 0, 0, 0, 0};
            if ((unsigned)iy < (unsigned)HW && (unsigned)ix < (unsigned)HW) {
                const int o = ((sb[j] * HW + iy) * HW + ix) * CIN + c0 + sg[j] * 8;
                vh = *(const half8_t*)(inh + o);
                vl = *(const half8_t*)(inl + o);
            }
            *(half8_t*)(&Ash[sm[j] * PS + sg[j] * 8]) = vh;
            *(half8_t*)(&Asl[sm[j] * PS + sg[j] * 8]) = vl;
        }
        __syncthreads();

        half8_t ah[2], al[2];
        #pragma unroll
        for (int mt = 0; mt < 2; ++mt) {
            const int mr = (mt0 + mt) * 16 + ml;
            ah[mt] = *(const half8_t*)(&Ash[mr * PS + fr * 8]);
            al[mt] = *(const half8_t*)(&Asl[mr * PS + fr * 8]);
        }
        half8_t bh[4], bl[4];
        #pragma unroll
        for (int tn = 0; tn < 4; ++tn) {
            const int bo = ((ch * NT + nb * 4 + tn) * 64 + lane) * 8;
            bh[tn] = *(const half8_t*)(Bh + bo);
            bl[tn] = *(const half8_t*)(Bl + bo);
        }
        #pragma unroll
        for (int tn = 0; tn < 4; ++tn)
            #pragma unroll
            for (int mt = 0; mt < 2; ++mt)
                acc[mt][tn] = __builtin_amdgcn_mfma_f32_16x16x32_f16(ah[mt], bh[tn], acc[mt][tn], 0, 0, 0);
        #pragma unroll
        for (int tn = 0; tn < 4; ++tn)
            #pragma unroll
            for (int mt = 0; mt < 2; ++mt)
                acc[mt][tn] = __builtin_amdgcn_mfma_f32_16x16x32_f16(al[mt], bh[tn], acc[mt][tn], 0, 0, 0);
        #pragma unroll
        for (int tn = 0; tn < 4; ++tn)
            #pragma unroll
            for (int mt = 0; mt < 2; ++mt)
                acc[mt][tn] = __builtin_amdgcn_mfma_f32_16x16x32_f16(ah[mt], bl[tn], acc[mt][tn], 0, 0, 0);
        // (al,bl) term dropped: <= 2^-22 relative contribution.
    }

    // epilogue: C/D frag col=lane&15, row=(lane>>4)*4+reg  [guide m89/m91]
    #pragma unroll
    for (int mt = 0; mt < 2; ++mt)
        #pragma unroll
        for (int tn = 0; tn < 4; ++tn) {
            const int oc = nb * 64 + tn * 16 + ml;
            const float bv = bias[oc];
            #pragma unroll
            for (int r = 0; r < 4; ++r) {
                const int m = m0 + (mt0 + mt) * 16 + fr * 4 + r;
                const float v = fmaxf(acc[mt][tn][r] + bv, 0.f);
                if (OUTF32) {
                    outf[m * COUT + oc] = v;
                } else {
                    const _Float16 h = (_Float16)v;
                    outh[m * COUT + oc] = h;
                    outl[m * COUT + oc] = (_Float16)(v - (float)h);
                }
            }
        }
}

// ---------------------------------------------------------------------------
// 2x2 maxpool on dual fp16 planes, NHWC [128][32][32][64] -> [128][16][16][64]
// ---------------------------------------------------------------------------
__global__ __launch_bounds__(256)
void k_pool2h(const _Float16* __restrict__ inh, const _Float16* __restrict__ inl,
              _Float16* __restrict__ outh, _Float16* __restrict__ outl)
{
    const int g = blockIdx.x * 256 + threadIdx.x;
    const int c4 = g & 15, xo = (g >> 4) & 15, yo = (g >> 8) & 15, b = g >> 12;
    const int base = ((b * 32 + yo * 2) * 32 + xo * 2) * 64 + c4 * 4;
    const int offs[4] = {0, 64, 2048, 2112};
    float mx[4] = {-1e30f, -1e30f, -1e30f, -1e30f};
    #pragma unroll
    for (int cnd = 0; cnd < 4; ++cnd) {
        const half4_t h = *(const half4_t*)(inh + base + offs[cnd]);
        const half4_t l = *(const half4_t*)(inl + base + offs[cnd]);
        #pragma unroll
        for (int e = 0; e < 4; ++e)
            mx[e] = fmaxf(mx[e], (float)h[e] + (float)l[e]);
    }
    half4_t oh, ol;
    #pragma unroll
    for (int e = 0; e < 4; ++e) {
        const _Float16 h = (_Float16)mx[e];
        oh[e] = h;
        ol[e] = (_Float16)(mx[e] - (float)h);
    }
    const int ob = ((b * 16 + yo) * 16 + xo) * 64 + c4 * 4;
    *(half4_t*)(outh + ob) = oh;
    *(half4_t*)(outl + ob) = ol;
}

// ---------------------------------------------------------------------------
// Split-K FC partial (fp32): A[128 x K] @ B[K x 512] -> part[ky][128][512]
// ---------------------------------------------------------------------------
template<int LDA, int KCHUNK, int TN, bool PERM>
__global__ __launch_bounds__(256, 2)
void k_fc_partial(const float* __restrict__ A, const float* __restrict__ Bw,
                  float* __restrict__ part)
{
    constexpr int BN = 16 * TN;
    constexpr int SA = 140;
    constexpr int SB = (BN == 128) ? 140 : 68;
    __shared__ __align__(16) float As[32 * SA];
    __shared__ __align__(16) float Bs[32 * SB];
    const int t  = threadIdx.x;
    const int tm = t >> 4, tn = t & 15;
    const int n0 = blockIdx.x * BN;
    const int k0 = blockIdx.y * KCHUNK;

    float acc[8][TN];
    #pragma unroll
    for (int r = 0; r < 8; ++r)
        #pragma unroll
        for (int c = 0; c < TN; ++c) acc[r][c] = 0.f;

    #pragma unroll 1
    for (int ks = 0; ks < KCHUNK / 32; ++ks) {
        if (ks) __syncthreads();
        const int kb = k0 + ks * 32;
        for (int i = t; i < 4096; i += 256) {
            const int m = i >> 5, kk = i & 31;
            As[kk * SA + m + ((m >> 5) << 2)] = A[m * LDA + kb + kk];
        }
        for (int i = t; i < 32 * BN; i += 256) {
            const int kk = i / BN, n = i - kk * BN;
            const int krow = kb + kk;
            const int kref = PERM ? ((krow & 127) * 256 + (krow >> 7)) : krow;
            Bs[kk * SB + n + ((n >> 5) << 2)] = Bw[kref * 512 + n0 + n];
        }
        __syncthreads();
        #pragma unroll 2
        for (int kk = 0; kk < 32; ++kk) {
            const float* ap = &As[kk * SA + tm * 8 + ((tm >> 2) << 2)];
            const float* bp = &Bs[kk * SB + tn * TN + (((tn * TN) >> 5) << 2)];
            float a[8], bb[TN];
            #pragma unroll
            for (int q = 0; q < 8; q += 4) {
                const float4 v = *(const float4*)(ap + q);
                a[q] = v.x; a[q + 1] = v.y; a[q + 2] = v.z; a[q + 3] = v.w;
            }
            #pragma unroll
            for (int q = 0; q < TN; q += 4) {
                const float4 v = *(const float4*)(bp + q);
                bb[q] = v.x; bb[q + 1] = v.y; bb[q + 2] = v.z; bb[q + 3] = v.w;
            }
            #pragma unroll
            for (int r = 0; r < 8; ++r)
                #pragma unroll
                for (int c = 0; c < TN; ++c)
                    acc[r][c] = fmaf(a[r], bb[c], acc[r][c]);
        }
    }

    const long pb = (long)blockIdx.y * 65536;
    #pragma unroll
    for (int r = 0; r < 8; ++r)
        #pragma unroll
        for (int c = 0; c < TN; ++c)
            part[pb + (tm * 8 + r) * 512 + n0 + tn * TN + c] = acc[r][c];
}

template<int NS>
__global__ __launch_bounds__(256)
void k_fc_reduce(const float* __restrict__ part, const float* __restrict__ bias,
                 float* __restrict__ H)
{
    const int f = (blockIdx.x * 256 + threadIdx.x) * 4;
    const int m = f >> 9, n = f & 511;
    float s0 = 0.f, s1 = 0.f, s2 = 0.f, s3 = 0.f;
    #pragma unroll 4
    for (int q = 0; q < NS; ++q) {
        const float* p = &part[(q * 128 + m) * 512 + n];
        s0 += p[0]; s1 += p[1]; s2 += p[2]; s3 += p[3];
    }
    H[f]     = fmaxf(s0 + bias[n],     0.f);
    H[f + 1] = fmaxf(s1 + bias[n + 1], 0.f);
    H[f + 2] = fmaxf(s2 + bias[n + 2], 0.f);
    H[f + 3] = fmaxf(s3 + bias[n + 3], 0.f);
}

// ---------------------------------------------------------------------------
// Final: FC3 + sampling + patch gather
// ---------------------------------------------------------------------------
__device__ __forceinline__ float softplusf(float x) {
    return (x > 20.f) ? x : log1pf(expf(x));
}
__device__ __forceinline__ float sigmoidf_(float x) {
    return 1.f / (1.f + expf(-x));
}

__global__ __launch_bounds__(256)
void k_final(const float* __restrict__ H2, const float* __restrict__ wl3,
             const float* __restrict__ bl3, const float* __restrict__ noise,
             const float* __restrict__ img, float* __restrict__ outp)
{
    __shared__ float h2[512];
    __shared__ float red[144];
    __shared__ float prep[36];
    __shared__ int ptsh[12], ptsw[12];
    const int b = blockIdx.x, t = threadIdx.x;

    h2[t]       = H2[b * 512 + t];
    h2[t + 256] = H2[b * 512 + 256 + t];
    __syncthreads();

    if (t < 144) {
        const int n = t >> 2, q = t & 3;
        float s = 0.f;
        for (int k = q * 128; k < q * 128 + 128; ++k)
            s = fmaf(h2[k], wl3[k * 36 + n], s);
        red[t] = s;
    }
    __syncthreads();
    if (t < 36)
        prep[t] = red[t * 4] + red[t * 4 + 1] + red[t * 4 + 2] + red[t * 4 + 3] + bl3[t];
    __syncthreads();

    if (t < 12) {
        const float m0 = prep[t * 3], m1 = prep[t * 3 + 1], sv = prep[t * 3 + 2];
        const float sig = softplusf(sv + 2.0f) * 128.f + 1e-7f;
        const float n0 = noise[(b * 12 + t) * 2], n1 = noise[(b * 12 + t) * 2 + 1];
        const float sa0 = m0 + sig * n0;
        const float sa1 = m1 + sig * n1;
        int p0 = (int)rintf(sigmoidf_(sa0) * 111.f);
        int p1 = (int)rintf(sigmoidf_(sa1) * 111.f);
        p0 = min(max(p0, 0), 111);
        p1 = min(max(p1, 0), 111);
        const int RM = 1179648;
        outp[RM        + (b * 12 + t) * 2 + 0] = m0;
        outp[RM        + (b * 12 + t) * 2 + 1] = m1;
        outp[RM + 3072 + (b * 12 + t) * 2 + 0] = sig;
        outp[RM + 3072 + (b * 12 + t) * 2 + 1] = sig;
        outp[RM + 6144 + (b * 12 + t) * 2 + 0] = sa0;
        outp[RM + 6144 + (b * 12 + t) * 2 + 1] = sa1;
        ptsh[t] = p0;
        ptsw[t] = p1;
    }
    __syncthreads();

    for (int i = t; i < 9216; i += 256) {
        const int g  = i / 768, r = i - g * 768;
        const int c  = r >> 8, r2 = r & 255;
        const int y  = r2 >> 4, x = r2 & 15;
        outp[b * 9216 + i] = img[((b * 3 + c) * 128 + ptsh[g] + y) * 128 + (ptsw[g] + x)];
    }
}

// ---------------------------------------------------------------------------
extern "C" void kernel_launch(void* const* d_in, const int* in_sizes, int n_in,
                              void* d_out, int out_size, void* d_ws, size_t ws_size,
                              hipStream_t stream)
{
    const float* img  = (const float*)d_in[0];
    const float* nois = (const float*)d_in[1];
    const float* w1 = (const float*)d_in[2];  const float* b1 = (const float*)d_in[3];
    const float* w2 = (const float*)d_in[4];  const float* b2 = (const float*)d_in[5];
    const float* w3 = (const float*)d_in[6];  const float* b3 = (const float*)d_in[7];
    const float* w4 = (const float*)d_in[8];  const float* b4 = (const float*)d_in[9];
    const float* w5 = (const float*)d_in[10]; const float* b5 = (const float*)d_in[11];
    const float* w6 = (const float*)d_in[12]; const float* b6 = (const float*)d_in[13];
    const float* wl1 = (const float*)d_in[14]; const float* bl1 = (const float*)d_in[15];
    const float* wl2 = (const float*)d_in[16]; const float* bl2 = (const float*)d_in[17];
    const float* wl3 = (const float*)d_in[18]; const float* bl3 = (const float*)d_in[19];
    float* out = (float*)d_out;
    float* ws  = (float*)d_ws;

    // workspace (float units). Activation regions span [0 .. 20971520).
    // Weight packs live ABOVE all activations.
    _Float16* P1h = (_Float16*)(ws);               // [128*32*32*32] halves
    _Float16* P1l = (_Float16*)(ws + 2097152);
    _Float16* A3h = (_Float16*)(ws + 4194304);     // [128*32*32*64]
    _Float16* A3l = (_Float16*)(ws + 8388608);
    _Float16* A4h = (_Float16*)(ws + 12582912);    // [128*32*32*64]
    _Float16* A4l = (_Float16*)(ws + 16777216);    // ..20971520
    _Float16* P2h = (_Float16*)(ws);               // [128*16*16*64] (P1 dead)
    _Float16* P2l = (_Float16*)(ws + 1048576);
    _Float16* A5h = (_Float16*)(ws + 4194304);     // [128*16*16*128] (A3 dead)
    _Float16* A5l = (_Float16*)(ws + 6291456);
    float* A6  = ws + 8388608;                     // [128*16*16*128] fp32 (A3 dead)
    float* FP1 = ws + 12582912;                    // [64][128][512] (A4h dead)
    float* H1  = ws + 16777216;                    // [128][512]     (A4l dead)
    float* FP2 = ws + 16842752;                    // [16][128][512]
    float* H2  = ws + 17891328;                    // [128][512]
    _Float16* Bh = (_Float16*)(ws + 20971520);     // 285696 halves (w2..w6)
    _Float16* Bl = (_Float16*)(ws + 21114368);     // ends 21257216 fl = 85 MB

    hipLaunchKernelGGL(k_wrepackm, dim3(1116), dim3(256), 0, stream,
                       w2, w3, w4, w5, w6, Bh, Bl);

    // conv1+conv2+pool4: grid = 8x8 tiles x 128 batch
    hipLaunchKernelGGL(k_conv12, dim3(64, 128), dim3(256), 0, stream,
                       img, w1, b1, Bh + 0, Bl + 0, b2, P1h, P1l);
    // conv3: M=131072, K=288, COUT=64
    hipLaunchKernelGGL((k_mgemm<32, 64, 32, false>), dim3(1024, 1), dim3(256), 0, stream,
                       P1h, P1l, Bh + 9216, Bl + 9216, b3, A3h, A3l, nullptr);
    // conv4: K=576
    hipLaunchKernelGGL((k_mgemm<64, 64, 32, false>), dim3(1024, 1), dim3(256), 0, stream,
                       A3h, A3l, Bh + 27648, Bl + 27648, b4, A4h, A4l, nullptr);
    hipLaunchKernelGGL(k_pool2h, dim3(2048), dim3(256), 0, stream, A4h, A4l, P2h, P2l);
    // conv5: M=32768, K=576, COUT=128
    hipLaunchKernelGGL((k_mgemm<64, 128, 16, false>), dim3(256, 2), dim3(256), 0, stream,
                       P2h, P2l, Bh + 64512, Bl + 64512, b5, A5h, A5l, nullptr);
    // conv6: K=1152, fp32 out for FC1
    hipLaunchKernelGGL((k_mgemm<128, 128, 16, true>), dim3(256, 2), dim3(256), 0, stream,
                       A5h, A5l, Bh + 138240, Bl + 138240, b6, nullptr, nullptr, A6);
    hipLaunchKernelGGL((k_fc_partial<32768, 512, 4, true>), dim3(8, 64), dim3(256), 0, stream,
                       A6, wl1, FP1);
    hipLaunchKernelGGL(k_fc_reduce<64>, dim3(64), dim3(256), 0, stream, FP1, bl1, H1);
    hipLaunchKernelGGL((k_fc_partial<512, 32, 4, false>), dim3(8, 16), dim3(256), 0, stream,
                       H1, wl2, FP2);
    hipLaunchKernelGGL(k_fc_reduce<16>, dim3(64), dim3(256), 0, stream, FP2, bl2, H2);
    hipLaunchKernelGGL(k_final, dim3(128), dim3(256), 0, stream,
                       H2, wl3, bl3, nois, img, out);
}

// Round 4
// 660.458 us; speedup vs baseline: 1.2711x; 1.0138x over previous
//
#include <hip/hip_runtime.h>
#include <math.h>

typedef _Float16 __attribute__((ext_vector_type(8))) half8_t;
typedef _Float16 __attribute__((ext_vector_type(4))) half4_t;
typedef _Float16 __attribute__((ext_vector_type(2))) half2_t;
typedef float    __attribute__((ext_vector_type(4))) float4_t;

// ---------------------------------------------------------------------------
// Kernel 1: fully-MFMA conv1 + conv2 + maxpool4 (block = 16x16 output tile).
// Phase A: im2col img -> LDS A[slot=k/8][pos=18*18][j=k&7] fp16 hi/lo,
//   k = ci*9+tap (27, zero-pad to 32). Same swizzled layout conv2 reads.
// Phase B: conv1 = GEMM M=324(pad 336), N=32, K=32 in ONE k-step:
//   21 m-tiles x 2 n-tiles x 3 split-term MFMAs. Waves own mt = wv+4q.
// Phase C: epilogue (bias/relu/out-of-image-zero) overwrites the SAME LDS
//   buffer with conv1 output (A is dead) -> LDS stays 43 KB, 3 blocks/CU.
// Phase D: conv2 implicit GEMM (M=256,K=288,N=32) + thread-local 4x4 pool.
// POSP=336: multiple of 8 keeps the XOR swizzle bijective (R2 lesson).
// ---------------------------------------------------------------------------
#define POSP 336

__device__ __forceinline__ int c1idx(int slot, int pos) {
    return ((slot * POSP + pos) * 8) ^ (((pos >> 3) & 7) << 3);
}

__global__ __launch_bounds__(256, 3)
void k_conv12(const float* __restrict__ img, const float* __restrict__ b1,
              const _Float16* __restrict__ B1h, const _Float16* __restrict__ B1l,
              const _Float16* __restrict__ B2h, const _Float16* __restrict__ B2l,
              const float* __restrict__ b2,
              _Float16* __restrict__ P1h, _Float16* __restrict__ P1l)
{
    __shared__ __align__(16) _Float16 C1h[4 * POSP * 8];   // A, then conv1 out
    __shared__ __align__(16) _Float16 C1l[4 * POSP * 8];

    const int t  = threadIdx.x;
    const int bt = blockIdx.x;
    const int b  = blockIdx.y;
    const int ty = bt >> 3, tx = bt & 7;
    const int oy = ty * 16, ox = tx * 16;

    // ---- Phase A: im2col into C1 (used as A). pos=(py,px) in 18x18 halo ----
    for (int i = t; i < 4 * POSP; i += 256) {
        const int slot = i / POSP;
        const int pos  = i - slot * POSP;
        half8_t vh = {0,0,0,0,0,0,0,0}, vl = {0,0,0,0,0,0,0,0};
        if (pos < 324) {
            const int py  = pos / 18, px = pos - py * 18;
            const int gy0 = oy + py - 2, gx0 = ox + px - 2;
            #pragma unroll
            for (int j = 0; j < 8; ++j) {
                const int k = slot * 8 + j;
                float v = 0.f;
                if (k < 27) {
                    const int ci = k / 9, tap = k - ci * 9;
                    const int dy = tap / 3, dx = tap - dy * 3;
                    const int gy = gy0 + dy, gx = gx0 + dx;
                    if ((unsigned)gy < 128u && (unsigned)gx < 128u)
                        v = img[((b * 3 + ci) * 128 + gy) * 128 + gx];
                }
                const _Float16 h = (_Float16)v;
                vh[j] = h;
                vl[j] = (_Float16)(v - (float)h);
            }
        }
        const int wi = c1idx(slot, pos);
        *(half8_t*)(&C1h[wi]) = vh;
        *(half8_t*)(&C1l[wi]) = vl;
    }
    __syncthreads();

    const int wv   = __builtin_amdgcn_readfirstlane(t >> 6);
    const int lane = t & 63;
    const int fr   = lane >> 4;
    const int ml   = lane & 15;

    // ---- Phase B: conv1 MFMA (K=32 in one step; 3-term fp16 split) ----
    half8_t w1h[2], w1l[2];
    #pragma unroll
    for (int nt = 0; nt < 2; ++nt) {
        w1h[nt] = *(const half8_t*)(B1h + (nt * 64 + lane) * 8);
        w1l[nt] = *(const half8_t*)(B1l + (nt * 64 + lane) * 8);
    }
    float4_t acc1[6][2];
    #pragma unroll
    for (int q = 0; q < 6; ++q)
        #pragma unroll
        for (int nt = 0; nt < 2; ++nt)
            acc1[q][nt] = (float4_t){0.f, 0.f, 0.f, 0.f};

    #pragma unroll
    for (int q = 0; q < 6; ++q) {
        const int mt = wv + q * 4;
        if (mt < 21) {
            const int ri = c1idx(fr, mt * 16 + ml);
            const half8_t ah = *(const half8_t*)(&C1h[ri]);
            const half8_t al = *(const half8_t*)(&C1l[ri]);
            #pragma unroll
            for (int nt = 0; nt < 2; ++nt) {
                acc1[q][nt] = __builtin_amdgcn_mfma_f32_16x16x32_f16(ah, w1h[nt], acc1[q][nt], 0, 0, 0);
                acc1[q][nt] = __builtin_amdgcn_mfma_f32_16x16x32_f16(al, w1h[nt], acc1[q][nt], 0, 0, 0);
                acc1[q][nt] = __builtin_amdgcn_mfma_f32_16x16x32_f16(ah, w1l[nt], acc1[q][nt], 0, 0, 0);
            }
        }
    }
    __syncthreads();          // all A reads done; buffer reusable

    // ---- Phase C: conv1 epilogue -> overwrite C1 with conv1 output ----
    // D-frag: ch(n)=nt*16+ml, pos(m)=mt*16+fr*4+r. Out-of-image rows/cols -> 0.
    #pragma unroll
    for (int q = 0; q < 6; ++q) {
        const int mt = wv + q * 4;
        if (mt < 21) {
            #pragma unroll
            for (int nt = 0; nt < 2; ++nt) {
                const int ch  = nt * 16 + ml;
                const float bb = b1[ch];
                #pragma unroll
                for (int r = 0; r < 4; ++r) {
                    const int pos = mt * 16 + fr * 4 + r;
                    if (pos < 324) {
                        const int py = pos / 18, px = pos - py * 18;
                        const int gy = oy + py - 1, gx = ox + px - 1;
                        float v = 0.f;
                        if ((unsigned)gy < 128u && (unsigned)gx < 128u)
                            v = fmaxf(acc1[q][nt][r] + bb, 0.f);
                        const int wi = c1idx(ch >> 3, pos) + (ch & 7);
                        const _Float16 h = (_Float16)v;
                        C1h[wi] = h;
                        C1l[wi] = (_Float16)(v - (float)h);
                    }
                }
            }
        }
    }
    __syncthreads();

    // ---- Phase D: conv2 implicit-GEMM, wave wv owns out rows wv*4..wv*4+3 --
    float4_t acc[4][2];
    #pragma unroll
    for (int i = 0; i < 4; ++i)
        #pragma unroll
        for (int nt = 0; nt < 2; ++nt)
            acc[i][nt] = (float4_t){0.f, 0.f, 0.f, 0.f};

    #pragma unroll 1
    for (int tap = 0; tap < 9; ++tap) {
        const int dy = tap / 3, dx = tap - dy * 3;
        half8_t bh[2], bl[2];
        #pragma unroll
        for (int nt = 0; nt < 2; ++nt) {
            const int bo = ((tap * 2 + nt) * 64 + lane) * 8;
            bh[nt] = *(const half8_t*)(B2h + bo);
            bl[nt] = *(const half8_t*)(B2l + bo);
        }
        half8_t ah[4], al[4];
        #pragma unroll
        for (int i = 0; i < 4; ++i) {
            const int pos = (wv * 4 + i + dy) * 18 + ml + dx;
            const int ri  = c1idx(fr, pos);
            ah[i] = *(const half8_t*)(&C1h[ri]);
            al[i] = *(const half8_t*)(&C1l[ri]);
        }
        #pragma unroll
        for (int nt = 0; nt < 2; ++nt)
            #pragma unroll
            for (int i = 0; i < 4; ++i)
                acc[i][nt] = __builtin_amdgcn_mfma_f32_16x16x32_f16(ah[i], bh[nt], acc[i][nt], 0, 0, 0);
        #pragma unroll
        for (int nt = 0; nt < 2; ++nt)
            #pragma unroll
            for (int i = 0; i < 4; ++i)
                acc[i][nt] = __builtin_amdgcn_mfma_f32_16x16x32_f16(al[i], bh[nt], acc[i][nt], 0, 0, 0);
        #pragma unroll
        for (int nt = 0; nt < 2; ++nt)
            #pragma unroll
            for (int i = 0; i < 4; ++i)
                acc[i][nt] = __builtin_amdgcn_mfma_f32_16x16x32_f16(ah[i], bl[nt], acc[i][nt], 0, 0, 0);
    }

    // ---- maxpool4 (thread-local) + bias + relu + hi/lo store ----
    const int py = ty * 4 + wv;
    const int px = tx * 4 + fr;
    #pragma unroll
    for (int nt = 0; nt < 2; ++nt) {
        float m = -1e30f;
        #pragma unroll
        for (int i = 0; i < 4; ++i)
            #pragma unroll
            for (int r = 0; r < 4; ++r)
                m = fmaxf(m, acc[i][nt][r]);
        const int oc = nt * 16 + ml;
        const float v = fmaxf(m + b2[oc], 0.f);
        const _Float16 h = (_Float16)v;
        const int base = ((b * 32 + py) * 32 + px) * 32 + oc;
        P1h[base] = h;
        P1l[base] = (_Float16)(v - (float)h);
    }
}

// ---------------------------------------------------------------------------
// Weight repack: fp16 hi/lo MFMA-fragment packs for w2..w6 (+ w1, K padded
// 27->32). Frag order: Bh[((c*NT + ntg)*64 + lane)*8 + j], element B[k][n]:
//   n = ntg*16 + (lane&15), k = c*32 + (lane>>4)*8 + j.
// w2..w6: k = tap*CIN + ci.  w1: k = ci*9 + tap (= w1 natural order).
// ---------------------------------------------------------------------------
__global__ void k_wrepackm(const float* __restrict__ w1, const float* __restrict__ w2,
                           const float* __restrict__ w3, const float* __restrict__ w4,
                           const float* __restrict__ w5, const float* __restrict__ w6,
                           _Float16* __restrict__ Bh, _Float16* __restrict__ Bl,
                           _Float16* __restrict__ B1h, _Float16* __restrict__ B1l)
{
    int idx = blockIdx.x * 256 + threadIdx.x;
    if (idx >= 285696) {
        const int i = idx - 285696;
        if (i >= 1024) return;
        const int ntg = i >> 9, rr = i & 511;
        const int lane = rr >> 3, j = rr & 7;
        const int k = (lane >> 4) * 8 + j;
        const int n = ntg * 16 + (lane & 15);
        const float v = (k < 27) ? w1[n * 27 + k] : 0.f;
        const _Float16 h = (_Float16)v;
        B1h[i] = h;
        B1l[i] = (_Float16)(v - (float)h);
        return;
    }
    const float* w; int CIN, COUT, off;
    if (idx < 9216)        { w = w2; CIN = 32;  COUT = 32;  off = 0; }
    else if (idx < 27648)  { idx -= 9216;   w = w3; CIN = 32;  COUT = 64;  off = 9216; }
    else if (idx < 64512)  { idx -= 27648;  w = w4; CIN = 64;  COUT = 64;  off = 27648; }
    else if (idx < 138240) { idx -= 64512;  w = w5; CIN = 64;  COUT = 128; off = 64512; }
    else                   { idx -= 138240; w = w6; CIN = 128; COUT = 128; off = 138240; }
    const int NT  = COUT / 16;
    const int c   = idx / (NT * 512);
    const int r   = idx - c * NT * 512;
    const int ntg = r >> 9;
    const int rr  = r & 511;
    const int lane = rr >> 3, j = rr & 7;
    const int k   = c * 32 + (lane >> 4) * 8 + j;
    const int tap = k / CIN, ci = k - tap * CIN;
    const int oc  = ntg * 16 + (lane & 15);
    const float v = w[(oc * CIN + ci) * 9 + tap];
    const _Float16 h = (_Float16)v;
    Bh[off + idx] = h;
    Bl[off + idx] = (_Float16)(v - (float)h);
}

// ---------------------------------------------------------------------------
// MFMA implicit-GEMM conv3x3, fp16x3 split (fp32-class: ll term <= 2^-22 rel).
// BM=128, BN=64 per block; 4 waves, wave = 2 m-tiles x 4 n-tiles.
// ---------------------------------------------------------------------------
template<int CIN, int COUT, int HW, bool OUTF32>
__global__ __launch_bounds__(256, 2)
void k_mgemm(const _Float16* __restrict__ inh, const _Float16* __restrict__ inl,
             const _Float16* __restrict__ Bh, const _Float16* __restrict__ Bl,
             const float* __restrict__ bias,
             _Float16* __restrict__ outh, _Float16* __restrict__ outl,
             float* __restrict__ outf)
{
    constexpr int NCH = CIN * 9 / 32;
    constexpr int NT  = COUT / 16;
    constexpr int LOG = (HW == 32) ? 5 : 4;
    constexpr int PS  = 40;
    __shared__ _Float16 Ash[128 * PS];
    __shared__ _Float16 Asl[128 * PS];

    const int t    = threadIdx.x;
    const int wv   = t >> 6;
    const int lane = t & 63;
    const int m0   = blockIdx.x * 128;
    const int nb   = blockIdx.y;

    int sm[2], sg[2], sb[2], sy[2], sx[2];
    #pragma unroll
    for (int j = 0; j < 2; ++j) {
        const int q = t + 256 * j;
        sm[j] = q >> 2;
        sg[j] = q & 3;
        const int m  = m0 + sm[j];
        const int yx = m & (HW * HW - 1);
        sb[j] = m >> (2 * LOG);
        sy[j] = yx >> LOG;
        sx[j] = yx & (HW - 1);
    }

    const int mt0 = wv * 2;
    const int fr  = lane >> 4;
    const int ml  = lane & 15;

    float4_t acc[2][4];
    #pragma unroll
    for (int mt = 0; mt < 2; ++mt)
        #pragma unroll
        for (int tn = 0; tn < 4; ++tn)
            acc[mt][tn] = (float4_t){0.f, 0.f, 0.f, 0.f};

    #pragma unroll 1
    for (int ch = 0; ch < NCH; ++ch) {
        const int kb  = ch * 32;
        const int tap = kb / CIN;
        const int c0  = kb - tap * CIN;
        const int dy  = tap / 3 - 1, dx = tap - (tap / 3) * 3 - 1;

        if (ch) __syncthreads();
        #pragma unroll
        for (int j = 0; j < 2; ++j) {
            const int iy = sy[j] + dy, ix = sx[j] + dx;
            half8_t vh = {0, 0, 0, 0, 0, 0, 0, 0};
            half8_t vl = {0, 0, 0, 0, 0, 0, 0, 0};
            if ((unsigned)iy < (unsigned)HW && (unsigned)ix < (unsigned)HW) {
                const int o = ((sb[j] * HW + iy) * HW + ix) * CIN + c0 + sg[j] * 8;
                vh = *(const half8_t*)(inh + o);
                vl = *(const half8_t*)(inl + o);
            }
            *(half8_t*)(&Ash[sm[j] * PS + sg[j] * 8]) = vh;
            *(half8_t*)(&Asl[sm[j] * PS + sg[j] * 8]) = vl;
        }
        __syncthreads();

        half8_t ah[2], al[2];
        #pragma unroll
        for (int mt = 0; mt < 2; ++mt) {
            const int mr = (mt0 + mt) * 16 + ml;
            ah[mt] = *(const half8_t*)(&Ash[mr * PS + fr * 8]);
            al[mt] = *(const half8_t*)(&Asl[mr * PS + fr * 8]);
        }
        half8_t bh[4], bl[4];
        #pragma unroll
        for (int tn = 0; tn < 4; ++tn) {
            const int bo = ((ch * NT + nb * 4 + tn) * 64 + lane) * 8;
            bh[tn] = *(const half8_t*)(Bh + bo);
            bl[tn] = *(const half8_t*)(Bl + bo);
        }
        #pragma unroll
        for (int tn = 0; tn < 4; ++tn)
            #pragma unroll
            for (int mt = 0; mt < 2; ++mt)
                acc[mt][tn] = __builtin_amdgcn_mfma_f32_16x16x32_f16(ah[mt], bh[tn], acc[mt][tn], 0, 0, 0);
        #pragma unroll
        for (int tn = 0; tn < 4; ++tn)
            #pragma unroll
            for (int mt = 0; mt < 2; ++mt)
                acc[mt][tn] = __builtin_amdgcn_mfma_f32_16x16x32_f16(al[mt], bh[tn], acc[mt][tn], 0, 0, 0);
        #pragma unroll
        for (int tn = 0; tn < 4; ++tn)
            #pragma unroll
            for (int mt = 0; mt < 2; ++mt)
                acc[mt][tn] = __builtin_amdgcn_mfma_f32_16x16x32_f16(ah[mt], bl[tn], acc[mt][tn], 0, 0, 0);
        // (al,bl) term dropped: <= 2^-22 relative contribution.
    }

    // epilogue: C/D frag col=lane&15, row=(lane>>4)*4+reg  [guide m89/m91]
    #pragma unroll
    for (int mt = 0; mt < 2; ++mt)
        #pragma unroll
        for (int tn = 0; tn < 4; ++tn) {
            const int oc = nb * 64 + tn * 16 + ml;
            const float bv = bias[oc];
            #pragma unroll
            for (int r = 0; r < 4; ++r) {
                const int m = m0 + (mt0 + mt) * 16 + fr * 4 + r;
                const float v = fmaxf(acc[mt][tn][r] + bv, 0.f);
                if (OUTF32) {
                    outf[m * COUT + oc] = v;
                } else {
                    const _Float16 h = (_Float16)v;
                    outh[m * COUT + oc] = h;
                    outl[m * COUT + oc] = (_Float16)(v - (float)h);
                }
            }
        }
}

// ---------------------------------------------------------------------------
// 2x2 maxpool on dual fp16 planes, NHWC [128][32][32][64] -> [128][16][16][64]
// ---------------------------------------------------------------------------
__global__ __launch_bounds__(256)
void k_pool2h(const _Float16* __restrict__ inh, const _Float16* __restrict__ inl,
              _Float16* __restrict__ outh, _Float16* __restrict__ outl)
{
    const int g = blockIdx.x * 256 + threadIdx.x;
    const int c4 = g & 15, xo = (g >> 4) & 15, yo = (g >> 8) & 15, b = g >> 12;
    const int base = ((b * 32 + yo * 2) * 32 + xo * 2) * 64 + c4 * 4;
    const int offs[4] = {0, 64, 2048, 2112};
    float mx[4] = {-1e30f, -1e30f, -1e30f, -1e30f};
    #pragma unroll
    for (int cnd = 0; cnd < 4; ++cnd) {
        const half4_t h = *(const half4_t*)(inh + base + offs[cnd]);
        const half4_t l = *(const half4_t*)(inl + base + offs[cnd]);
        #pragma unroll
        for (int e = 0; e < 4; ++e)
            mx[e] = fmaxf(mx[e], (float)h[e] + (float)l[e]);
    }
    half4_t oh, ol;
    #pragma unroll
    for (int e = 0; e < 4; ++e) {
        const _Float16 h = (_Float16)mx[e];
        oh[e] = h;
        ol[e] = (_Float16)(mx[e] - (float)h);
    }
    const int ob = ((b * 16 + yo) * 16 + xo) * 64 + c4 * 4;
    *(half4_t*)(outh + ob) = oh;
    *(half4_t*)(outl + ob) = ol;
}

// ---------------------------------------------------------------------------
// Split-K FC partial (fp32): A[128 x K] @ B[K x 512] -> part[ky][128][512]
// ---------------------------------------------------------------------------
template<int LDA, int KCHUNK, int TN, bool PERM>
__global__ __launch_bounds__(256, 2)
void k_fc_partial(const float* __restrict__ A, const float* __restrict__ Bw,
                  float* __restrict__ part)
{
    constexpr int BN = 16 * TN;
    constexpr int SA = 140;
    constexpr int SB = (BN == 128) ? 140 : 68;
    __shared__ __align__(16) float As[32 * SA];
    __shared__ __align__(16) float Bs[32 * SB];
    const int t  = threadIdx.x;
    const int tm = t >> 4, tn = t & 15;
    const int n0 = blockIdx.x * BN;
    const int k0 = blockIdx.y * KCHUNK;

    float acc[8][TN];
    #pragma unroll
    for (int r = 0; r < 8; ++r)
        #pragma unroll
        for (int c = 0; c < TN; ++c) acc[r][c] = 0.f;

    #pragma unroll 1
    for (int ks = 0; ks < KCHUNK / 32; ++ks) {
        if (ks) __syncthreads();
        const int kb = k0 + ks * 32;
        for (int i = t; i < 4096; i += 256) {
            const int m = i >> 5, kk = i & 31;
            As[kk * SA + m + ((m >> 5) << 2)] = A[m * LDA + kb + kk];
        }
        for (int i = t; i < 32 * BN; i += 256) {
            const int kk = i / BN, n = i - kk * BN;
            const int krow = kb + kk;
            const int kref = PERM ? ((krow & 127) * 256 + (krow >> 7)) : krow;
            Bs[kk * SB + n + ((n >> 5) << 2)] = Bw[kref * 512 + n0 + n];
        }
        __syncthreads();
        #pragma unroll 2
        for (int kk = 0; kk < 32; ++kk) {
            const float* ap = &As[kk * SA + tm * 8 + ((tm >> 2) << 2)];
            const float* bp = &Bs[kk * SB + tn * TN + (((tn * TN) >> 5) << 2)];
            float a[8], bb[TN];
            #pragma unroll
            for (int q = 0; q < 8; q += 4) {
                const float4 v = *(const float4*)(ap + q);
                a[q] = v.x; a[q + 1] = v.y; a[q + 2] = v.z; a[q + 3] = v.w;
            }
            #pragma unroll
            for (int q = 0; q < TN; q += 4) {
                const float4 v = *(const float4*)(bp + q);
                bb[q] = v.x; bb[q + 1] = v.y; bb[q + 2] = v.z; bb[q + 3] = v.w;
            }
            #pragma unroll
            for (int r = 0; r < 8; ++r)
                #pragma unroll
                for (int c = 0; c < TN; ++c)
                    acc[r][c] = fmaf(a[r], bb[c], acc[r][c]);
        }
    }

    const long pb = (long)blockIdx.y * 65536;
    #pragma unroll
    for (int r = 0; r < 8; ++r)
        #pragma unroll
        for (int c = 0; c < TN; ++c)
            part[pb + (tm * 8 + r) * 512 + n0 + tn * TN + c] = acc[r][c];
}

template<int NS>
__global__ __launch_bounds__(256)
void k_fc_reduce(const float* __restrict__ part, const float* __restrict__ bias,
                 float* __restrict__ H)
{
    const int f = (blockIdx.x * 256 + threadIdx.x) * 4;
    const int m = f >> 9, n = f & 511;
    float s0 = 0.f, s1 = 0.f, s2 = 0.f, s3 = 0.f;
    #pragma unroll 4
    for (int q = 0; q < NS; ++q) {
        const float* p = &part[(q * 128 + m) * 512 + n];
        s0 += p[0]; s1 += p[1]; s2 += p[2]; s3 += p[3];
    }
    H[f]     = fmaxf(s0 + bias[n],     0.f);
    H[f + 1] = fmaxf(s1 + bias[n + 1], 0.f);
    H[f + 2] = fmaxf(s2 + bias[n + 2], 0.f);
    H[f + 3] = fmaxf(s3 + bias[n + 3], 0.f);
}

// ---------------------------------------------------------------------------
// Final: FC3 + sampling + patch gather
// ---------------------------------------------------------------------------
__device__ __forceinline__ float softplusf(float x) {
    return (x > 20.f) ? x : log1pf(expf(x));
}
__device__ __forceinline__ float sigmoidf_(float x) {
    return 1.f / (1.f + expf(-x));
}

__global__ __launch_bounds__(256)
void k_final(const float* __restrict__ H2, const float* __restrict__ wl3,
             const float* __restrict__ bl3, const float* __restrict__ noise,
             const float* __restrict__ img, float* __restrict__ outp)
{
    __shared__ float h2[512];
    __shared__ float red[144];
    __shared__ float prep[36];
    __shared__ int ptsh[12], ptsw[12];
    const int b = blockIdx.x, t = threadIdx.x;

    h2[t]       = H2[b * 512 + t];
    h2[t + 256] = H2[b * 512 + 256 + t];
    __syncthreads();

    if (t < 144) {
        const int n = t >> 2, q = t & 3;
        float s = 0.f;
        for (int k = q * 128; k < q * 128 + 128; ++k)
            s = fmaf(h2[k], wl3[k * 36 + n], s);
        red[t] = s;
    }
    __syncthreads();
    if (t < 36)
        prep[t] = red[t * 4] + red[t * 4 + 1] + red[t * 4 + 2] + red[t * 4 + 3] + bl3[t];
    __syncthreads();

    if (t < 12) {
        const float m0 = prep[t * 3], m1 = prep[t * 3 + 1], sv = prep[t * 3 + 2];
        const float sig = softplusf(sv + 2.0f) * 128.f + 1e-7f;
        const float n0 = noise[(b * 12 + t) * 2], n1 = noise[(b * 12 + t) * 2 + 1];
        const float sa0 = m0 + sig * n0;
        const float sa1 = m1 + sig * n1;
        int p0 = (int)rintf(sigmoidf_(sa0) * 111.f);
        int p1 = (int)rintf(sigmoidf_(sa1) * 111.f);
        p0 = min(max(p0, 0), 111);
        p1 = min(max(p1, 0), 111);
        const int RM = 1179648;
        outp[RM        + (b * 12 + t) * 2 + 0] = m0;
        outp[RM        + (b * 12 + t) * 2 + 1] = m1;
        outp[RM + 3072 + (b * 12 + t) * 2 + 0] = sig;
        outp[RM + 3072 + (b * 12 + t) * 2 + 1] = sig;
        outp[RM + 6144 + (b * 12 + t) * 2 + 0] = sa0;
        outp[RM + 6144 + (b * 12 + t) * 2 + 1] = sa1;
        ptsh[t] = p0;
        ptsw[t] = p1;
    }
    __syncthreads();

    for (int i = t; i < 9216; i += 256) {
        const int g  = i / 768, r = i - g * 768;
        const int c  = r >> 8, r2 = r & 255;
        const int y  = r2 >> 4, x = r2 & 15;
        outp[b * 9216 + i] = img[((b * 3 + c) * 128 + ptsh[g] + y) * 128 + (ptsw[g] + x)];
    }
}

// ---------------------------------------------------------------------------
extern "C" void kernel_launch(void* const* d_in, const int* in_sizes, int n_in,
                              void* d_out, int out_size, void* d_ws, size_t ws_size,
                              hipStream_t stream)
{
    const float* img  = (const float*)d_in[0];
    const float* nois = (const float*)d_in[1];
    const float* w1 = (const float*)d_in[2];  const float* b1 = (const float*)d_in[3];
    const float* w2 = (const float*)d_in[4];  const float* b2 = (const float*)d_in[5];
    const float* w3 = (const float*)d_in[6];  const float* b3 = (const float*)d_in[7];
    const float* w4 = (const float*)d_in[8];  const float* b4 = (const float*)d_in[9];
    const float* w5 = (const float*)d_in[10]; const float* b5 = (const float*)d_in[11];
    const float* w6 = (const float*)d_in[12]; const float* b6 = (const float*)d_in[13];
    const float* wl1 = (const float*)d_in[14]; const float* bl1 = (const float*)d_in[15];
    const float* wl2 = (const float*)d_in[16]; const float* bl2 = (const float*)d_in[17];
    const float* wl3 = (const float*)d_in[18]; const float* bl3 = (const float*)d_in[19];
    float* out = (float*)d_out;
    float* ws  = (float*)d_ws;

    // workspace (float units). Activation regions span [0 .. 20971520).
    // Weight packs live ABOVE all activations, EXCEPT the tiny w1 frag pack,
    // which sits in [17956864..17957888) -- inside A4l's range but only live
    // before conv4 writes A4l (wrepackm -> conv12 both precede conv4).
    _Float16* P1h = (_Float16*)(ws);               // [128*32*32*32] halves
    _Float16* P1l = (_Float16*)(ws + 2097152);
    _Float16* A3h = (_Float16*)(ws + 4194304);     // [128*32*32*64]
    _Float16* A3l = (_Float16*)(ws + 8388608);
    _Float16* A4h = (_Float16*)(ws + 12582912);    // [128*32*32*64]
    _Float16* A4l = (_Float16*)(ws + 16777216);    // ..20971520
    _Float16* P2h = (_Float16*)(ws);               // [128*16*16*64] (P1 dead)
    _Float16* P2l = (_Float16*)(ws + 1048576);
    _Float16* A5h = (_Float16*)(ws + 4194304);     // [128*16*16*128] (A3 dead)
    _Float16* A5l = (_Float16*)(ws + 6291456);
    float* A6  = ws + 8388608;                     // [128*16*16*128] fp32 (A3 dead)
    float* FP1 = ws + 12582912;                    // [64][128][512] (A4h dead)
    float* H1  = ws + 16777216;                    // [128][512]     (A4l dead)
    float* FP2 = ws + 16842752;                    // [16][128][512]
    float* H2  = ws + 17891328;                    // [128][512]
    _Float16* B1h = (_Float16*)(ws + 17956864);    // 1024 halves (w1 pack)
    _Float16* B1l = (_Float16*)(ws + 17957376);
    _Float16* Bh = (_Float16*)(ws + 20971520);     // 285696 halves (w2..w6)
    _Float16* Bl = (_Float16*)(ws + 21114368);     // ends 21257216 fl = 85 MB

    hipLaunchKernelGGL(k_wrepackm, dim3(1120), dim3(256), 0, stream,
                       w1, w2, w3, w4, w5, w6, Bh, Bl, B1h, B1l);

    // conv1+conv2+pool4: grid = 8x8 tiles x 128 batch
    hipLaunchKernelGGL(k_conv12, dim3(64, 128), dim3(256), 0, stream,
                       img, b1, B1h, B1l, Bh + 0, Bl + 0, b2, P1h, P1l);
    // conv3: M=131072, K=288, COUT=64
    hipLaunchKernelGGL((k_mgemm<32, 64, 32, false>), dim3(1024, 1), dim3(256), 0, stream,
                       P1h, P1l, Bh + 9216, Bl + 9216, b3, A3h, A3l, nullptr);
    // conv4: K=576
    hipLaunchKernelGGL((k_mgemm<64, 64, 32, false>), dim3(1024, 1), dim3(256), 0, stream,
                       A3h, A3l, Bh + 27648, Bl + 27648, b4, A4h, A4l, nullptr);
    hipLaunchKernelGGL(k_pool2h, dim3(2048), dim3(256), 0, stream, A4h, A4l, P2h, P2l);
    // conv5: M=32768, K=576, COUT=128
    hipLaunchKernelGGL((k_mgemm<64, 128, 16, false>), dim3(256, 2), dim3(256), 0, stream,
                       P2h, P2l, Bh + 64512, Bl + 64512, b5, A5h, A5l, nullptr);
    // conv6: K=1152, fp32 out for FC1
    hipLaunchKernelGGL((k_mgemm<128, 128, 16, true>), dim3(256, 2), dim3(256), 0, stream,
                       A5h, A5l, Bh + 138240, Bl + 138240, b6, nullptr, nullptr, A6);
    hipLaunchKernelGGL((k_fc_partial<32768, 512, 4, true>), dim3(8, 64), dim3(256), 0, stream,
                       A6, wl1, FP1);
    hipLaunchKernelGGL(k_fc_reduce<64>, dim3(64), dim3(256), 0, stream, FP1, bl1, H1);
    hipLaunchKernelGGL((k_fc_partial<512, 32, 4, false>), dim3(8, 16), dim3(256), 0, stream,
                       H1, wl2, FP2);
    hipLaunchKernelGGL(k_fc_reduce<16>, dim3(64), dim3(256), 0, stream, FP2, bl2, H2);
    hipLaunchKernelGGL(k_final, dim3(128), dim3(256), 0, stream,
                       H2, wl3, bl3, nois, img, out);
}

// Round 6
// 644.634 us; speedup vs baseline: 1.3023x; 1.0245x over previous
//
#include <hip/hip_runtime.h>
#include <math.h>

typedef _Float16 __attribute__((ext_vector_type(8))) half8_t;
typedef _Float16 __attribute__((ext_vector_type(4))) half4_t;
typedef _Float16 __attribute__((ext_vector_type(2))) half2_t;
typedef float    __attribute__((ext_vector_type(4))) float4_t;

// ---------------------------------------------------------------------------
// Kernel 1: fully-MFMA conv1 + conv2 + maxpool4 (block = 16x16 output tile).
// Phase A: img -> simg (fp32 LDS halo-2, coalesced, zero-padded) -> im2col
//   into C1[slot=k/8][pos=18*18][j=k&7] fp16 hi/lo with compile-time tap
//   offsets (slot/j unrolled => ci,dy,dx constants; no per-element bounds).
// Phase B: conv1 = GEMM M=324(pad 336), N=32, K=32 in ONE k-step:
//   21 m-tiles x 2 n-tiles x 3 split-term MFMAs.
// Phase C: epilogue overwrites C1 with conv1 output. Interior blocks
//   (1<=ty,tx<=6) take a maskless fast path. NOTE (R5 bug): the swizzled
//   index must be ((g0+r)*8)^key per element -- post-XOR +r*8 collides.
// Phase D: conv2 implicit GEMM (M=256,K=288,N=32) + thread-local 4x4 pool.
// POSP=336: multiple of 8 keeps the XOR swizzle bijective (R2 lesson).
// LDS = 6000(simg) + 43008(C1) = 47.9 KB -> 3 blocks/CU.
// ---------------------------------------------------------------------------
#define POSP 336

__device__ __forceinline__ int c1idx(int slot, int pos) {
    return ((slot * POSP + pos) * 8) ^ (((pos >> 3) & 7) << 3);
}

__global__ __launch_bounds__(256, 3)
void k_conv12(const float* __restrict__ img, const float* __restrict__ b1,
              const _Float16* __restrict__ B1h, const _Float16* __restrict__ B1l,
              const _Float16* __restrict__ B2h, const _Float16* __restrict__ B2l,
              const float* __restrict__ b2,
              _Float16* __restrict__ P1h, _Float16* __restrict__ P1l)
{
    __shared__ float simg[3 * 20 * 25];                    // input halo-2
    __shared__ __align__(16) _Float16 C1h[4 * POSP * 8];   // A, then conv1 out
    __shared__ __align__(16) _Float16 C1l[4 * POSP * 8];

    const int t  = threadIdx.x;
    const int bt = blockIdx.x;
    const int b  = blockIdx.y;
    const int ty = bt >> 3, tx = bt & 7;
    const int oy = ty * 16, ox = tx * 16;

    // ---- Phase A1: stage fp32 halo (bounds-checked ONCE, zero-padded) ----
    for (int i = t; i < 1500; i += 256) {
        const int ci = i / 500, r = i - ci * 500;
        const int yy = r / 25, xx = r - yy * 25;
        const int gy = oy - 2 + yy, gx = ox - 2 + xx;
        float v = 0.f;
        if ((unsigned)gy < 128u && (unsigned)gx < 128u)
            v = img[((b * 3 + ci) * 128 + gy) * 128 + gx];
        simg[i] = v;
    }
    __syncthreads();

    // ---- Phase A2: im2col simg -> C1 (compile-time tap offsets) ----
    #pragma unroll
    for (int hf = 0; hf < 2; ++hf) {
        const int pos = hf * 256 + t;
        if (pos < POSP) {
            const bool val = pos < 324;
            int sb = 0;
            if (val) {
                const int py = pos / 18, px = pos - py * 18;
                sb = py * 25 + px;
            }
            #pragma unroll
            for (int s = 0; s < 4; ++s) {
                half8_t vh = {0,0,0,0,0,0,0,0}, vl = {0,0,0,0,0,0,0,0};
                if (val) {
                    #pragma unroll
                    for (int j = 0; j < 8; ++j) {
                        const int k = s * 8 + j;
                        if (k < 27) {
                            const int ci = k / 9, tap = k - ci * 9;   // const
                            const int dy = tap / 3, dx = tap - dy * 3; // const
                            const float v = simg[sb + (ci * 20 + dy) * 25 + dx];
                            const _Float16 h = (_Float16)v;
                            vh[j] = h;
                            vl[j] = (_Float16)(v - (float)h);
                        }
                    }
                }
                const int wi = c1idx(s, pos);
                *(half8_t*)(&C1h[wi]) = vh;
                *(half8_t*)(&C1l[wi]) = vl;
            }
        }
    }
    __syncthreads();

    const int wv   = __builtin_amdgcn_readfirstlane(t >> 6);
    const int lane = t & 63;
    const int fr   = lane >> 4;
    const int ml   = lane & 15;

    // ---- Phase B: conv1 MFMA (K=32 in one step; 3-term fp16 split) ----
    half8_t w1h[2], w1l[2];
    #pragma unroll
    for (int nt = 0; nt < 2; ++nt) {
        w1h[nt] = *(const half8_t*)(B1h + (nt * 64 + lane) * 8);
        w1l[nt] = *(const half8_t*)(B1l + (nt * 64 + lane) * 8);
    }
    float4_t acc1[6][2];
    #pragma unroll
    for (int q = 0; q < 6; ++q)
        #pragma unroll
        for (int nt = 0; nt < 2; ++nt)
            acc1[q][nt] = (float4_t){0.f, 0.f, 0.f, 0.f};

    #pragma unroll
    for (int q = 0; q < 6; ++q) {
        const int mt = wv + q * 4;
        if (mt < 21) {
            const int ri = c1idx(fr, mt * 16 + ml);
            const half8_t ah = *(const half8_t*)(&C1h[ri]);
            const half8_t al = *(const half8_t*)(&C1l[ri]);
            #pragma unroll
            for (int nt = 0; nt < 2; ++nt) {
                acc1[q][nt] = __builtin_amdgcn_mfma_f32_16x16x32_f16(ah, w1h[nt], acc1[q][nt], 0, 0, 0);
                acc1[q][nt] = __builtin_amdgcn_mfma_f32_16x16x32_f16(al, w1h[nt], acc1[q][nt], 0, 0, 0);
                acc1[q][nt] = __builtin_amdgcn_mfma_f32_16x16x32_f16(ah, w1l[nt], acc1[q][nt], 0, 0, 0);
            }
        }
    }
    __syncthreads();          // all A reads done; buffer reusable

    // ---- Phase C: conv1 epilogue -> overwrite C1 with conv1 output ----
    // D-frag: ch(n)=nt*16+ml, pos(m)=mt*16+fr*4+r.
    const bool interior = ((unsigned)(ty - 1) < 6u) && ((unsigned)(tx - 1) < 6u);
    if (interior) {
        // all halo-1 positions in-image: no masking, no pos->(py,px) div.
        // Swizzled index computed per element: ((g0+r)*8)^key  (R5 fix).
        #pragma unroll
        for (int q = 0; q < 6; ++q) {
            const int mt = wv + q * 4;
            if (mt < 21) {
                const int pos0 = mt * 16 + fr * 4;
                const int key  = ((pos0 >> 3) & 7) << 3;   // const across r<4
                #pragma unroll
                for (int nt = 0; nt < 2; ++nt) {
                    const int ch  = nt * 16 + ml;
                    const float bb = b1[ch];
                    const int g0  = (ch >> 3) * POSP + pos0;
                    #pragma unroll
                    for (int r = 0; r < 4; ++r) {
                        if (pos0 + r < 324) {
                            const float v = fmaxf(acc1[q][nt][r] + bb, 0.f);
                            const int wi = (((g0 + r) * 8) ^ key) + (ch & 7);
                            const _Float16 h = (_Float16)v;
                            C1h[wi] = h;
                            C1l[wi] = (_Float16)(v - (float)h);
                        }
                    }
                }
            }
        }
    } else {
        #pragma unroll
        for (int q = 0; q < 6; ++q) {
            const int mt = wv + q * 4;
            if (mt < 21) {
                #pragma unroll
                for (int nt = 0; nt < 2; ++nt) {
                    const int ch  = nt * 16 + ml;
                    const float bb = b1[ch];
                    #pragma unroll
                    for (int r = 0; r < 4; ++r) {
                        const int pos = mt * 16 + fr * 4 + r;
                        if (pos < 324) {
                            const int py = pos / 18, px = pos - py * 18;
                            const int gy = oy + py - 1, gx = ox + px - 1;
                            float v = 0.f;
                            if ((unsigned)gy < 128u && (unsigned)gx < 128u)
                                v = fmaxf(acc1[q][nt][r] + bb, 0.f);
                            const int wi = c1idx(ch >> 3, pos) + (ch & 7);
                            const _Float16 h = (_Float16)v;
                            C1h[wi] = h;
                            C1l[wi] = (_Float16)(v - (float)h);
                        }
                    }
                }
            }
        }
    }
    __syncthreads();

    // ---- Phase D: conv2 implicit-GEMM, wave wv owns out rows wv*4..wv*4+3 --
    float4_t acc[4][2];
    #pragma unroll
    for (int i = 0; i < 4; ++i)
        #pragma unroll
        for (int nt = 0; nt < 2; ++nt)
            acc[i][nt] = (float4_t){0.f, 0.f, 0.f, 0.f};

    #pragma unroll 1
    for (int tap = 0; tap < 9; ++tap) {
        const int dy = tap / 3, dx = tap - dy * 3;
        half8_t bh[2], bl[2];
        #pragma unroll
        for (int nt = 0; nt < 2; ++nt) {
            const int bo = ((tap * 2 + nt) * 64 + lane) * 8;
            bh[nt] = *(const half8_t*)(B2h + bo);
            bl[nt] = *(const half8_t*)(B2l + bo);
        }
        half8_t ah[4], al[4];
        #pragma unroll
        for (int i = 0; i < 4; ++i) {
            const int pos = (wv * 4 + i + dy) * 18 + ml + dx;
            const int ri  = c1idx(fr, pos);
            ah[i] = *(const half8_t*)(&C1h[ri]);
            al[i] = *(const half8_t*)(&C1l[ri]);
        }
        #pragma unroll
        for (int nt = 0; nt < 2; ++nt)
            #pragma unroll
            for (int i = 0; i < 4; ++i)
                acc[i][nt] = __builtin_amdgcn_mfma_f32_16x16x32_f16(ah[i], bh[nt], acc[i][nt], 0, 0, 0);
        #pragma unroll
        for (int nt = 0; nt < 2; ++nt)
            #pragma unroll
            for (int i = 0; i < 4; ++i)
                acc[i][nt] = __builtin_amdgcn_mfma_f32_16x16x32_f16(al[i], bh[nt], acc[i][nt], 0, 0, 0);
        #pragma unroll
        for (int nt = 0; nt < 2; ++nt)
            #pragma unroll
            for (int i = 0; i < 4; ++i)
                acc[i][nt] = __builtin_amdgcn_mfma_f32_16x16x32_f16(ah[i], bl[nt], acc[i][nt], 0, 0, 0);
    }

    // ---- maxpool4 (thread-local) + bias + relu + hi/lo store ----
    const int py = ty * 4 + wv;
    const int px = tx * 4 + fr;
    #pragma unroll
    for (int nt = 0; nt < 2; ++nt) {
        float m = -1e30f;
        #pragma unroll
        for (int i = 0; i < 4; ++i)
            #pragma unroll
            for (int r = 0; r < 4; ++r)
                m = fmaxf(m, acc[i][nt][r]);
        const int oc = nt * 16 + ml;
        const float v = fmaxf(m + b2[oc], 0.f);
        const _Float16 h = (_Float16)v;
        const int base = ((b * 32 + py) * 32 + px) * 32 + oc;
        P1h[base] = h;
        P1l[base] = (_Float16)(v - (float)h);
    }
}

// ---------------------------------------------------------------------------
// Weight repack: fp16 hi/lo MFMA-fragment packs for w2..w6 (+ w1, K padded
// 27->32). Frag order: Bh[((c*NT + ntg)*64 + lane)*8 + j], element B[k][n]:
//   n = ntg*16 + (lane&15), k = c*32 + (lane>>4)*8 + j.
// w2..w6: k = tap*CIN + ci.  w1: k = ci*9 + tap (= w1 natural order).
// ---------------------------------------------------------------------------
__global__ void k_wrepackm(const float* __restrict__ w1, const float* __restrict__ w2,
                           const float* __restrict__ w3, const float* __restrict__ w4,
                           const float* __restrict__ w5, const float* __restrict__ w6,
                           _Float16* __restrict__ Bh, _Float16* __restrict__ Bl,
                           _Float16* __restrict__ B1h, _Float16* __restrict__ B1l)
{
    int idx = blockIdx.x * 256 + threadIdx.x;
    if (idx >= 285696) {
        const int i = idx - 285696;
        if (i >= 1024) return;
        const int ntg = i >> 9, rr = i & 511;
        const int lane = rr >> 3, j = rr & 7;
        const int k = (lane >> 4) * 8 + j;
        const int n = ntg * 16 + (lane & 15);
        const float v = (k < 27) ? w1[n * 27 + k] : 0.f;
        const _Float16 h = (_Float16)v;
        B1h[i] = h;
        B1l[i] = (_Float16)(v - (float)h);
        return;
    }
    const float* w; int CIN, COUT, off;
    if (idx < 9216)        { w = w2; CIN = 32;  COUT = 32;  off = 0; }
    else if (idx < 27648)  { idx -= 9216;   w = w3; CIN = 32;  COUT = 64;  off = 9216; }
    else if (idx < 64512)  { idx -= 27648;  w = w4; CIN = 64;  COUT = 64;  off = 27648; }
    else if (idx < 138240) { idx -= 64512;  w = w5; CIN = 64;  COUT = 128; off = 64512; }
    else                   { idx -= 138240; w = w6; CIN = 128; COUT = 128; off = 138240; }
    const int NT  = COUT / 16;
    const int c   = idx / (NT * 512);
    const int r   = idx - c * NT * 512;
    const int ntg = r >> 9;
    const int rr  = r & 511;
    const int lane = rr >> 3, j = rr & 7;
    const int k   = c * 32 + (lane >> 4) * 8 + j;
    const int tap = k / CIN, ci = k - tap * CIN;
    const int oc  = ntg * 16 + (lane & 15);
    const float v = w[(oc * CIN + ci) * 9 + tap];
    const _Float16 h = (_Float16)v;
    Bh[off + idx] = h;
    Bl[off + idx] = (_Float16)(v - (float)h);
}

// ---------------------------------------------------------------------------
// MFMA implicit-GEMM conv3x3, fp16x3 split (fp32-class: ll term <= 2^-22 rel).
// BM=128, BN=64 per block; 4 waves, wave = 2 m-tiles x 4 n-tiles.
// ---------------------------------------------------------------------------
template<int CIN, int COUT, int HW, bool OUTF32>
__global__ __launch_bounds__(256, 2)
void k_mgemm(const _Float16* __restrict__ inh, const _Float16* __restrict__ inl,
             const _Float16* __restrict__ Bh, const _Float16* __restrict__ Bl,
             const float* __restrict__ bias,
             _Float16* __restrict__ outh, _Float16* __restrict__ outl,
             float* __restrict__ outf)
{
    constexpr int NCH = CIN * 9 / 32;
    constexpr int NT  = COUT / 16;
    constexpr int LOG = (HW == 32) ? 5 : 4;
    constexpr int PS  = 40;
    __shared__ _Float16 Ash[128 * PS];
    __shared__ _Float16 Asl[128 * PS];

    const int t    = threadIdx.x;
    const int wv   = t >> 6;
    const int lane = t & 63;
    const int m0   = blockIdx.x * 128;
    const int nb   = blockIdx.y;

    int sm[2], sg[2], sb[2], sy[2], sx[2];
    #pragma unroll
    for (int j = 0; j < 2; ++j) {
        const int q = t + 256 * j;
        sm[j] = q >> 2;
        sg[j] = q & 3;
        const int m  = m0 + sm[j];
        const int yx = m & (HW * HW - 1);
        sb[j] = m >> (2 * LOG);
        sy[j] = yx >> LOG;
        sx[j] = yx & (HW - 1);
    }

    const int mt0 = wv * 2;
    const int fr  = lane >> 4;
    const int ml  = lane & 15;

    float4_t acc[2][4];
    #pragma unroll
    for (int mt = 0; mt < 2; ++mt)
        #pragma unroll
        for (int tn = 0; tn < 4; ++tn)
            acc[mt][tn] = (float4_t){0.f, 0.f, 0.f, 0.f};

    #pragma unroll 1
    for (int ch = 0; ch < NCH; ++ch) {
        const int kb  = ch * 32;
        const int tap = kb / CIN;
        const int c0  = kb - tap * CIN;
        const int dy  = tap / 3 - 1, dx = tap - (tap / 3) * 3 - 1;

        if (ch) __syncthreads();
        #pragma unroll
        for (int j = 0; j < 2; ++j) {
            const int iy = sy[j] + dy, ix = sx[j] + dx;
            half8_t vh = {0, 0, 0, 0, 0, 0, 0, 0};
            half8_t vl = {0, 0, 0, 0, 0, 0, 0, 0};
            if ((unsigned)iy < (unsigned)HW && (unsigned)ix < (unsigned)HW) {
                const int o = ((sb[j] * HW + iy) * HW + ix) * CIN + c0 + sg[j] * 8;
                vh = *(const half8_t*)(inh + o);
                vl = *(const half8_t*)(inl + o);
            }
            *(half8_t*)(&Ash[sm[j] * PS + sg[j] * 8]) = vh;
            *(half8_t*)(&Asl[sm[j] * PS + sg[j] * 8]) = vl;
        }
        __syncthreads();

        half8_t ah[2], al[2];
        #pragma unroll
        for (int mt = 0; mt < 2; ++mt) {
            const int mr = (mt0 + mt) * 16 + ml;
            ah[mt] = *(const half8_t*)(&Ash[mr * PS + fr * 8]);
            al[mt] = *(const half8_t*)(&Asl[mr * PS + fr * 8]);
        }
        half8_t bh[4], bl[4];
        #pragma unroll
        for (int tn = 0; tn < 4; ++tn) {
            const int bo = ((ch * NT + nb * 4 + tn) * 64 + lane) * 8;
            bh[tn] = *(const half8_t*)(Bh + bo);
            bl[tn] = *(const half8_t*)(Bl + bo);
        }
        #pragma unroll
        for (int tn = 0; tn < 4; ++tn)
            #pragma unroll
            for (int mt = 0; mt < 2; ++mt)
                acc[mt][tn] = __builtin_amdgcn_mfma_f32_16x16x32_f16(ah[mt], bh[tn], acc[mt][tn], 0, 0, 0);
        #pragma unroll
        for (int tn = 0; tn < 4; ++tn)
            #pragma unroll
            for (int mt = 0; mt < 2; ++mt)
                acc[mt][tn] = __builtin_amdgcn_mfma_f32_16x16x32_f16(al[mt], bh[tn], acc[mt][tn], 0, 0, 0);
        #pragma unroll
        for (int tn = 0; tn < 4; ++tn)
            #pragma unroll
            for (int mt = 0; mt < 2; ++mt)
                acc[mt][tn] = __builtin_amdgcn_mfma_f32_16x16x32_f16(ah[mt], bl[tn], acc[mt][tn], 0, 0, 0);
        // (al,bl) term dropped: <= 2^-22 relative contribution.
    }

    // epilogue: C/D frag col=lane&15, row=(lane>>4)*4+reg  [guide m89/m91]
    #pragma unroll
    for (int mt = 0; mt < 2; ++mt)
        #pragma unroll
        for (int tn = 0; tn < 4; ++tn) {
            const int oc = nb * 64 + tn * 16 + ml;
            const float bv = bias[oc];
            #pragma unroll
            for (int r = 0; r < 4; ++r) {
                const int m = m0 + (mt0 + mt) * 16 + fr * 4 + r;
                const float v = fmaxf(acc[mt][tn][r] + bv, 0.f);
                if (OUTF32) {
                    outf[m * COUT + oc] = v;
                } else {
                    const _Float16 h = (_Float16)v;
                    outh[m * COUT + oc] = h;
                    outl[m * COUT + oc] = (_Float16)(v - (float)h);
                }
            }
        }
}

// ---------------------------------------------------------------------------
// 2x2 maxpool on dual fp16 planes, NHWC [128][32][32][64] -> [128][16][16][64]
// ---------------------------------------------------------------------------
__global__ __launch_bounds__(256)
void k_pool2h(const _Float16* __restrict__ inh, const _Float16* __restrict__ inl,
              _Float16* __restrict__ outh, _Float16* __restrict__ outl)
{
    const int g = blockIdx.x * 256 + threadIdx.x;
    const int c4 = g & 15, xo = (g >> 4) & 15, yo = (g >> 8) & 15, b = g >> 12;
    const int base = ((b * 32 + yo * 2) * 32 + xo * 2) * 64 + c4 * 4;
    const int offs[4] = {0, 64, 2048, 2112};
    float mx[4] = {-1e30f, -1e30f, -1e30f, -1e30f};
    #pragma unroll
    for (int cnd = 0; cnd < 4; ++cnd) {
        const half4_t h = *(const half4_t*)(inh + base + offs[cnd]);
        const half4_t l = *(const half4_t*)(inl + base + offs[cnd]);
        #pragma unroll
        for (int e = 0; e < 4; ++e)
            mx[e] = fmaxf(mx[e], (float)h[e] + (float)l[e]);
    }
    half4_t oh, ol;
    #pragma unroll
    for (int e = 0; e < 4; ++e) {
        const _Float16 h = (_Float16)mx[e];
        oh[e] = h;
        ol[e] = (_Float16)(mx[e] - (float)h);
    }
    const int ob = ((b * 16 + yo) * 16 + xo) * 64 + c4 * 4;
    *(half4_t*)(outh + ob) = oh;
    *(half4_t*)(outl + ob) = ol;
}

// ---------------------------------------------------------------------------
// Split-K FC partial (fp32): A[128 x K] @ B[K x 512] -> part[ky][128][512]
// ---------------------------------------------------------------------------
template<int LDA, int KCHUNK, int TN, bool PERM>
__global__ __launch_bounds__(256, 2)
void k_fc_partial(const float* __restrict__ A, const float* __restrict__ Bw,
                  float* __restrict__ part)
{
    constexpr int BN = 16 * TN;
    constexpr int SA = 140;
    constexpr int SB = (BN == 128) ? 140 : 68;
    __shared__ __align__(16) float As[32 * SA];
    __shared__ __align__(16) float Bs[32 * SB];
    const int t  = threadIdx.x;
    const int tm = t >> 4, tn = t & 15;
    const int n0 = blockIdx.x * BN;
    const int k0 = blockIdx.y * KCHUNK;

    float acc[8][TN];
    #pragma unroll
    for (int r = 0; r < 8; ++r)
        #pragma unroll
        for (int c = 0; c < TN; ++c) acc[r][c] = 0.f;

    #pragma unroll 1
    for (int ks = 0; ks < KCHUNK / 32; ++ks) {
        if (ks) __syncthreads();
        const int kb = k0 + ks * 32;
        for (int i = t; i < 4096; i += 256) {
            const int m = i >> 5, kk = i & 31;
            As[kk * SA + m + ((m >> 5) << 2)] = A[m * LDA + kb + kk];
        }
        for (int i = t; i < 32 * BN; i += 256) {
            const int kk = i / BN, n = i - kk * BN;
            const int krow = kb + kk;
            const int kref = PERM ? ((krow & 127) * 256 + (krow >> 7)) : krow;
            Bs[kk * SB + n + ((n >> 5) << 2)] = Bw[kref * 512 + n0 + n];
        }
        __syncthreads();
        #pragma unroll 2
        for (int kk = 0; kk < 32; ++kk) {
            const float* ap = &As[kk * SA + tm * 8 + ((tm >> 2) << 2)];
            const float* bp = &Bs[kk * SB + tn * TN + (((tn * TN) >> 5) << 2)];
            float a[8], bb[TN];
            #pragma unroll
            for (int q = 0; q < 8; q += 4) {
                const float4 v = *(const float4*)(ap + q);
                a[q] = v.x; a[q + 1] = v.y; a[q + 2] = v.z; a[q + 3] = v.w;
            }
            #pragma unroll
            for (int q = 0; q < TN; q += 4) {
                const float4 v = *(const float4*)(bp + q);
                bb[q] = v.x; bb[q + 1] = v.y; bb[q + 2] = v.z; bb[q + 3] = v.w;
            }
            #pragma unroll
            for (int r = 0; r < 8; ++r)
                #pragma unroll
                for (int c = 0; c < TN; ++c)
                    acc[r][c] = fmaf(a[r], bb[c], acc[r][c]);
        }
    }

    const long pb = (long)blockIdx.y * 65536;
    #pragma unroll
    for (int r = 0; r < 8; ++r)
        #pragma unroll
        for (int c = 0; c < TN; ++c)
            part[pb + (tm * 8 + r) * 512 + n0 + tn * TN + c] = acc[r][c];
}

template<int NS>
__global__ __launch_bounds__(256)
void k_fc_reduce(const float* __restrict__ part, const float* __restrict__ bias,
                 float* __restrict__ H)
{
    const int f = (blockIdx.x * 256 + threadIdx.x) * 4;
    const int m = f >> 9, n = f & 511;
    float s0 = 0.f, s1 = 0.f, s2 = 0.f, s3 = 0.f;
    #pragma unroll 4
    for (int q = 0; q < NS; ++q) {
        const float* p = &part[(q * 128 + m) * 512 + n];
        s0 += p[0]; s1 += p[1]; s2 += p[2]; s3 += p[3];
    }
    H[f]     = fmaxf(s0 + bias[n],     0.f);
    H[f + 1] = fmaxf(s1 + bias[n + 1], 0.f);
    H[f + 2] = fmaxf(s2 + bias[n + 2], 0.f);
    H[f + 3] = fmaxf(s3 + bias[n + 3], 0.f);
}

// ---------------------------------------------------------------------------
// Final: FC3 + sampling + patch gather
// ---------------------------------------------------------------------------
__device__ __forceinline__ float softplusf(float x) {
    return (x > 20.f) ? x : log1pf(expf(x));
}
__device__ __forceinline__ float sigmoidf_(float x) {
    return 1.f / (1.f + expf(-x));
}

__global__ __launch_bounds__(256)
void k_final(const float* __restrict__ H2, const float* __restrict__ wl3,
             const float* __restrict__ bl3, const float* __restrict__ noise,
             const float* __restrict__ img, float* __restrict__ outp)
{
    __shared__ float h2[512];
    __shared__ float red[144];
    __shared__ float prep[36];
    __shared__ int ptsh[12], ptsw[12];
    const int b = blockIdx.x, t = threadIdx.x;

    h2[t]       = H2[b * 512 + t];
    h2[t + 256] = H2[b * 512 + 256 + t];
    __syncthreads();

    if (t < 144) {
        const int n = t >> 2, q = t & 3;
        float s = 0.f;
        for (int k = q * 128; k < q * 128 + 128; ++k)
            s = fmaf(h2[k], wl3[k * 36 + n], s);
        red[t] = s;
    }
    __syncthreads();
    if (t < 36)
        prep[t] = red[t * 4] + red[t * 4 + 1] + red[t * 4 + 2] + red[t * 4 + 3] + bl3[t];
    __syncthreads();

    if (t < 12) {
        const float m0 = prep[t * 3], m1 = prep[t * 3 + 1], sv = prep[t * 3 + 2];
        const float sig = softplusf(sv + 2.0f) * 128.f + 1e-7f;
        const float n0 = noise[(b * 12 + t) * 2], n1 = noise[(b * 12 + t) * 2 + 1];
        const float sa0 = m0 + sig * n0;
        const float sa1 = m1 + sig * n1;
        int p0 = (int)rintf(sigmoidf_(sa0) * 111.f);
        int p1 = (int)rintf(sigmoidf_(sa1) * 111.f);
        p0 = min(max(p0, 0), 111);
        p1 = min(max(p1, 0), 111);
        const int RM = 1179648;
        outp[RM        + (b * 12 + t) * 2 + 0] = m0;
        outp[RM        + (b * 12 + t) * 2 + 1] = m1;
        outp[RM + 3072 + (b * 12 + t) * 2 + 0] = sig;
        outp[RM + 3072 + (b * 12 + t) * 2 + 1] = sig;
        outp[RM + 6144 + (b * 12 + t) * 2 + 0] = sa0;
        outp[RM + 6144 + (b * 12 + t) * 2 + 1] = sa1;
        ptsh[t] = p0;
        ptsw[t] = p1;
    }
    __syncthreads();

    for (int i = t; i < 9216; i += 256) {
        const int g  = i / 768, r = i - g * 768;
        const int c  = r >> 8, r2 = r & 255;
        const int y  = r2 >> 4, x = r2 & 15;
        outp[b * 9216 + i] = img[((b * 3 + c) * 128 + ptsh[g] + y) * 128 + (ptsw[g] + x)];
    }
}

// ---------------------------------------------------------------------------
extern "C" void kernel_launch(void* const* d_in, const int* in_sizes, int n_in,
                              void* d_out, int out_size, void* d_ws, size_t ws_size,
                              hipStream_t stream)
{
    const float* img  = (const float*)d_in[0];
    const float* nois = (const float*)d_in[1];
    const float* w1 = (const float*)d_in[2];  const float* b1 = (const float*)d_in[3];
    const float* w2 = (const float*)d_in[4];  const float* b2 = (const float*)d_in[5];
    const float* w3 = (const float*)d_in[6];  const float* b3 = (const float*)d_in[7];
    const float* w4 = (const float*)d_in[8];  const float* b4 = (const float*)d_in[9];
    const float* w5 = (const float*)d_in[10]; const float* b5 = (const float*)d_in[11];
    const float* w6 = (const float*)d_in[12]; const float* b6 = (const float*)d_in[13];
    const float* wl1 = (const float*)d_in[14]; const float* bl1 = (const float*)d_in[15];
    const float* wl2 = (const float*)d_in[16]; const float* bl2 = (const float*)d_in[17];
    const float* wl3 = (const float*)d_in[18]; const float* bl3 = (const float*)d_in[19];
    float* out = (float*)d_out;
    float* ws  = (float*)d_ws;

    // workspace (float units). Activation regions span [0 .. 20971520).
    // Weight packs live ABOVE all activations, EXCEPT the tiny w1 frag pack,
    // which sits in [17956864..17957888) -- inside A4l's range but only live
    // before conv4 writes A4l (wrepackm -> conv12 both precede conv4).
    _Float16* P1h = (_Float16*)(ws);               // [128*32*32*32] halves
    _Float16* P1l = (_Float16*)(ws + 2097152);
    _Float16* A3h = (_Float16*)(ws + 4194304);     // [128*32*32*64]
    _Float16* A3l = (_Float16*)(ws + 8388608);
    _Float16* A4h = (_Float16*)(ws + 12582912);    // [128*32*32*64]
    _Float16* A4l = (_Float16*)(ws + 16777216);    // ..20971520
    _Float16* P2h = (_Float16*)(ws);               // [128*16*16*64] (P1 dead)
    _Float16* P2l = (_Float16*)(ws + 1048576);
    _Float16* A5h = (_Float16*)(ws + 4194304);     // [128*16*16*128] (A3 dead)
    _Float16* A5l = (_Float16*)(ws + 6291456);
    float* A6  = ws + 8388608;                     // [128*16*16*128] fp32 (A3 dead)
    float* FP1 = ws + 12582912;                    // [64][128][512] (A4h dead)
    float* H1  = ws + 16777216;                    // [128][512]     (A4l dead)
    float* FP2 = ws + 16842752;                    // [16][128][512]
    float* H2  = ws + 17891328;                    // [128][512]
    _Float16* B1h = (_Float16*)(ws + 17956864);    // 1024 halves (w1 pack)
    _Float16* B1l = (_Float16*)(ws + 17957376);
    _Float16* Bh = (_Float16*)(ws + 20971520);     // 285696 halves (w2..w6)
    _Float16* Bl = (_Float16*)(ws + 21114368);     // ends 21257216 fl = 85 MB

    hipLaunchKernelGGL(k_wrepackm, dim3(1120), dim3(256), 0, stream,
                       w1, w2, w3, w4, w5, w6, Bh, Bl, B1h, B1l);

    // conv1+conv2+pool4: grid = 8x8 tiles x 128 batch
    hipLaunchKernelGGL(k_conv12, dim3(64, 128), dim3(256), 0, stream,
                       img, b1, B1h, B1l, Bh + 0, Bl + 0, b2, P1h, P1l);
    // conv3: M=131072, K=288, COUT=64
    hipLaunchKernelGGL((k_mgemm<32, 64, 32, false>), dim3(1024, 1), dim3(256), 0, stream,
                       P1h, P1l, Bh + 9216, Bl + 9216, b3, A3h, A3l, nullptr);
    // conv4: K=576
    hipLaunchKernelGGL((k_mgemm<64, 64, 32, false>), dim3(1024, 1), dim3(256), 0, stream,
                       A3h, A3l, Bh + 27648, Bl + 27648, b4, A4h, A4l, nullptr);
    hipLaunchKernelGGL(k_pool2h, dim3(2048), dim3(256), 0, stream, A4h, A4l, P2h, P2l);
    // conv5: M=32768, K=576, COUT=128
    hipLaunchKernelGGL((k_mgemm<64, 128, 16, false>), dim3(256, 2), dim3(256), 0, stream,
                       P2h, P2l, Bh + 64512, Bl + 64512, b5, A5h, A5l, nullptr);
    // conv6: K=1152, fp32 out for FC1
    hipLaunchKernelGGL((k_mgemm<128, 128, 16, true>), dim3(256, 2), dim3(256), 0, stream,
                       A5h, A5l, Bh + 138240, Bl + 138240, b6, nullptr, nullptr, A6);
    hipLaunchKernelGGL((k_fc_partial<32768, 512, 4, true>), dim3(8, 64), dim3(256), 0, stream,
                       A6, wl1, FP1);
    hipLaunchKernelGGL(k_fc_reduce<64>, dim3(64), dim3(256), 0, stream, FP1, bl1, H1);
    hipLaunchKernelGGL((k_fc_partial<512, 32, 4, false>), dim3(8, 16), dim3(256), 0, stream,
                       H1, wl2, FP2);
    hipLaunchKernelGGL(k_fc_reduce<16>, dim3(64), dim3(256), 0, stream, FP2, bl2, H2);
    hipLaunchKernelGGL(k_final, dim3(128), dim3(256), 0, stream,
                       H2, wl3, bl3, nois, img, out);
}

// Round 7
// 607.875 us; speedup vs baseline: 1.3811x; 1.0605x over previous
//
#include <hip/hip_runtime.h>
#include <math.h>

typedef _Float16 __attribute__((ext_vector_type(8))) half8_t;
typedef _Float16 __attribute__((ext_vector_type(4))) half4_t;
typedef _Float16 __attribute__((ext_vector_type(2))) half2_t;
typedef float    __attribute__((ext_vector_type(4))) float4_t;

// ---------------------------------------------------------------------------
// Kernel 1: fully-MFMA conv1 + conv2 + maxpool4 (block = 16x16 output tile).
// Phase A: img -> simg (fp32 LDS halo-2) -> im2col into
//   C1[slot=k/8][pos=18*18][j=k&7] fp16 hi/lo, compile-time tap offsets.
// Phase B: conv1 GEMM TRANSPOSED (R7): M=32 ch, N=324 pos (21 n-tiles),
//   K=32. A = w1 frag pack (same bytes as before under A-frag mapping),
//   B = im2col data (read = old A-frag read). D-frag then gives each
//   thread 4 CONSECUTIVE ch at ONE pos.
// Phase C: epilogue -> C1 overwrite with half4 stores (4 ch contiguous in
//   j), ONE pos->(py,px)/bounds mask per q (shared by 8 ch) - no dual path.
// Phase D: conv2 implicit GEMM (M=256,K=288,N=32) + thread-local 4x4 pool.
// POSP=336: multiple of 8 keeps the XOR swizzle bijective (R2 lesson).
// Swizzled idx per element: ((g)*8)^key computed per (slot,pos) (R5 lesson).
// LDS = 6000(simg) + 43008(C1) = 47.9 KB -> 3 blocks/CU.
// ---------------------------------------------------------------------------
#define POSP 336

__device__ __forceinline__ int c1idx(int slot, int pos) {
    return ((slot * POSP + pos) * 8) ^ (((pos >> 3) & 7) << 3);
}

__global__ __launch_bounds__(256, 3)
void k_conv12(const float* __restrict__ img, const float* __restrict__ b1,
              const _Float16* __restrict__ B1h, const _Float16* __restrict__ B1l,
              const _Float16* __restrict__ B2h, const _Float16* __restrict__ B2l,
              const float* __restrict__ b2,
              _Float16* __restrict__ P1h, _Float16* __restrict__ P1l)
{
    __shared__ float simg[3 * 20 * 25];                    // input halo-2
    __shared__ __align__(16) _Float16 C1h[4 * POSP * 8];   // A, then conv1 out
    __shared__ __align__(16) _Float16 C1l[4 * POSP * 8];

    const int t  = threadIdx.x;
    const int bt = blockIdx.x;
    const int b  = blockIdx.y;
    const int ty = bt >> 3, tx = bt & 7;
    const int oy = ty * 16, ox = tx * 16;

    // ---- Phase A1: stage fp32 halo (bounds-checked ONCE, zero-padded) ----
    for (int i = t; i < 1500; i += 256) {
        const int ci = i / 500, r = i - ci * 500;
        const int yy = r / 25, xx = r - yy * 25;
        const int gy = oy - 2 + yy, gx = ox - 2 + xx;
        float v = 0.f;
        if ((unsigned)gy < 128u && (unsigned)gx < 128u)
            v = img[((b * 3 + ci) * 128 + gy) * 128 + gx];
        simg[i] = v;
    }
    __syncthreads();

    // ---- Phase A2: im2col simg -> C1 (compile-time tap offsets) ----
    #pragma unroll
    for (int hf = 0; hf < 2; ++hf) {
        const int pos = hf * 256 + t;
        if (pos < POSP) {
            const bool val = pos < 324;
            int sb = 0;
            if (val) {
                const int py = pos / 18, px = pos - py * 18;
                sb = py * 25 + px;
            }
            #pragma unroll
            for (int s = 0; s < 4; ++s) {
                half8_t vh = {0,0,0,0,0,0,0,0}, vl = {0,0,0,0,0,0,0,0};
                if (val) {
                    #pragma unroll
                    for (int j = 0; j < 8; ++j) {
                        const int k = s * 8 + j;
                        if (k < 27) {
                            const int ci = k / 9, tap = k - ci * 9;   // const
                            const int dy = tap / 3, dx = tap - dy * 3; // const
                            const float v = simg[sb + (ci * 20 + dy) * 25 + dx];
                            const _Float16 h = (_Float16)v;
                            vh[j] = h;
                            vl[j] = (_Float16)(v - (float)h);
                        }
                    }
                }
                const int wi = c1idx(s, pos);
                *(half8_t*)(&C1h[wi]) = vh;
                *(half8_t*)(&C1l[wi]) = vl;
            }
        }
    }
    __syncthreads();

    const int wv   = __builtin_amdgcn_readfirstlane(t >> 6);
    const int lane = t & 63;
    const int fr   = lane >> 4;
    const int ml   = lane & 15;

    // ---- Phase B: conv1 MFMA, transposed: D[ch][pos] = w1 @ im2col ----
    half8_t wAh[2], wAl[2];
    #pragma unroll
    for (int mt = 0; mt < 2; ++mt) {
        wAh[mt] = *(const half8_t*)(B1h + (mt * 64 + lane) * 8);
        wAl[mt] = *(const half8_t*)(B1l + (mt * 64 + lane) * 8);
    }
    float4_t acc1[6][2];
    #pragma unroll
    for (int q = 0; q < 6; ++q)
        #pragma unroll
        for (int mt = 0; mt < 2; ++mt)
            acc1[q][mt] = (float4_t){0.f, 0.f, 0.f, 0.f};

    #pragma unroll
    for (int q = 0; q < 6; ++q) {
        const int nt = wv + q * 4;
        if (nt < 21) {
            const int ri = c1idx(fr, nt * 16 + ml);
            const half8_t dh = *(const half8_t*)(&C1h[ri]);
            const half8_t dl = *(const half8_t*)(&C1l[ri]);
            #pragma unroll
            for (int mt = 0; mt < 2; ++mt) {
                acc1[q][mt] = __builtin_amdgcn_mfma_f32_16x16x32_f16(wAh[mt], dh, acc1[q][mt], 0, 0, 0);
                acc1[q][mt] = __builtin_amdgcn_mfma_f32_16x16x32_f16(wAl[mt], dh, acc1[q][mt], 0, 0, 0);
                acc1[q][mt] = __builtin_amdgcn_mfma_f32_16x16x32_f16(wAh[mt], dl, acc1[q][mt], 0, 0, 0);
            }
        }
    }
    __syncthreads();          // all A reads done; buffer reusable

    // ---- Phase C: epilogue -> overwrite C1. Thread: 4 consecutive ch at
    //      one pos per (q,mt); ONE bounds mask per q; half4 stores.
    const float4_t bA = *(const float4_t*)(b1 + fr * 4);
    const float4_t bB = *(const float4_t*)(b1 + 16 + fr * 4);
    #pragma unroll
    for (int q = 0; q < 6; ++q) {
        const int nt = wv + q * 4;
        if (nt < 21) {
            const int pos = nt * 16 + ml;
            if (pos < 324) {
                const int py = pos / 18, px = pos - py * 18;
                const int gy = oy + py - 1, gx = ox + px - 1;
                const bool ok = (unsigned)gy < 128u && (unsigned)gx < 128u;
                #pragma unroll
                for (int mt = 0; mt < 2; ++mt) {
                    const int slot = mt * 2 + (fr >> 1);
                    const int wi = c1idx(slot, pos) + (fr & 1) * 4;
                    const float4_t bb = mt ? bB : bA;
                    half4_t oh, ol;
                    #pragma unroll
                    for (int r = 0; r < 4; ++r) {
                        const float v = ok ? fmaxf(acc1[q][mt][r] + bb[r], 0.f) : 0.f;
                        const _Float16 h = (_Float16)v;
                        oh[r] = h;
                        ol[r] = (_Float16)(v - (float)h);
                    }
                    *(half4_t*)(&C1h[wi]) = oh;
                    *(half4_t*)(&C1l[wi]) = ol;
                }
            }
        }
    }
    __syncthreads();

    // ---- Phase D: conv2 implicit-GEMM, wave wv owns out rows wv*4..wv*4+3 --
    float4_t acc[4][2];
    #pragma unroll
    for (int i = 0; i < 4; ++i)
        #pragma unroll
        for (int nt = 0; nt < 2; ++nt)
            acc[i][nt] = (float4_t){0.f, 0.f, 0.f, 0.f};

    #pragma unroll 1
    for (int tap = 0; tap < 9; ++tap) {
        const int dy = tap / 3, dx = tap - dy * 3;
        half8_t bh[2], bl[2];
        #pragma unroll
        for (int nt = 0; nt < 2; ++nt) {
            const int bo = ((tap * 2 + nt) * 64 + lane) * 8;
            bh[nt] = *(const half8_t*)(B2h + bo);
            bl[nt] = *(const half8_t*)(B2l + bo);
        }
        half8_t ah[4], al[4];
        #pragma unroll
        for (int i = 0; i < 4; ++i) {
            const int pos = (wv * 4 + i + dy) * 18 + ml + dx;
            const int ri  = c1idx(fr, pos);
            ah[i] = *(const half8_t*)(&C1h[ri]);
            al[i] = *(const half8_t*)(&C1l[ri]);
        }
        #pragma unroll
        for (int nt = 0; nt < 2; ++nt)
            #pragma unroll
            for (int i = 0; i < 4; ++i)
                acc[i][nt] = __builtin_amdgcn_mfma_f32_16x16x32_f16(ah[i], bh[nt], acc[i][nt], 0, 0, 0);
        #pragma unroll
        for (int nt = 0; nt < 2; ++nt)
            #pragma unroll
            for (int i = 0; i < 4; ++i)
                acc[i][nt] = __builtin_amdgcn_mfma_f32_16x16x32_f16(al[i], bh[nt], acc[i][nt], 0, 0, 0);
        #pragma unroll
        for (int nt = 0; nt < 2; ++nt)
            #pragma unroll
            for (int i = 0; i < 4; ++i)
                acc[i][nt] = __builtin_amdgcn_mfma_f32_16x16x32_f16(ah[i], bl[nt], acc[i][nt], 0, 0, 0);
    }

    // ---- maxpool4 (thread-local) + bias + relu + hi/lo store ----
    const int py = ty * 4 + wv;
    const int px = tx * 4 + fr;
    #pragma unroll
    for (int nt = 0; nt < 2; ++nt) {
        float m = -1e30f;
        #pragma unroll
        for (int i = 0; i < 4; ++i)
            #pragma unroll
            for (int r = 0; r < 4; ++r)
                m = fmaxf(m, acc[i][nt][r]);
        const int oc = nt * 16 + ml;
        const float v = fmaxf(m + b2[oc], 0.f);
        const _Float16 h = (_Float16)v;
        const int base = ((b * 32 + py) * 32 + px) * 32 + oc;
        P1h[base] = h;
        P1l[base] = (_Float16)(v - (float)h);
    }
}

// ---------------------------------------------------------------------------
// Weight repack: fp16 hi/lo MFMA-fragment packs for w2..w6 (+ w1, K padded
// 27->32). Frag order: Bh[((c*NT + ntg)*64 + lane)*8 + j], element B[k][n]:
//   n = ntg*16 + (lane&15), k = c*32 + (lane>>4)*8 + j.
// w2..w6: k = tap*CIN + ci.  w1: k = ci*9 + tap (= w1 natural order).
// (w1 pack doubles as the A-frag under m=lane&15 -- same bytes.)
// ---------------------------------------------------------------------------
__global__ void k_wrepackm(const float* __restrict__ w1, const float* __restrict__ w2,
                           const float* __restrict__ w3, const float* __restrict__ w4,
                           const float* __restrict__ w5, const float* __restrict__ w6,
                           _Float16* __restrict__ Bh, _Float16* __restrict__ Bl,
                           _Float16* __restrict__ B1h, _Float16* __restrict__ B1l)
{
    int idx = blockIdx.x * 256 + threadIdx.x;
    if (idx >= 285696) {
        const int i = idx - 285696;
        if (i >= 1024) return;
        const int ntg = i >> 9, rr = i & 511;
        const int lane = rr >> 3, j = rr & 7;
        const int k = (lane >> 4) * 8 + j;
        const int n = ntg * 16 + (lane & 15);
        const float v = (k < 27) ? w1[n * 27 + k] : 0.f;
        const _Float16 h = (_Float16)v;
        B1h[i] = h;
        B1l[i] = (_Float16)(v - (float)h);
        return;
    }
    const float* w; int CIN, COUT, off;
    if (idx < 9216)        { w = w2; CIN = 32;  COUT = 32;  off = 0; }
    else if (idx < 27648)  { idx -= 9216;   w = w3; CIN = 32;  COUT = 64;  off = 9216; }
    else if (idx < 64512)  { idx -= 27648;  w = w4; CIN = 64;  COUT = 64;  off = 27648; }
    else if (idx < 138240) { idx -= 64512;  w = w5; CIN = 64;  COUT = 128; off = 64512; }
    else                   { idx -= 138240; w = w6; CIN = 128; COUT = 128; off = 138240; }
    const int NT  = COUT / 16;
    const int c   = idx / (NT * 512);
    const int r   = idx - c * NT * 512;
    const int ntg = r >> 9;
    const int rr  = r & 511;
    const int lane = rr >> 3, j = rr & 7;
    const int k   = c * 32 + (lane >> 4) * 8 + j;
    const int tap = k / CIN, ci = k - tap * CIN;
    const int oc  = ntg * 16 + (lane & 15);
    const float v = w[(oc * CIN + ci) * 9 + tap];
    const _Float16 h = (_Float16)v;
    Bh[off + idx] = h;
    Bl[off + idx] = (_Float16)(v - (float)h);
}

// ---------------------------------------------------------------------------
// MFMA implicit-GEMM conv3x3, fp16x3 split (fp32-class: ll term <= 2^-22 rel).
// BM=128, BN=64 per block; 4 waves, wave = 2 m-tiles x 4 n-tiles.
// ---------------------------------------------------------------------------
template<int CIN, int COUT, int HW, bool OUTF32>
__global__ __launch_bounds__(256, 2)
void k_mgemm(const _Float16* __restrict__ inh, const _Float16* __restrict__ inl,
             const _Float16* __restrict__ Bh, const _Float16* __restrict__ Bl,
             const float* __restrict__ bias,
             _Float16* __restrict__ outh, _Float16* __restrict__ outl,
             float* __restrict__ outf)
{
    constexpr int NCH = CIN * 9 / 32;
    constexpr int NT  = COUT / 16;
    constexpr int LOG = (HW == 32) ? 5 : 4;
    constexpr int PS  = 40;
    __shared__ _Float16 Ash[128 * PS];
    __shared__ _Float16 Asl[128 * PS];

    const int t    = threadIdx.x;
    const int wv   = t >> 6;
    const int lane = t & 63;
    const int m0   = blockIdx.x * 128;
    const int nb   = blockIdx.y;

    int sm[2], sg[2], sb[2], sy[2], sx[2];
    #pragma unroll
    for (int j = 0; j < 2; ++j) {
        const int q = t + 256 * j;
        sm[j] = q >> 2;
        sg[j] = q & 3;
        const int m  = m0 + sm[j];
        const int yx = m & (HW * HW - 1);
        sb[j] = m >> (2 * LOG);
        sy[j] = yx >> LOG;
        sx[j] = yx & (HW - 1);
    }

    const int mt0 = wv * 2;
    const int fr  = lane >> 4;
    const int ml  = lane & 15;

    float4_t acc[2][4];
    #pragma unroll
    for (int mt = 0; mt < 2; ++mt)
        #pragma unroll
        for (int tn = 0; tn < 4; ++tn)
            acc[mt][tn] = (float4_t){0.f, 0.f, 0.f, 0.f};

    #pragma unroll 1
    for (int ch = 0; ch < NCH; ++ch) {
        const int kb  = ch * 32;
        const int tap = kb / CIN;
        const int c0  = kb - tap * CIN;
        const int dy  = tap / 3 - 1, dx = tap - (tap / 3) * 3 - 1;

        if (ch) __syncthreads();
        #pragma unroll
        for (int j = 0; j < 2; ++j) {
            const int iy = sy[j] + dy, ix = sx[j] + dx;
            half8_t vh = {0, 0, 0, 0, 0, 0, 0, 0};
            half8_t vl = {0, 0, 0, 0, 0, 0, 0, 0};
            if ((unsigned)iy < (unsigned)HW && (unsigned)ix < (unsigned)HW) {
                const int o = ((sb[j] * HW + iy) * HW + ix) * CIN + c0 + sg[j] * 8;
                vh = *(const half8_t*)(inh + o);
                vl = *(const half8_t*)(inl + o);
            }
            *(half8_t*)(&Ash[sm[j] * PS + sg[j] * 8]) = vh;
            *(half8_t*)(&Asl[sm[j] * PS + sg[j] * 8]) = vl;
        }
        __syncthreads();

        half8_t ah[2], al[2];
        #pragma unroll
        for (int mt = 0; mt < 2; ++mt) {
            const int mr = (mt0 + mt) * 16 + ml;
            ah[mt] = *(const half8_t*)(&Ash[mr * PS + fr * 8]);
            al[mt] = *(const half8_t*)(&Asl[mr * PS + fr * 8]);
        }
        half8_t bh[4], bl[4];
        #pragma unroll
        for (int tn = 0; tn < 4; ++tn) {
            const int bo = ((ch * NT + nb * 4 + tn) * 64 + lane) * 8;
            bh[tn] = *(const half8_t*)(Bh + bo);
            bl[tn] = *(const half8_t*)(Bl + bo);
        }
        #pragma unroll
        for (int tn = 0; tn < 4; ++tn)
            #pragma unroll
            for (int mt = 0; mt < 2; ++mt)
                acc[mt][tn] = __builtin_amdgcn_mfma_f32_16x16x32_f16(ah[mt], bh[tn], acc[mt][tn], 0, 0, 0);
        #pragma unroll
        for (int tn = 0; tn < 4; ++tn)
            #pragma unroll
            for (int mt = 0; mt < 2; ++mt)
                acc[mt][tn] = __builtin_amdgcn_mfma_f32_16x16x32_f16(al[mt], bh[tn], acc[mt][tn], 0, 0, 0);
        #pragma unroll
        for (int tn = 0; tn < 4; ++tn)
            #pragma unroll
            for (int mt = 0; mt < 2; ++mt)
                acc[mt][tn] = __builtin_amdgcn_mfma_f32_16x16x32_f16(ah[mt], bl[tn], acc[mt][tn], 0, 0, 0);
        // (al,bl) term dropped: <= 2^-22 relative contribution.
    }

    // epilogue: C/D frag col=lane&15, row=(lane>>4)*4+reg  [guide m89/m91]
    #pragma unroll
    for (int mt = 0; mt < 2; ++mt)
        #pragma unroll
        for (int tn = 0; tn < 4; ++tn) {
            const int oc = nb * 64 + tn * 16 + ml;
            const float bv = bias[oc];
            #pragma unroll
            for (int r = 0; r < 4; ++r) {
                const int m = m0 + (mt0 + mt) * 16 + fr * 4 + r;
                const float v = fmaxf(acc[mt][tn][r] + bv, 0.f);
                if (OUTF32) {
                    outf[m * COUT + oc] = v;
                } else {
                    const _Float16 h = (_Float16)v;
                    outh[m * COUT + oc] = h;
                    outl[m * COUT + oc] = (_Float16)(v - (float)h);
                }
            }
        }
}

// ---------------------------------------------------------------------------
// 2x2 maxpool on dual fp16 planes, NHWC [128][32][32][64] -> [128][16][16][64]
// ---------------------------------------------------------------------------
__global__ __launch_bounds__(256)
void k_pool2h(const _Float16* __restrict__ inh, const _Float16* __restrict__ inl,
              _Float16* __restrict__ outh, _Float16* __restrict__ outl)
{
    const int g = blockIdx.x * 256 + threadIdx.x;
    const int c4 = g & 15, xo = (g >> 4) & 15, yo = (g >> 8) & 15, b = g >> 12;
    const int base = ((b * 32 + yo * 2) * 32 + xo * 2) * 64 + c4 * 4;
    const int offs[4] = {0, 64, 2048, 2112};
    float mx[4] = {-1e30f, -1e30f, -1e30f, -1e30f};
    #pragma unroll
    for (int cnd = 0; cnd < 4; ++cnd) {
        const half4_t h = *(const half4_t*)(inh + base + offs[cnd]);
        const half4_t l = *(const half4_t*)(inl + base + offs[cnd]);
        #pragma unroll
        for (int e = 0; e < 4; ++e)
            mx[e] = fmaxf(mx[e], (float)h[e] + (float)l[e]);
    }
    half4_t oh, ol;
    #pragma unroll
    for (int e = 0; e < 4; ++e) {
        const _Float16 h = (_Float16)mx[e];
        oh[e] = h;
        ol[e] = (_Float16)(mx[e] - (float)h);
    }
    const int ob = ((b * 16 + yo) * 16 + xo) * 64 + c4 * 4;
    *(half4_t*)(outh + ob) = oh;
    *(half4_t*)(outl + ob) = ol;
}

// ---------------------------------------------------------------------------
// Split-K FC partial (fp32): A[128 x K] @ B[K x 512] -> part[ky][128][512]
// ---------------------------------------------------------------------------
template<int LDA, int KCHUNK, int TN, bool PERM>
__global__ __launch_bounds__(256, 2)
void k_fc_partial(const float* __restrict__ A, const float* __restrict__ Bw,
                  float* __restrict__ part)
{
    constexpr int BN = 16 * TN;
    constexpr int SA = 140;
    constexpr int SB = (BN == 128) ? 140 : 68;
    __shared__ __align__(16) float As[32 * SA];
    __shared__ __align__(16) float Bs[32 * SB];
    const int t  = threadIdx.x;
    const int tm = t >> 4, tn = t & 15;
    const int n0 = blockIdx.x * BN;
    const int k0 = blockIdx.y * KCHUNK;

    float acc[8][TN];
    #pragma unroll
    for (int r = 0; r < 8; ++r)
        #pragma unroll
        for (int c = 0; c < TN; ++c) acc[r][c] = 0.f;

    #pragma unroll 1
    for (int ks = 0; ks < KCHUNK / 32; ++ks) {
        if (ks) __syncthreads();
        const int kb = k0 + ks * 32;
        for (int i = t; i < 4096; i += 256) {
            const int m = i >> 5, kk = i & 31;
            As[kk * SA + m + ((m >> 5) << 2)] = A[m * LDA + kb + kk];
        }
        for (int i = t; i < 32 * BN; i += 256) {
            const int kk = i / BN, n = i - kk * BN;
            const int krow = kb + kk;
            const int kref = PERM ? ((krow & 127) * 256 + (krow >> 7)) : krow;
            Bs[kk * SB + n + ((n >> 5) << 2)] = Bw[kref * 512 + n0 + n];
        }
        __syncthreads();
        #pragma unroll 2
        for (int kk = 0; kk < 32; ++kk) {
            const float* ap = &As[kk * SA + tm * 8 + ((tm >> 2) << 2)];
            const float* bp = &Bs[kk * SB + tn * TN + (((tn * TN) >> 5) << 2)];
            float a[8], bb[TN];
            #pragma unroll
            for (int q = 0; q < 8; q += 4) {
                const float4 v = *(const float4*)(ap + q);
                a[q] = v.x; a[q + 1] = v.y; a[q + 2] = v.z; a[q + 3] = v.w;
            }
            #pragma unroll
            for (int q = 0; q < TN; q += 4) {
                const float4 v = *(const float4*)(bp + q);
                bb[q] = v.x; bb[q + 1] = v.y; bb[q + 2] = v.z; bb[q + 3] = v.w;
            }
            #pragma unroll
            for (int r = 0; r < 8; ++r)
                #pragma unroll
                for (int c = 0; c < TN; ++c)
                    acc[r][c] = fmaf(a[r], bb[c], acc[r][c]);
        }
    }

    const long pb = (long)blockIdx.y * 65536;
    #pragma unroll
    for (int r = 0; r < 8; ++r)
        #pragma unroll
        for (int c = 0; c < TN; ++c)
            part[pb + (tm * 8 + r) * 512 + n0 + tn * TN + c] = acc[r][c];
}

template<int NS>
__global__ __launch_bounds__(256)
void k_fc_reduce(const float* __restrict__ part, const float* __restrict__ bias,
                 float* __restrict__ H)
{
    const int f = (blockIdx.x * 256 + threadIdx.x) * 4;
    const int m = f >> 9, n = f & 511;
    float s0 = 0.f, s1 = 0.f, s2 = 0.f, s3 = 0.f;
    #pragma unroll 4
    for (int q = 0; q < NS; ++q) {
        const float* p = &part[(q * 128 + m) * 512 + n];
        s0 += p[0]; s1 += p[1]; s2 += p[2]; s3 += p[3];
    }
    H[f]     = fmaxf(s0 + bias[n],     0.f);
    H[f + 1] = fmaxf(s1 + bias[n + 1], 0.f);
    H[f + 2] = fmaxf(s2 + bias[n + 2], 0.f);
    H[f + 3] = fmaxf(s3 + bias[n + 3], 0.f);
}

// ---------------------------------------------------------------------------
// Final: FC3 + sampling + patch gather
// ---------------------------------------------------------------------------
__device__ __forceinline__ float softplusf(float x) {
    return (x > 20.f) ? x : log1pf(expf(x));
}
__device__ __forceinline__ float sigmoidf_(float x) {
    return 1.f / (1.f + expf(-x));
}

__global__ __launch_bounds__(256)
void k_final(const float* __restrict__ H2, const float* __restrict__ wl3,
             const float* __restrict__ bl3, const float* __restrict__ noise,
             const float* __restrict__ img, float* __restrict__ outp)
{
    __shared__ float h2[512];
    __shared__ float red[144];
    __shared__ float prep[36];
    __shared__ int ptsh[12], ptsw[12];
    const int b = blockIdx.x, t = threadIdx.x;

    h2[t]       = H2[b * 512 + t];
    h2[t + 256] = H2[b * 512 + 256 + t];
    __syncthreads();

    if (t < 144) {
        const int n = t >> 2, q = t & 3;
        float s = 0.f;
        for (int k = q * 128; k < q * 128 + 128; ++k)
            s = fmaf(h2[k], wl3[k * 36 + n], s);
        red[t] = s;
    }
    __syncthreads();
    if (t < 36)
        prep[t] = red[t * 4] + red[t * 4 + 1] + red[t * 4 + 2] + red[t * 4 + 3] + bl3[t];
    __syncthreads();

    if (t < 12) {
        const float m0 = prep[t * 3], m1 = prep[t * 3 + 1], sv = prep[t * 3 + 2];
        const float sig = softplusf(sv + 2.0f) * 128.f + 1e-7f;
        const float n0 = noise[(b * 12 + t) * 2], n1 = noise[(b * 12 + t) * 2 + 1];
        const float sa0 = m0 + sig * n0;
        const float sa1 = m1 + sig * n1;
        int p0 = (int)rintf(sigmoidf_(sa0) * 111.f);
        int p1 = (int)rintf(sigmoidf_(sa1) * 111.f);
        p0 = min(max(p0, 0), 111);
        p1 = min(max(p1, 0), 111);
        const int RM = 1179648;
        outp[RM        + (b * 12 + t) * 2 + 0] = m0;
        outp[RM        + (b * 12 + t) * 2 + 1] = m1;
        outp[RM + 3072 + (b * 12 + t) * 2 + 0] = sig;
        outp[RM + 3072 + (b * 12 + t) * 2 + 1] = sig;
        outp[RM + 6144 + (b * 12 + t) * 2 + 0] = sa0;
        outp[RM + 6144 + (b * 12 + t) * 2 + 1] = sa1;
        ptsh[t] = p0;
        ptsw[t] = p1;
    }
    __syncthreads();

    for (int i = t; i < 9216; i += 256) {
        const int g  = i / 768, r = i - g * 768;
        const int c  = r >> 8, r2 = r & 255;
        const int y  = r2 >> 4, x = r2 & 15;
        outp[b * 9216 + i] = img[((b * 3 + c) * 128 + ptsh[g] + y) * 128 + (ptsw[g] + x)];
    }
}

// ---------------------------------------------------------------------------
extern "C" void kernel_launch(void* const* d_in, const int* in_sizes, int n_in,
                              void* d_out, int out_size, void* d_ws, size_t ws_size,
                              hipStream_t stream)
{
    const float* img  = (const float*)d_in[0];
    const float* nois = (const float*)d_in[1];
    const float* w1 = (const float*)d_in[2];  const float* b1 = (const float*)d_in[3];
    const float* w2 = (const float*)d_in[4];  const float* b2 = (const float*)d_in[5];
    const float* w3 = (const float*)d_in[6];  const float* b3 = (const float*)d_in[7];
    const float* w4 = (const float*)d_in[8];  const float* b4 = (const float*)d_in[9];
    const float* w5 = (const float*)d_in[10]; const float* b5 = (const float*)d_in[11];
    const float* w6 = (const float*)d_in[12]; const float* b6 = (const float*)d_in[13];
    const float* wl1 = (const float*)d_in[14]; const float* bl1 = (const float*)d_in[15];
    const float* wl2 = (const float*)d_in[16]; const float* bl2 = (const float*)d_in[17];
    const float* wl3 = (const float*)d_in[18]; const float* bl3 = (const float*)d_in[19];
    float* out = (float*)d_out;
    float* ws  = (float*)d_ws;

    // workspace (float units). Activation regions span [0 .. 20971520).
    // Weight packs live ABOVE all activations, EXCEPT the tiny w1 frag pack,
    // which sits in [17956864..17957888) -- inside A4l's range but only live
    // before conv4 writes A4l (wrepackm -> conv12 both precede conv4).
    _Float16* P1h = (_Float16*)(ws);               // [128*32*32*32] halves
    _Float16* P1l = (_Float16*)(ws + 2097152);
    _Float16* A3h = (_Float16*)(ws + 4194304);     // [128*32*32*64]
    _Float16* A3l = (_Float16*)(ws + 8388608);
    _Float16* A4h = (_Float16*)(ws + 12582912);    // [128*32*32*64]
    _Float16* A4l = (_Float16*)(ws + 16777216);    // ..20971520
    _Float16* P2h = (_Float16*)(ws);               // [128*16*16*64] (P1 dead)
    _Float16* P2l = (_Float16*)(ws + 1048576);
    _Float16* A5h = (_Float16*)(ws + 4194304);     // [128*16*16*128] (A3 dead)
    _Float16* A5l = (_Float16*)(ws + 6291456);
    float* A6  = ws + 8388608;                     // [128*16*16*128] fp32 (A3 dead)
    float* FP1 = ws + 12582912;                    // [64][128][512] (A4h dead)
    float* H1  = ws + 16777216;                    // [128][512]     (A4l dead)
    float* FP2 = ws + 16842752;                    // [16][128][512]
    float* H2  = ws + 17891328;                    // [128][512]
    _Float16* B1h = (_Float16*)(ws + 17956864);    // 1024 halves (w1 pack)
    _Float16* B1l = (_Float16*)(ws + 17957376);
    _Float16* Bh = (_Float16*)(ws + 20971520);     // 285696 halves (w2..w6)
    _Float16* Bl = (_Float16*)(ws + 21114368);     // ends 21257216 fl = 85 MB

    hipLaunchKernelGGL(k_wrepackm, dim3(1120), dim3(256), 0, stream,
                       w1, w2, w3, w4, w5, w6, Bh, Bl, B1h, B1l);

    // conv1+conv2+pool4: grid = 8x8 tiles x 128 batch
    hipLaunchKernelGGL(k_conv12, dim3(64, 128), dim3(256), 0, stream,
                       img, b1, B1h, B1l, Bh + 0, Bl + 0, b2, P1h, P1l);
    // conv3: M=131072, K=288, COUT=64
    hipLaunchKernelGGL((k_mgemm<32, 64, 32, false>), dim3(1024, 1), dim3(256), 0, stream,
                       P1h, P1l, Bh + 9216, Bl + 9216, b3, A3h, A3l, nullptr);
    // conv4: K=576
    hipLaunchKernelGGL((k_mgemm<64, 64, 32, false>), dim3(1024, 1), dim3(256), 0, stream,
                       A3h, A3l, Bh + 27648, Bl + 27648, b4, A4h, A4l, nullptr);
    hipLaunchKernelGGL(k_pool2h, dim3(2048), dim3(256), 0, stream, A4h, A4l, P2h, P2l);
    // conv5: M=32768, K=576, COUT=128
    hipLaunchKernelGGL((k_mgemm<64, 128, 16, false>), dim3(256, 2), dim3(256), 0, stream,
                       P2h, P2l, Bh + 64512, Bl + 64512, b5, A5h, A5l, nullptr);
    // conv6: K=1152, fp32 out for FC1
    hipLaunchKernelGGL((k_mgemm<128, 128, 16, true>), dim3(256, 2), dim3(256), 0, stream,
                       A5h, A5l, Bh + 138240, Bl + 138240, b6, nullptr, nullptr, A6);
    hipLaunchKernelGGL((k_fc_partial<32768, 512, 4, true>), dim3(8, 64), dim3(256), 0, stream,
                       A6, wl1, FP1);
    hipLaunchKernelGGL(k_fc_reduce<64>, dim3(64), dim3(256), 0, stream, FP1, bl1, H1);
    hipLaunchKernelGGL((k_fc_partial<512, 32, 4, false>), dim3(8, 16), dim3(256), 0, stream,
                       H1, wl2, FP2);
    hipLaunchKernelGGL(k_fc_reduce<16>, dim3(64), dim3(256), 0, stream, FP2, bl2, H2);
    hipLaunchKernelGGL(k_final, dim3(128), dim3(256), 0, stream,
                       H2, wl3, bl3, nois, img, out);
}

// Round 9
// 593.524 us; speedup vs baseline: 1.4145x; 1.0242x over previous
//
#include <hip/hip_runtime.h>
#include <math.h>

typedef _Float16 __attribute__((ext_vector_type(8))) half8_t;
typedef _Float16 __attribute__((ext_vector_type(4))) half4_t;
typedef _Float16 __attribute__((ext_vector_type(2))) half2_t;
typedef float    __attribute__((ext_vector_type(4))) float4_t;

// ---------------------------------------------------------------------------
// Kernel 1: fully-MFMA conv1 + conv2 + maxpool4 (block = 16x16 output tile).
// Phase A: img -> simg (fp32 LDS halo-2) -> im2col into
//   C1h[slot=k/8][pos=18*18][j=k&7] fp16 HI ONLY (R8: input lo-plane dropped;
//   ~1e-3 rel perturbation, far inside the ~20 output threshold per R2).
// Phase B: conv1 GEMM transposed: M=32 ch, N=324 pos, K=32, 2-term split
//   (wh+wl)*xh.  D-frag: thread holds 4 consecutive ch at one pos.
// Phase C: epilogue -> C1h/C1l overwrite (conv1 OUTPUT keeps hi/lo), half4
//   stores, one bounds mask per q.
// Phase D: conv2 implicit GEMM (M=256,K=288,N=32, 3-term) + 4x4 pool.
// POSP=336 (mult of 8: swizzle bijective, R2 lesson); swizzled idx computed
// per (slot,pos) (R5 lesson). LDS 47.9 KB -> 3 blocks/CU.
// ---------------------------------------------------------------------------
#define POSP 336

__device__ __forceinline__ int c1idx(int slot, int pos) {
    return ((slot * POSP + pos) * 8) ^ (((pos >> 3) & 7) << 3);
}

__global__ __launch_bounds__(256, 3)
void k_conv12(const float* __restrict__ img, const float* __restrict__ b1,
              const _Float16* __restrict__ B1h, const _Float16* __restrict__ B1l,
              const _Float16* __restrict__ B2h, const _Float16* __restrict__ B2l,
              const float* __restrict__ b2,
              _Float16* __restrict__ P1h, _Float16* __restrict__ P1l)
{
    __shared__ float simg[3 * 20 * 25];                    // input halo-2
    __shared__ __align__(16) _Float16 C1h[4 * POSP * 8];   // A, then conv1 out
    __shared__ __align__(16) _Float16 C1l[4 * POSP * 8];   // conv1 out lo only

    const int t  = threadIdx.x;
    const int bt = blockIdx.x;
    const int b  = blockIdx.y;
    const int ty = bt >> 3, tx = bt & 7;
    const int oy = ty * 16, ox = tx * 16;

    // ---- Phase A1: stage fp32 halo (bounds-checked ONCE, zero-padded) ----
    for (int i = t; i < 1500; i += 256) {
        const int ci = i / 500, r = i - ci * 500;
        const int yy = r / 25, xx = r - yy * 25;
        const int gy = oy - 2 + yy, gx = ox - 2 + xx;
        float v = 0.f;
        if ((unsigned)gy < 128u && (unsigned)gx < 128u)
            v = img[((b * 3 + ci) * 128 + gy) * 128 + gx];
        simg[i] = v;
    }
    __syncthreads();

    // ---- Phase A2: im2col simg -> C1h (hi only; compile-time tap offsets) --
    #pragma unroll
    for (int hf = 0; hf < 2; ++hf) {
        const int pos = hf * 256 + t;
        if (pos < POSP) {
            const bool val = pos < 324;
            int sb = 0;
            if (val) {
                const int py = pos / 18, px = pos - py * 18;
                sb = py * 25 + px;
            }
            #pragma unroll
            for (int s = 0; s < 4; ++s) {
                half8_t vh = {0,0,0,0,0,0,0,0};
                if (val) {
                    #pragma unroll
                    for (int j = 0; j < 8; ++j) {
                        const int k = s * 8 + j;
                        if (k < 27) {
                            const int ci = k / 9, tap = k - ci * 9;   // const
                            const int dy = tap / 3, dx = tap - dy * 3; // const
                            vh[j] = (_Float16)simg[sb + (ci * 20 + dy) * 25 + dx];
                        }
                    }
                }
                *(half8_t*)(&C1h[c1idx(s, pos)]) = vh;
            }
        }
    }
    __syncthreads();

    const int wv   = __builtin_amdgcn_readfirstlane(t >> 6);
    const int lane = t & 63;
    const int fr   = lane >> 4;
    const int ml   = lane & 15;

    // ---- Phase B: conv1 MFMA, transposed, 2-term: D[ch][pos] = w @ xh ----
    half8_t wAh[2], wAl[2];
    #pragma unroll
    for (int mt = 0; mt < 2; ++mt) {
        wAh[mt] = *(const half8_t*)(B1h + (mt * 64 + lane) * 8);
        wAl[mt] = *(const half8_t*)(B1l + (mt * 64 + lane) * 8);
    }
    float4_t acc1[6][2];
    #pragma unroll
    for (int q = 0; q < 6; ++q)
        #pragma unroll
        for (int mt = 0; mt < 2; ++mt)
            acc1[q][mt] = (float4_t){0.f, 0.f, 0.f, 0.f};

    #pragma unroll
    for (int q = 0; q < 6; ++q) {
        const int nt = wv + q * 4;
        if (nt < 21) {
            const int ri = c1idx(fr, nt * 16 + ml);
            const half8_t dh = *(const half8_t*)(&C1h[ri]);
            #pragma unroll
            for (int mt = 0; mt < 2; ++mt) {
                acc1[q][mt] = __builtin_amdgcn_mfma_f32_16x16x32_f16(wAh[mt], dh, acc1[q][mt], 0, 0, 0);
                acc1[q][mt] = __builtin_amdgcn_mfma_f32_16x16x32_f16(wAl[mt], dh, acc1[q][mt], 0, 0, 0);
            }
        }
    }
    __syncthreads();          // all A reads done; buffer reusable

    // ---- Phase C: epilogue -> overwrite C1. Thread: 4 consecutive ch at
    //      one pos per (q,mt); ONE bounds mask per q; half4 stores.
    const float4_t bA = *(const float4_t*)(b1 + fr * 4);
    const float4_t bB = *(const float4_t*)(b1 + 16 + fr * 4);
    #pragma unroll
    for (int q = 0; q < 6; ++q) {
        const int nt = wv + q * 4;
        if (nt < 21) {
            const int pos = nt * 16 + ml;
            if (pos < 324) {
                const int py = pos / 18, px = pos - py * 18;
                const int gy = oy + py - 1, gx = ox + px - 1;
                const bool ok = (unsigned)gy < 128u && (unsigned)gx < 128u;
                #pragma unroll
                for (int mt = 0; mt < 2; ++mt) {
                    const int slot = mt * 2 + (fr >> 1);
                    const int wi = c1idx(slot, pos) + (fr & 1) * 4;
                    const float4_t bb = mt ? bB : bA;
                    half4_t oh, ol;
                    #pragma unroll
                    for (int r = 0; r < 4; ++r) {
                        const float v = ok ? fmaxf(acc1[q][mt][r] + bb[r], 0.f) : 0.f;
                        const _Float16 h = (_Float16)v;
                        oh[r] = h;
                        ol[r] = (_Float16)(v - (float)h);
                    }
                    *(half4_t*)(&C1h[wi]) = oh;
                    *(half4_t*)(&C1l[wi]) = ol;
                }
            }
        }
    }
    __syncthreads();

    // ---- Phase D: conv2 implicit-GEMM, wave wv owns out rows wv*4..wv*4+3 --
    float4_t acc[4][2];
    #pragma unroll
    for (int i = 0; i < 4; ++i)
        #pragma unroll
        for (int nt = 0; nt < 2; ++nt)
            acc[i][nt] = (float4_t){0.f, 0.f, 0.f, 0.f};

    #pragma unroll 1
    for (int tap = 0; tap < 9; ++tap) {
        const int dy = tap / 3, dx = tap - dy * 3;
        half8_t bh[2], bl[2];
        #pragma unroll
        for (int nt = 0; nt < 2; ++nt) {
            const int bo = ((tap * 2 + nt) * 64 + lane) * 8;
            bh[nt] = *(const half8_t*)(B2h + bo);
            bl[nt] = *(const half8_t*)(B2l + bo);
        }
        half8_t ah[4], al[4];
        #pragma unroll
        for (int i = 0; i < 4; ++i) {
            const int pos = (wv * 4 + i + dy) * 18 + ml + dx;
            const int ri  = c1idx(fr, pos);
            ah[i] = *(const half8_t*)(&C1h[ri]);
            al[i] = *(const half8_t*)(&C1l[ri]);
        }
        #pragma unroll
        for (int nt = 0; nt < 2; ++nt)
            #pragma unroll
            for (int i = 0; i < 4; ++i)
                acc[i][nt] = __builtin_amdgcn_mfma_f32_16x16x32_f16(ah[i], bh[nt], acc[i][nt], 0, 0, 0);
        #pragma unroll
        for (int nt = 0; nt < 2; ++nt)
            #pragma unroll
            for (int i = 0; i < 4; ++i)
                acc[i][nt] = __builtin_amdgcn_mfma_f32_16x16x32_f16(al[i], bh[nt], acc[i][nt], 0, 0, 0);
        #pragma unroll
        for (int nt = 0; nt < 2; ++nt)
            #pragma unroll
            for (int i = 0; i < 4; ++i)
                acc[i][nt] = __builtin_amdgcn_mfma_f32_16x16x32_f16(ah[i], bl[nt], acc[i][nt], 0, 0, 0);
    }

    // ---- maxpool4 (thread-local) + bias + relu + hi/lo store ----
    const int py = ty * 4 + wv;
    const int px = tx * 4 + fr;
    #pragma unroll
    for (int nt = 0; nt < 2; ++nt) {
        float m = -1e30f;
        #pragma unroll
        for (int i = 0; i < 4; ++i)
            #pragma unroll
            for (int r = 0; r < 4; ++r)
                m = fmaxf(m, acc[i][nt][r]);
        const int oc = nt * 16 + ml;
        const float v = fmaxf(m + b2[oc], 0.f);
        const _Float16 h = (_Float16)v;
        const int base = ((b * 32 + py) * 32 + px) * 32 + oc;
        P1h[base] = h;
        P1l[base] = (_Float16)(v - (float)h);
    }
}

// ---------------------------------------------------------------------------
// Weight repack: fp16 hi/lo MFMA-fragment packs for w2..w6 (+ w1, K padded
// 27->32). Frag order: Bh[((c*NT + ntg)*64 + lane)*8 + j], element B[k][n]:
//   n = ntg*16 + (lane&15), k = c*32 + (lane>>4)*8 + j.
// w2..w6: k = tap*CIN + ci.  w1: k = ci*9 + tap (= w1 natural order).
// ---------------------------------------------------------------------------
__global__ void k_wrepackm(const float* __restrict__ w1, const float* __restrict__ w2,
                           const float* __restrict__ w3, const float* __restrict__ w4,
                           const float* __restrict__ w5, const float* __restrict__ w6,
                           _Float16* __restrict__ Bh, _Float16* __restrict__ Bl,
                           _Float16* __restrict__ B1h, _Float16* __restrict__ B1l)
{
    int idx = blockIdx.x * 256 + threadIdx.x;
    if (idx >= 285696) {
        const int i = idx - 285696;
        if (i >= 1024) return;
        const int ntg = i >> 9, rr = i & 511;
        const int lane = rr >> 3, j = rr & 7;
        const int k = (lane >> 4) * 8 + j;
        const int n = ntg * 16 + (lane & 15);
        const float v = (k < 27) ? w1[n * 27 + k] : 0.f;
        const _Float16 h = (_Float16)v;
        B1h[i] = h;
        B1l[i] = (_Float16)(v - (float)h);
        return;
    }
    const float* w; int CIN, COUT, off;
    if (idx < 9216)        { w = w2; CIN = 32;  COUT = 32;  off = 0; }
    else if (idx < 27648)  { idx -= 9216;   w = w3; CIN = 32;  COUT = 64;  off = 9216; }
    else if (idx < 64512)  { idx -= 27648;  w = w4; CIN = 64;  COUT = 64;  off = 27648; }
    else if (idx < 138240) { idx -= 64512;  w = w5; CIN = 64;  COUT = 128; off = 64512; }
    else                   { idx -= 138240; w = w6; CIN = 128; COUT = 128; off = 138240; }
    const int NT  = COUT / 16;
    const int c   = idx / (NT * 512);
    const int r   = idx - c * NT * 512;
    const int ntg = r >> 9;
    const int rr  = r & 511;
    const int lane = rr >> 3, j = rr & 7;
    const int k   = c * 32 + (lane >> 4) * 8 + j;
    const int tap = k / CIN, ci = k - tap * CIN;
    const int oc  = ntg * 16 + (lane & 15);
    const float v = w[(oc * CIN + ci) * 9 + tap];
    const _Float16 h = (_Float16)v;
    Bh[off + idx] = h;
    Bl[off + idx] = (_Float16)(v - (float)h);
}

// ---------------------------------------------------------------------------
// MFMA implicit-GEMM conv3x3, fp16x3 split (fp32-class: ll term <= 2^-22 rel).
// BM=128, BN=64 per block; 4 waves, wave = 2 m-tiles x 4 n-tiles.
// BK=64 (R8) for CIN>=64: stage two 32-k chunks per barrier pair (barriers
// halve); a 64-k window never crosses a tap when CIN>=64. MFMA order per
// 32-chunk unchanged -> bitwise-identical results. PS=68 (stride 136B = 2
// dwords mod 32 -> 2-way free). conv3 (CIN=32) keeps BK=32/PS=40.
// ---------------------------------------------------------------------------
template<int CIN, int COUT, int HW, bool OUTF32, int BK>
__global__ __launch_bounds__(256, 2)
void k_mgemm(const _Float16* __restrict__ inh, const _Float16* __restrict__ inl,
             const _Float16* __restrict__ Bh, const _Float16* __restrict__ Bl,
             const float* __restrict__ bias,
             _Float16* __restrict__ outh, _Float16* __restrict__ outl,
             float* __restrict__ outf)
{
    constexpr int NCH = CIN * 9 / BK;
    constexpr int SUB = BK / 32;
    constexpr int NT  = COUT / 16;
    constexpr int LOG = (HW == 32) ? 5 : 4;
    constexpr int PS  = BK + ((BK == 64) ? 4 : 8);
    constexpr int NJ  = BK / 16;          // staging iterations
    constexpr int GPR = BK / 8;           // half8 groups per row
    __shared__ _Float16 Ash[128 * PS];
    __shared__ _Float16 Asl[128 * PS];

    const int t    = threadIdx.x;
    const int wv   = t >> 6;
    const int lane = t & 63;
    const int m0   = blockIdx.x * 128;
    const int nb   = blockIdx.y;

    int sm[NJ], sg[NJ], sb[NJ], sy[NJ], sx[NJ];
    #pragma unroll
    for (int j = 0; j < NJ; ++j) {
        const int q = t + 256 * j;
        sm[j] = q / GPR;
        sg[j] = q - sm[j] * GPR;
        const int m  = m0 + sm[j];
        const int yx = m & (HW * HW - 1);
        sb[j] = m >> (2 * LOG);
        sy[j] = yx >> LOG;
        sx[j] = yx & (HW - 1);
    }

    const int mt0 = wv * 2;
    const int fr  = lane >> 4;
    const int ml  = lane & 15;

    float4_t acc[2][4];
    #pragma unroll
    for (int mt = 0; mt < 2; ++mt)
        #pragma unroll
        for (int tn = 0; tn < 4; ++tn)
            acc[mt][tn] = (float4_t){0.f, 0.f, 0.f, 0.f};

    #pragma unroll 1
    for (int ch = 0; ch < NCH; ++ch) {
        const int kb  = ch * BK;
        const int tap = kb / CIN;
        const int c0  = kb - tap * CIN;
        const int dy  = tap / 3 - 1, dx = tap - (tap / 3) * 3 - 1;

        if (ch) __syncthreads();
        #pragma unroll
        for (int j = 0; j < NJ; ++j) {
            const int iy = sy[j] + dy, ix = sx[j] + dx;
            half8_t vh = {0, 0, 0, 0, 0, 0, 0, 0};
            half8_t vl = {0, 0, 0, 0, 0, 0, 0, 0};
            if ((unsigned)iy < (unsigned)HW && (unsigned)ix < (unsigned)HW) {
                const int o = ((sb[j] * HW + iy) * HW + ix) * CIN + c0 + sg[j] * 8;
                vh = *(const half8_t*)(inh + o);
                vl = *(const half8_t*)(inl + o);
            }
            *(half8_t*)(&Ash[sm[j] * PS + sg[j] * 8]) = vh;
            *(half8_t*)(&Asl[sm[j] * PS + sg[j] * 8]) = vl;
        }
        __syncthreads();

        #pragma unroll
        for (int ss = 0; ss < SUB; ++ss) {
            half8_t ah[2], al[2];
            #pragma unroll
            for (int mt = 0; mt < 2; ++mt) {
                const int mr = (mt0 + mt) * 16 + ml;
                ah[mt] = *(const half8_t*)(&Ash[mr * PS + ss * 32 + fr * 8]);
                al[mt] = *(const half8_t*)(&Asl[mr * PS + ss * 32 + fr * 8]);
            }
            half8_t bh[4], bl[4];
            #pragma unroll
            for (int tn = 0; tn < 4; ++tn) {
                const int bo = (((ch * SUB + ss) * NT + nb * 4 + tn) * 64 + lane) * 8;
                bh[tn] = *(const half8_t*)(Bh + bo);
                bl[tn] = *(const half8_t*)(Bl + bo);
            }
            #pragma unroll
            for (int tn = 0; tn < 4; ++tn)
                #pragma unroll
                for (int mt = 0; mt < 2; ++mt)
                    acc[mt][tn] = __builtin_amdgcn_mfma_f32_16x16x32_f16(ah[mt], bh[tn], acc[mt][tn], 0, 0, 0);
            #pragma unroll
            for (int tn = 0; tn < 4; ++tn)
                #pragma unroll
                for (int mt = 0; mt < 2; ++mt)
                    acc[mt][tn] = __builtin_amdgcn_mfma_f32_16x16x32_f16(al[mt], bh[tn], acc[mt][tn], 0, 0, 0);
            #pragma unroll
            for (int tn = 0; tn < 4; ++tn)
                #pragma unroll
                for (int mt = 0; mt < 2; ++mt)
                    acc[mt][tn] = __builtin_amdgcn_mfma_f32_16x16x32_f16(ah[mt], bl[tn], acc[mt][tn], 0, 0, 0);
            // (al,bl) term dropped: <= 2^-22 relative contribution.
        }
    }

    // epilogue: C/D frag col=lane&15, row=(lane>>4)*4+reg  [guide m89/m91]
    #pragma unroll
    for (int mt = 0; mt < 2; ++mt)
        #pragma unroll
        for (int tn = 0; tn < 4; ++tn) {
            const int oc = nb * 64 + tn * 16 + ml;
            const float bv = bias[oc];
            #pragma unroll
            for (int r = 0; r < 4; ++r) {
                const int m = m0 + (mt0 + mt) * 16 + fr * 4 + r;
                const float v = fmaxf(acc[mt][tn][r] + bv, 0.f);
                if (OUTF32) {
                    outf[m * COUT + oc] = v;
                } else {
                    const _Float16 h = (_Float16)v;
                    outh[m * COUT + oc] = h;
                    outl[m * COUT + oc] = (_Float16)(v - (float)h);
                }
            }
        }
}

// ---------------------------------------------------------------------------
// 2x2 maxpool on dual fp16 planes, NHWC [128][32][32][64] -> [128][16][16][64]
// ---------------------------------------------------------------------------
__global__ __launch_bounds__(256)
void k_pool2h(const _Float16* __restrict__ inh, const _Float16* __restrict__ inl,
              _Float16* __restrict__ outh, _Float16* __restrict__ outl)
{
    const int g = blockIdx.x * 256 + threadIdx.x;
    const int c4 = g & 15, xo = (g >> 4) & 15, yo = (g >> 8) & 15, b = g >> 12;
    const int base = ((b * 32 + yo * 2) * 32 + xo * 2) * 64 + c4 * 4;
    const int offs[4] = {0, 64, 2048, 2112};
    float mx[4] = {-1e30f, -1e30f, -1e30f, -1e30f};
    #pragma unroll
    for (int cnd = 0; cnd < 4; ++cnd) {
        const half4_t h = *(const half4_t*)(inh + base + offs[cnd]);
        const half4_t l = *(const half4_t*)(inl + base + offs[cnd]);
        #pragma unroll
        for (int e = 0; e < 4; ++e)
            mx[e] = fmaxf(mx[e], (float)h[e] + (float)l[e]);
    }
    half4_t oh, ol;
    #pragma unroll
    for (int e = 0; e < 4; ++e) {
        const _Float16 h = (_Float16)mx[e];
        oh[e] = h;
        ol[e] = (_Float16)(mx[e] - (float)h);
    }
    const int ob = ((b * 16 + yo) * 16 + xo) * 64 + c4 * 4;
    *(half4_t*)(outh + ob) = oh;
    *(half4_t*)(outl + ob) = ol;
}

// ---------------------------------------------------------------------------
// Split-K FC partial (fp32): A[128 x K] @ B[K x 512] -> part[ky][128][512]
// ---------------------------------------------------------------------------
template<int LDA, int KCHUNK, int TN, bool PERM>
__global__ __launch_bounds__(256, 2)
void k_fc_partial(const float* __restrict__ A, const float* __restrict__ Bw,
                  float* __restrict__ part)
{
    constexpr int BN = 16 * TN;
    constexpr int SA = 140;
    constexpr int SB = (BN == 128) ? 140 : 68;
    __shared__ __align__(16) float As[32 * SA];
    __shared__ __align__(16) float Bs[32 * SB];
    const int t  = threadIdx.x;
    const int tm = t >> 4, tn = t & 15;
    const int n0 = blockIdx.x * BN;
    const int k0 = blockIdx.y * KCHUNK;

    float acc[8][TN];
    #pragma unroll
    for (int r = 0; r < 8; ++r)
        #pragma unroll
        for (int c = 0; c < TN; ++c) acc[r][c] = 0.f;

    #pragma unroll 1
    for (int ks = 0; ks < KCHUNK / 32; ++ks) {
        if (ks) __syncthreads();
        const int kb = k0 + ks * 32;
        for (int i = t; i < 4096; i += 256) {
            const int m = i >> 5, kk = i & 31;
            As[kk * SA + m + ((m >> 5) << 2)] = A[m * LDA + kb + kk];
        }
        for (int i = t; i < 32 * BN; i += 256) {
            const int kk = i / BN, n = i - kk * BN;
            const int krow = kb + kk;
            const int kref = PERM ? ((krow & 127) * 256 + (krow >> 7)) : krow;
            Bs[kk * SB + n + ((n >> 5) << 2)] = Bw[kref * 512 + n0 + n];
        }
        __syncthreads();
        #pragma unroll 2
        for (int kk = 0; kk < 32; ++kk) {
            const float* ap = &As[kk * SA + tm * 8 + ((tm >> 2) << 2)];
            const float* bp = &Bs[kk * SB + tn * TN + (((tn * TN) >> 5) << 2)];
            float a[8], bb[TN];
            #pragma unroll
            for (int q = 0; q < 8; q += 4) {
                const float4 v = *(const float4*)(ap + q);
                a[q] = v.x; a[q + 1] = v.y; a[q + 2] = v.z; a[q + 3] = v.w;
            }
            #pragma unroll
            for (int q = 0; q < TN; q += 4) {
                const float4 v = *(const float4*)(bp + q);
                bb[q] = v.x; bb[q + 1] = v.y; bb[q + 2] = v.z; bb[q + 3] = v.w;
            }
            #pragma unroll
            for (int r = 0; r < 8; ++r)
                #pragma unroll
                for (int c = 0; c < TN; ++c)
                    acc[r][c] = fmaf(a[r], bb[c], acc[r][c]);
        }
    }

    const long pb = (long)blockIdx.y * 65536;
    #pragma unroll
    for (int r = 0; r < 8; ++r)
        #pragma unroll
        for (int c = 0; c < TN; ++c)
            part[pb + (tm * 8 + r) * 512 + n0 + tn * TN + c] = acc[r][c];
}

template<int NS>
__global__ __launch_bounds__(256)
void k_fc_reduce(const float* __restrict__ part, const float* __restrict__ bias,
                 float* __restrict__ H)
{
    const int f = (blockIdx.x * 256 + threadIdx.x) * 4;
    const int m = f >> 9, n = f & 511;
    float s0 = 0.f, s1 = 0.f, s2 = 0.f, s3 = 0.f;
    #pragma unroll 4
    for (int q = 0; q < NS; ++q) {
        const float* p = &part[(q * 128 + m) * 512 + n];
        s0 += p[0]; s1 += p[1]; s2 += p[2]; s3 += p[3];
    }
    H[f]     = fmaxf(s0 + bias[n],     0.f);
    H[f + 1] = fmaxf(s1 + bias[n + 1], 0.f);
    H[f + 2] = fmaxf(s2 + bias[n + 2], 0.f);
    H[f + 3] = fmaxf(s3 + bias[n + 3], 0.f);
}

// ---------------------------------------------------------------------------
// Final: FC3 + sampling + patch gather
// ---------------------------------------------------------------------------
__device__ __forceinline__ float softplusf(float x) {
    return (x > 20.f) ? x : log1pf(expf(x));
}
__device__ __forceinline__ float sigmoidf_(float x) {
    return 1.f / (1.f + expf(-x));
}

__global__ __launch_bounds__(256)
void k_final(const float* __restrict__ H2, const float* __restrict__ wl3,
             const float* __restrict__ bl3, const float* __restrict__ noise,
             const float* __restrict__ img, float* __restrict__ outp)
{
    __shared__ float h2[512];
    __shared__ float red[144];
    __shared__ float prep[36];
    __shared__ int ptsh[12], ptsw[12];
    const int b = blockIdx.x, t = threadIdx.x;

    h2[t]       = H2[b * 512 + t];
    h2[t + 256] = H2[b * 512 + 256 + t];
    __syncthreads();

    if (t < 144) {
        const int n = t >> 2, q = t & 3;
        float s = 0.f;
        for (int k = q * 128; k < q * 128 + 128; ++k)
            s = fmaf(h2[k], wl3[k * 36 + n], s);
        red[t] = s;
    }
    __syncthreads();
    if (t < 36)
        prep[t] = red[t * 4] + red[t * 4 + 1] + red[t * 4 + 2] + red[t * 4 + 3] + bl3[t];
    __syncthreads();

    if (t < 12) {
        const float m0 = prep[t * 3], m1 = prep[t * 3 + 1], sv = prep[t * 3 + 2];
        const float sig = softplusf(sv + 2.0f) * 128.f + 1e-7f;
        const float n0 = noise[(b * 12 + t) * 2], n1 = noise[(b * 12 + t) * 2 + 1];
        const float sa0 = m0 + sig * n0;
        const float sa1 = m1 + sig * n1;
        int p0 = (int)rintf(sigmoidf_(sa0) * 111.f);
        int p1 = (int)rintf(sigmoidf_(sa1) * 111.f);
        p0 = min(max(p0, 0), 111);
        p1 = min(max(p1, 0), 111);
        const int RM = 1179648;
        outp[RM        + (b * 12 + t) * 2 + 0] = m0;
        outp[RM        + (b * 12 + t) * 2 + 1] = m1;
        outp[RM + 3072 + (b * 12 + t) * 2 + 0] = sig;
        outp[RM + 3072 + (b * 12 + t) * 2 + 1] = sig;
        outp[RM + 6144 + (b * 12 + t) * 2 + 0] = sa0;
        outp[RM + 6144 + (b * 12 + t) * 2 + 1] = sa1;
        ptsh[t] = p0;
        ptsw[t] = p1;
    }
    __syncthreads();

    for (int i = t; i < 9216; i += 256) {
        const int g  = i / 768, r = i - g * 768;
        const int c  = r >> 8, r2 = r & 255;
        const int y  = r2 >> 4, x = r2 & 15;
        outp[b * 9216 + i] = img[((b * 3 + c) * 128 + ptsh[g] + y) * 128 + (ptsw[g] + x)];
    }
}

// ---------------------------------------------------------------------------
extern "C" void kernel_launch(void* const* d_in, const int* in_sizes, int n_in,
                              void* d_out, int out_size, void* d_ws, size_t ws_size,
                              hipStream_t stream)
{
    const float* img  = (const float*)d_in[0];
    const float* nois = (const float*)d_in[1];
    const float* w1 = (const float*)d_in[2];  const float* b1 = (const float*)d_in[3];
    const float* w2 = (const float*)d_in[4];  const float* b2 = (const float*)d_in[5];
    const float* w3 = (const float*)d_in[6];  const float* b3 = (const float*)d_in[7];
    const float* w4 = (const float*)d_in[8];  const float* b4 = (const float*)d_in[9];
    const float* w5 = (const float*)d_in[10]; const float* b5 = (const float*)d_in[11];
    const float* w6 = (const float*)d_in[12]; const float* b6 = (const float*)d_in[13];
    const float* wl1 = (const float*)d_in[14]; const float* bl1 = (const float*)d_in[15];
    const float* wl2 = (const float*)d_in[16]; const float* bl2 = (const float*)d_in[17];
    const float* wl3 = (const float*)d_in[18]; const float* bl3 = (const float*)d_in[19];
    float* out = (float*)d_out;
    float* ws  = (float*)d_ws;

    // workspace (float units). Activation regions span [0 .. 20971520).
    // Weight packs live ABOVE all activations, EXCEPT the tiny w1 frag pack,
    // which sits in [17956864..17957888) -- inside A4l's range but only live
    // before conv4 writes A4l (wrepackm -> conv12 both precede conv4).
    _Float16* P1h = (_Float16*)(ws);               // [128*32*32*32] halves
    _Float16* P1l = (_Float16*)(ws + 2097152);
    _Float16* A3h = (_Float16*)(ws + 4194304);     // [128*32*32*64]
    _Float16* A3l = (_Float16*)(ws + 8388608);
    _Float16* A4h = (_Float16*)(ws + 12582912);    // [128*32*32*64]
    _Float16* A4l = (_Float16*)(ws + 16777216);    // ..20971520
    _Float16* P2h = (_Float16*)(ws);               // [128*16*16*64] (P1 dead)
    _Float16* P2l = (_Float16*)(ws + 1048576);
    _Float16* A5h = (_Float16*)(ws + 4194304);     // [128*16*16*128] (A3 dead)
    _Float16* A5l = (_Float16*)(ws + 6291456);
    float* A6  = ws + 8388608;                     // [128*16*16*128] fp32 (A3 dead)
    float* FP1 = ws + 12582912;                    // [64][128][512] (A4h dead)
    float* H1  = ws + 16777216;                    // [128][512]     (A4l dead)
    float* FP2 = ws + 16842752;                    // [16][128][512]
    float* H2  = ws + 17891328;                    // [128][512]
    _Float16* B1h = (_Float16*)(ws + 17956864);    // 1024 halves (w1 pack)
    _Float16* B1l = (_Float16*)(ws + 17957376);
    _Float16* Bh = (_Float16*)(ws + 20971520);     // 285696 halves (w2..w6)
    _Float16* Bl = (_Float16*)(ws + 21114368);     // ends 21257216 fl = 85 MB

    hipLaunchKernelGGL(k_wrepackm, dim3(1120), dim3(256), 0, stream,
                       w1, w2, w3, w4, w5, w6, Bh, Bl, B1h, B1l);

    // conv1+conv2+pool4: grid = 8x8 tiles x 128 batch
    hipLaunchKernelGGL(k_conv12, dim3(64, 128), dim3(256), 0, stream,
                       img, b1, B1h, B1l, Bh + 0, Bl + 0, b2, P1h, P1l);
    // conv3: M=131072, K=288, COUT=64 (CIN=32 -> BK=32)
    hipLaunchKernelGGL((k_mgemm<32, 64, 32, false, 32>), dim3(1024, 1), dim3(256), 0, stream,
                       P1h, P1l, Bh + 9216, Bl + 9216, b3, A3h, A3l, nullptr);
    // conv4: K=576, BK=64
    hipLaunchKernelGGL((k_mgemm<64, 64, 32, false, 64>), dim3(1024, 1), dim3(256), 0, stream,
                       A3h, A3l, Bh + 27648, Bl + 27648, b4, A4h, A4l, nullptr);
    hipLaunchKernelGGL(k_pool2h, dim3(2048), dim3(256), 0, stream, A4h, A4l, P2h, P2l);
    // conv5: M=32768, K=576, COUT=128, BK=64
    hipLaunchKernelGGL((k_mgemm<64, 128, 16, false, 64>), dim3(256, 2), dim3(256), 0, stream,
                       P2h, P2l, Bh + 64512, Bl + 64512, b5, A5h, A5l, nullptr);
    // conv6: K=1152, fp32 out for FC1, BK=64
    hipLaunchKernelGGL((k_mgemm<128, 128, 16, true, 64>), dim3(256, 2), dim3(256), 0, stream,
                       A5h, A5l, Bh + 138240, Bl + 138240, b6, nullptr, nullptr, A6);
    hipLaunchKernelGGL((k_fc_partial<32768, 512, 4, true>), dim3(8, 64), dim3(256), 0, stream,
                       A6, wl1, FP1);
    hipLaunchKernelGGL(k_fc_reduce<64>, dim3(64), dim3(256), 0, stream, FP1, bl1, H1);
    hipLaunchKernelGGL((k_fc_partial<512, 32, 4, false>), dim3(8, 16), dim3(256), 0, stream,
                       H1, wl2, FP2);
    hipLaunchKernelGGL(k_fc_reduce<16>, dim3(64), dim3(256), 0, stream, FP2, bl2, H2);
    hipLaunchKernelGGL(k_final, dim3(128), dim3(256), 0, stream,
                       H2, wl3, bl3, nois, img, out);
}

// Round 10
// 550.077 us; speedup vs baseline: 1.5262x; 1.0790x over previous
//
#include <hip/hip_runtime.h>
#include <math.h>

typedef _Float16 __attribute__((ext_vector_type(8))) half8_t;
typedef _Float16 __attribute__((ext_vector_type(4))) half4_t;
typedef _Float16 __attribute__((ext_vector_type(2))) half2_t;
typedef float    __attribute__((ext_vector_type(4))) float4_t;

// ---------------------------------------------------------------------------
// Kernel 1: fully-MFMA conv1 + conv2 + maxpool4 (block = 16x16 output tile).
// Phase A: img -> simg (fp32 LDS halo-2) -> im2col into
//   C1h[slot=k/8][pos=18*18][j=k&7] fp16 HI ONLY (R8).
// Phase B: conv1 GEMM transposed: M=32 ch, N=324 pos, K=32, 2-term (wh+wl)*xh.
// Phase C: epilogue -> C1h overwrite, HI ONLY (R10: conv1-out lo dropped too;
//   same 2^-11 class perturbation as R8's input drop, absmax budget 20.48).
// Phase D: conv2 implicit GEMM 2-term (ah*bh + ah*bl) + thread-local 4x4 pool.
// LDS = 6000(simg) + 21504(C1h) = 27.5 KB -> 5 blocks/CU (R10 occupancy win).
// POSP=336 (mult of 8: swizzle bijective, R2); idx per (slot,pos) (R5).
// ---------------------------------------------------------------------------
#define POSP 336

__device__ __forceinline__ int c1idx(int slot, int pos) {
    return ((slot * POSP + pos) * 8) ^ (((pos >> 3) & 7) << 3);
}

__global__ __launch_bounds__(256, 5)
void k_conv12(const float* __restrict__ img, const float* __restrict__ b1,
              const _Float16* __restrict__ B1h, const _Float16* __restrict__ B1l,
              const _Float16* __restrict__ B2h, const _Float16* __restrict__ B2l,
              const float* __restrict__ b2,
              _Float16* __restrict__ P1h, _Float16* __restrict__ P1l)
{
    __shared__ float simg[3 * 20 * 25];                    // input halo-2
    __shared__ __align__(16) _Float16 C1h[4 * POSP * 8];   // A, then conv1 out

    const int t  = threadIdx.x;
    const int bt = blockIdx.x;
    const int b  = blockIdx.y;
    const int ty = bt >> 3, tx = bt & 7;
    const int oy = ty * 16, ox = tx * 16;

    // ---- Phase A1: stage fp32 halo (bounds-checked ONCE, zero-padded) ----
    for (int i = t; i < 1500; i += 256) {
        const int ci = i / 500, r = i - ci * 500;
        const int yy = r / 25, xx = r - yy * 25;
        const int gy = oy - 2 + yy, gx = ox - 2 + xx;
        float v = 0.f;
        if ((unsigned)gy < 128u && (unsigned)gx < 128u)
            v = img[((b * 3 + ci) * 128 + gy) * 128 + gx];
        simg[i] = v;
    }
    __syncthreads();

    // ---- Phase A2: im2col simg -> C1h (hi only; compile-time tap offsets) --
    #pragma unroll
    for (int hf = 0; hf < 2; ++hf) {
        const int pos = hf * 256 + t;
        if (pos < POSP) {
            const bool val = pos < 324;
            int sb = 0;
            if (val) {
                const int py = pos / 18, px = pos - py * 18;
                sb = py * 25 + px;
            }
            #pragma unroll
            for (int s = 0; s < 4; ++s) {
                half8_t vh = {0,0,0,0,0,0,0,0};
                if (val) {
                    #pragma unroll
                    for (int j = 0; j < 8; ++j) {
                        const int k = s * 8 + j;
                        if (k < 27) {
                            const int ci = k / 9, tap = k - ci * 9;   // const
                            const int dy = tap / 3, dx = tap - dy * 3; // const
                            vh[j] = (_Float16)simg[sb + (ci * 20 + dy) * 25 + dx];
                        }
                    }
                }
                *(half8_t*)(&C1h[c1idx(s, pos)]) = vh;
            }
        }
    }
    __syncthreads();

    const int wv   = __builtin_amdgcn_readfirstlane(t >> 6);
    const int lane = t & 63;
    const int fr   = lane >> 4;
    const int ml   = lane & 15;

    // ---- Phase B: conv1 MFMA, transposed, 2-term: D[ch][pos] = w @ xh ----
    half8_t wAh[2], wAl[2];
    #pragma unroll
    for (int mt = 0; mt < 2; ++mt) {
        wAh[mt] = *(const half8_t*)(B1h + (mt * 64 + lane) * 8);
        wAl[mt] = *(const half8_t*)(B1l + (mt * 64 + lane) * 8);
    }
    float4_t acc1[6][2];
    #pragma unroll
    for (int q = 0; q < 6; ++q)
        #pragma unroll
        for (int mt = 0; mt < 2; ++mt)
            acc1[q][mt] = (float4_t){0.f, 0.f, 0.f, 0.f};

    #pragma unroll
    for (int q = 0; q < 6; ++q) {
        const int nt = wv + q * 4;
        if (nt < 21) {
            const int ri = c1idx(fr, nt * 16 + ml);
            const half8_t dh = *(const half8_t*)(&C1h[ri]);
            #pragma unroll
            for (int mt = 0; mt < 2; ++mt) {
                acc1[q][mt] = __builtin_amdgcn_mfma_f32_16x16x32_f16(wAh[mt], dh, acc1[q][mt], 0, 0, 0);
                acc1[q][mt] = __builtin_amdgcn_mfma_f32_16x16x32_f16(wAl[mt], dh, acc1[q][mt], 0, 0, 0);
            }
        }
    }
    __syncthreads();          // all A reads done; buffer reusable

    // ---- Phase C: epilogue -> overwrite C1h (hi only). Thread: 4
    //      consecutive ch at one pos per (q,mt); ONE bounds mask per q.
    const float4_t bA = *(const float4_t*)(b1 + fr * 4);
    const float4_t bB = *(const float4_t*)(b1 + 16 + fr * 4);
    #pragma unroll
    for (int q = 0; q < 6; ++q) {
        const int nt = wv + q * 4;
        if (nt < 21) {
            const int pos = nt * 16 + ml;
            if (pos < 324) {
                const int py = pos / 18, px = pos - py * 18;
                const int gy = oy + py - 1, gx = ox + px - 1;
                const bool ok = (unsigned)gy < 128u && (unsigned)gx < 128u;
                #pragma unroll
                for (int mt = 0; mt < 2; ++mt) {
                    const int slot = mt * 2 + (fr >> 1);
                    const int wi = c1idx(slot, pos) + (fr & 1) * 4;
                    const float4_t bb = mt ? bB : bA;
                    half4_t oh;
                    #pragma unroll
                    for (int r = 0; r < 4; ++r) {
                        const float v = ok ? fmaxf(acc1[q][mt][r] + bb[r], 0.f) : 0.f;
                        oh[r] = (_Float16)v;
                    }
                    *(half4_t*)(&C1h[wi]) = oh;
                }
            }
        }
    }
    __syncthreads();

    // ---- Phase D: conv2 implicit-GEMM 2-term, wave wv owns rows wv*4.. ----
    float4_t acc[4][2];
    #pragma unroll
    for (int i = 0; i < 4; ++i)
        #pragma unroll
        for (int nt = 0; nt < 2; ++nt)
            acc[i][nt] = (float4_t){0.f, 0.f, 0.f, 0.f};

    #pragma unroll 1
    for (int tap = 0; tap < 9; ++tap) {
        const int dy = tap / 3, dx = tap - dy * 3;
        half8_t bh[2], bl[2];
        #pragma unroll
        for (int nt = 0; nt < 2; ++nt) {
            const int bo = ((tap * 2 + nt) * 64 + lane) * 8;
            bh[nt] = *(const half8_t*)(B2h + bo);
            bl[nt] = *(const half8_t*)(B2l + bo);
        }
        half8_t ah[4];
        #pragma unroll
        for (int i = 0; i < 4; ++i) {
            const int pos = (wv * 4 + i + dy) * 18 + ml + dx;
            ah[i] = *(const half8_t*)(&C1h[c1idx(fr, pos)]);
        }
        #pragma unroll
        for (int nt = 0; nt < 2; ++nt)
            #pragma unroll
            for (int i = 0; i < 4; ++i)
                acc[i][nt] = __builtin_amdgcn_mfma_f32_16x16x32_f16(ah[i], bh[nt], acc[i][nt], 0, 0, 0);
        #pragma unroll
        for (int nt = 0; nt < 2; ++nt)
            #pragma unroll
            for (int i = 0; i < 4; ++i)
                acc[i][nt] = __builtin_amdgcn_mfma_f32_16x16x32_f16(ah[i], bl[nt], acc[i][nt], 0, 0, 0);
    }

    // ---- maxpool4 (thread-local) + bias + relu + hi/lo store ----
    const int py = ty * 4 + wv;
    const int px = tx * 4 + fr;
    #pragma unroll
    for (int nt = 0; nt < 2; ++nt) {
        float m = -1e30f;
        #pragma unroll
        for (int i = 0; i < 4; ++i)
            #pragma unroll
            for (int r = 0; r < 4; ++r)
                m = fmaxf(m, acc[i][nt][r]);
        const int oc = nt * 16 + ml;
        const float v = fmaxf(m + b2[oc], 0.f);
        const _Float16 h = (_Float16)v;
        const int base = ((b * 32 + py) * 32 + px) * 32 + oc;
        P1h[base] = h;
        P1l[base] = (_Float16)(v - (float)h);
    }
}

// ---------------------------------------------------------------------------
// Weight repack: fp16 hi/lo MFMA-fragment packs for w2..w6 (+ w1, K padded
// 27->32). Frag order: Bh[((c*NT + ntg)*64 + lane)*8 + j], element B[k][n]:
//   n = ntg*16 + (lane&15), k = c*32 + (lane>>4)*8 + j.
// w2..w6: k = tap*CIN + ci.  w1: k = ci*9 + tap (= w1 natural order).
// ---------------------------------------------------------------------------
__global__ void k_wrepackm(const float* __restrict__ w1, const float* __restrict__ w2,
                           const float* __restrict__ w3, const float* __restrict__ w4,
                           const float* __restrict__ w5, const float* __restrict__ w6,
                           _Float16* __restrict__ Bh, _Float16* __restrict__ Bl,
                           _Float16* __restrict__ B1h, _Float16* __restrict__ B1l)
{
    int idx = blockIdx.x * 256 + threadIdx.x;
    if (idx >= 285696) {
        const int i = idx - 285696;
        if (i >= 1024) return;
        const int ntg = i >> 9, rr = i & 511;
        const int lane = rr >> 3, j = rr & 7;
        const int k = (lane >> 4) * 8 + j;
        const int n = ntg * 16 + (lane & 15);
        const float v = (k < 27) ? w1[n * 27 + k] : 0.f;
        const _Float16 h = (_Float16)v;
        B1h[i] = h;
        B1l[i] = (_Float16)(v - (float)h);
        return;
    }
    const float* w; int CIN, COUT, off;
    if (idx < 9216)        { w = w2; CIN = 32;  COUT = 32;  off = 0; }
    else if (idx < 27648)  { idx -= 9216;   w = w3; CIN = 32;  COUT = 64;  off = 9216; }
    else if (idx < 64512)  { idx -= 27648;  w = w4; CIN = 64;  COUT = 64;  off = 27648; }
    else if (idx < 138240) { idx -= 64512;  w = w5; CIN = 64;  COUT = 128; off = 64512; }
    else                   { idx -= 138240; w = w6; CIN = 128; COUT = 128; off = 138240; }
    const int NT  = COUT / 16;
    const int c   = idx / (NT * 512);
    const int r   = idx - c * NT * 512;
    const int ntg = r >> 9;
    const int rr  = r & 511;
    const int lane = rr >> 3, j = rr & 7;
    const int k   = c * 32 + (lane >> 4) * 8 + j;
    const int tap = k / CIN, ci = k - tap * CIN;
    const int oc  = ntg * 16 + (lane & 15);
    const float v = w[(oc * CIN + ci) * 9 + tap];
    const _Float16 h = (_Float16)v;
    Bh[off + idx] = h;
    Bl[off + idx] = (_Float16)(v - (float)h);
}

// ---------------------------------------------------------------------------
// MFMA implicit-GEMM conv3x3, fp16x3 split (fp32-class: ll term <= 2^-22 rel).
// BM=128, BN=64 per block; 4 waves, wave = 2 m-tiles x 4 n-tiles.
// BK=64 for CIN>=64: two 32-k chunks per barrier pair; MFMA order per
// 32-chunk unchanged -> bitwise-identical. PS=68 (2-way free). conv3 BK=32.
// ---------------------------------------------------------------------------
template<int CIN, int COUT, int HW, bool OUTF32, int BK>
__global__ __launch_bounds__(256, 2)
void k_mgemm(const _Float16* __restrict__ inh, const _Float16* __restrict__ inl,
             const _Float16* __restrict__ Bh, const _Float16* __restrict__ Bl,
             const float* __restrict__ bias,
             _Float16* __restrict__ outh, _Float16* __restrict__ outl,
             float* __restrict__ outf)
{
    constexpr int NCH = CIN * 9 / BK;
    constexpr int SUB = BK / 32;
    constexpr int NT  = COUT / 16;
    constexpr int LOG = (HW == 32) ? 5 : 4;
    constexpr int PS  = BK + ((BK == 64) ? 4 : 8);
    constexpr int NJ  = BK / 16;          // staging iterations
    constexpr int GPR = BK / 8;           // half8 groups per row
    __shared__ _Float16 Ash[128 * PS];
    __shared__ _Float16 Asl[128 * PS];

    const int t    = threadIdx.x;
    const int wv   = t >> 6;
    const int lane = t & 63;
    const int m0   = blockIdx.x * 128;
    const int nb   = blockIdx.y;

    int sm[NJ], sg[NJ], sb[NJ], sy[NJ], sx[NJ];
    #pragma unroll
    for (int j = 0; j < NJ; ++j) {
        const int q = t + 256 * j;
        sm[j] = q / GPR;
        sg[j] = q - sm[j] * GPR;
        const int m  = m0 + sm[j];
        const int yx = m & (HW * HW - 1);
        sb[j] = m >> (2 * LOG);
        sy[j] = yx >> LOG;
        sx[j] = yx & (HW - 1);
    }

    const int mt0 = wv * 2;
    const int fr  = lane >> 4;
    const int ml  = lane & 15;

    float4_t acc[2][4];
    #pragma unroll
    for (int mt = 0; mt < 2; ++mt)
        #pragma unroll
        for (int tn = 0; tn < 4; ++tn)
            acc[mt][tn] = (float4_t){0.f, 0.f, 0.f, 0.f};

    #pragma unroll 1
    for (int ch = 0; ch < NCH; ++ch) {
        const int kb  = ch * BK;
        const int tap = kb / CIN;
        const int c0  = kb - tap * CIN;
        const int dy  = tap / 3 - 1, dx = tap - (tap / 3) * 3 - 1;

        if (ch) __syncthreads();
        #pragma unroll
        for (int j = 0; j < NJ; ++j) {
            const int iy = sy[j] + dy, ix = sx[j] + dx;
            half8_t vh = {0, 0, 0, 0, 0, 0, 0, 0};
            half8_t vl = {0, 0, 0, 0, 0, 0, 0, 0};
            if ((unsigned)iy < (unsigned)HW && (unsigned)ix < (unsigned)HW) {
                const int o = ((sb[j] * HW + iy) * HW + ix) * CIN + c0 + sg[j] * 8;
                vh = *(const half8_t*)(inh + o);
                vl = *(const half8_t*)(inl + o);
            }
            *(half8_t*)(&Ash[sm[j] * PS + sg[j] * 8]) = vh;
            *(half8_t*)(&Asl[sm[j] * PS + sg[j] * 8]) = vl;
        }
        __syncthreads();

        #pragma unroll
        for (int ss = 0; ss < SUB; ++ss) {
            half8_t ah[2], al[2];
            #pragma unroll
            for (int mt = 0; mt < 2; ++mt) {
                const int mr = (mt0 + mt) * 16 + ml;
                ah[mt] = *(const half8_t*)(&Ash[mr * PS + ss * 32 + fr * 8]);
                al[mt] = *(const half8_t*)(&Asl[mr * PS + ss * 32 + fr * 8]);
            }
            half8_t bh[4], bl[4];
            #pragma unroll
            for (int tn = 0; tn < 4; ++tn) {
                const int bo = (((ch * SUB + ss) * NT + nb * 4 + tn) * 64 + lane) * 8;
                bh[tn] = *(const half8_t*)(Bh + bo);
                bl[tn] = *(const half8_t*)(Bl + bo);
            }
            #pragma unroll
            for (int tn = 0; tn < 4; ++tn)
                #pragma unroll
                for (int mt = 0; mt < 2; ++mt)
                    acc[mt][tn] = __builtin_amdgcn_mfma_f32_16x16x32_f16(ah[mt], bh[tn], acc[mt][tn], 0, 0, 0);
            #pragma unroll
            for (int tn = 0; tn < 4; ++tn)
                #pragma unroll
                for (int mt = 0; mt < 2; ++mt)
                    acc[mt][tn] = __builtin_amdgcn_mfma_f32_16x16x32_f16(al[mt], bh[tn], acc[mt][tn], 0, 0, 0);
            #pragma unroll
            for (int tn = 0; tn < 4; ++tn)
                #pragma unroll
                for (int mt = 0; mt < 2; ++mt)
                    acc[mt][tn] = __builtin_amdgcn_mfma_f32_16x16x32_f16(ah[mt], bl[tn], acc[mt][tn], 0, 0, 0);
            // (al,bl) term dropped: <= 2^-22 relative contribution.
        }
    }

    // epilogue: C/D frag col=lane&15, row=(lane>>4)*4+reg  [guide m89/m91]
    #pragma unroll
    for (int mt = 0; mt < 2; ++mt)
        #pragma unroll
        for (int tn = 0; tn < 4; ++tn) {
            const int oc = nb * 64 + tn * 16 + ml;
            const float bv = bias[oc];
            #pragma unroll
            for (int r = 0; r < 4; ++r) {
                const int m = m0 + (mt0 + mt) * 16 + fr * 4 + r;
                const float v = fmaxf(acc[mt][tn][r] + bv, 0.f);
                if (OUTF32) {
                    outf[m * COUT + oc] = v;
                } else {
                    const _Float16 h = (_Float16)v;
                    outh[m * COUT + oc] = h;
                    outl[m * COUT + oc] = (_Float16)(v - (float)h);
                }
            }
        }
}

// ---------------------------------------------------------------------------
// 2x2 maxpool on dual fp16 planes, NHWC [128][32][32][64] -> [128][16][16][64]
// ---------------------------------------------------------------------------
__global__ __launch_bounds__(256)
void k_pool2h(const _Float16* __restrict__ inh, const _Float16* __restrict__ inl,
              _Float16* __restrict__ outh, _Float16* __restrict__ outl)
{
    const int g = blockIdx.x * 256 + threadIdx.x;
    const int c4 = g & 15, xo = (g >> 4) & 15, yo = (g >> 8) & 15, b = g >> 12;
    const int base = ((b * 32 + yo * 2) * 32 + xo * 2) * 64 + c4 * 4;
    const int offs[4] = {0, 64, 2048, 2112};
    float mx[4] = {-1e30f, -1e30f, -1e30f, -1e30f};
    #pragma unroll
    for (int cnd = 0; cnd < 4; ++cnd) {
        const half4_t h = *(const half4_t*)(inh + base + offs[cnd]);
        const half4_t l = *(const half4_t*)(inl + base + offs[cnd]);
        #pragma unroll
        for (int e = 0; e < 4; ++e)
            mx[e] = fmaxf(mx[e], (float)h[e] + (float)l[e]);
    }
    half4_t oh, ol;
    #pragma unroll
    for (int e = 0; e < 4; ++e) {
        const _Float16 h = (_Float16)mx[e];
        oh[e] = h;
        ol[e] = (_Float16)(mx[e] - (float)h);
    }
    const int ob = ((b * 16 + yo) * 16 + xo) * 64 + c4 * 4;
    *(half4_t*)(outh + ob) = oh;
    *(half4_t*)(outl + ob) = ol;
}

// ---------------------------------------------------------------------------
// Split-K FC partial (fp32): A[128 x K] @ B[K x 512] -> part[ky][128][512]
// ---------------------------------------------------------------------------
template<int LDA, int KCHUNK, int TN, bool PERM>
__global__ __launch_bounds__(256, 2)
void k_fc_partial(const float* __restrict__ A, const float* __restrict__ Bw,
                  float* __restrict__ part)
{
    constexpr int BN = 16 * TN;
    constexpr int SA = 140;
    constexpr int SB = (BN == 128) ? 140 : 68;
    __shared__ __align__(16) float As[32 * SA];
    __shared__ __align__(16) float Bs[32 * SB];
    const int t  = threadIdx.x;
    const int tm = t >> 4, tn = t & 15;
    const int n0 = blockIdx.x * BN;
    const int k0 = blockIdx.y * KCHUNK;

    float acc[8][TN];
    #pragma unroll
    for (int r = 0; r < 8; ++r)
        #pragma unroll
        for (int c = 0; c < TN; ++c) acc[r][c] = 0.f;

    #pragma unroll 1
    for (int ks = 0; ks < KCHUNK / 32; ++ks) {
        if (ks) __syncthreads();
        const int kb = k0 + ks * 32;
        for (int i = t; i < 4096; i += 256) {
            const int m = i >> 5, kk = i & 31;
            As[kk * SA + m + ((m >> 5) << 2)] = A[m * LDA + kb + kk];
        }
        for (int i = t; i < 32 * BN; i += 256) {
            const int kk = i / BN, n = i - kk * BN;
            const int krow = kb + kk;
            const int kref = PERM ? ((krow & 127) * 256 + (krow >> 7)) : krow;
            Bs[kk * SB + n + ((n >> 5) << 2)] = Bw[kref * 512 + n0 + n];
        }
        __syncthreads();
        #pragma unroll 2
        for (int kk = 0; kk < 32; ++kk) {
            const float* ap = &As[kk * SA + tm * 8 + ((tm >> 2) << 2)];
            const float* bp = &Bs[kk * SB + tn * TN + (((tn * TN) >> 5) << 2)];
            float a[8], bb[TN];
            #pragma unroll
            for (int q = 0; q < 8; q += 4) {
                const float4 v = *(const float4*)(ap + q);
                a[q] = v.x; a[q + 1] = v.y; a[q + 2] = v.z; a[q + 3] = v.w;
            }
            #pragma unroll
            for (int q = 0; q < TN; q += 4) {
                const float4 v = *(const float4*)(bp + q);
                bb[q] = v.x; bb[q + 1] = v.y; bb[q + 2] = v.z; bb[q + 3] = v.w;
            }
            #pragma unroll
            for (int r = 0; r < 8; ++r)
                #pragma unroll
                for (int c = 0; c < TN; ++c)
                    acc[r][c] = fmaf(a[r], bb[c], acc[r][c]);
        }
    }

    const long pb = (long)blockIdx.y * 65536;
    #pragma unroll
    for (int r = 0; r < 8; ++r)
        #pragma unroll
        for (int c = 0; c < TN; ++c)
            part[pb + (tm * 8 + r) * 512 + n0 + tn * TN + c] = acc[r][c];
}

template<int NS>
__global__ __launch_bounds__(256)
void k_fc_reduce(const float* __restrict__ part, const float* __restrict__ bias,
                 float* __restrict__ H)
{
    const int f = (blockIdx.x * 256 + threadIdx.x) * 4;
    const int m = f >> 9, n = f & 511;
    float s0 = 0.f, s1 = 0.f, s2 = 0.f, s3 = 0.f;
    #pragma unroll 4
    for (int q = 0; q < NS; ++q) {
        const float* p = &part[(q * 128 + m) * 512 + n];
        s0 += p[0]; s1 += p[1]; s2 += p[2]; s3 += p[3];
    }
    H[f]     = fmaxf(s0 + bias[n],     0.f);
    H[f + 1] = fmaxf(s1 + bias[n + 1], 0.f);
    H[f + 2] = fmaxf(s2 + bias[n + 2], 0.f);
    H[f + 3] = fmaxf(s3 + bias[n + 3], 0.f);
}

// ---------------------------------------------------------------------------
// Final: FC3 + sampling + patch gather
// ---------------------------------------------------------------------------
__device__ __forceinline__ float softplusf(float x) {
    return (x > 20.f) ? x : log1pf(expf(x));
}
__device__ __forceinline__ float sigmoidf_(float x) {
    return 1.f / (1.f + expf(-x));
}

__global__ __launch_bounds__(256)
void k_final(const float* __restrict__ H2, const float* __restrict__ wl3,
             const float* __restrict__ bl3, const float* __restrict__ noise,
             const float* __restrict__ img, float* __restrict__ outp)
{
    __shared__ float h2[512];
    __shared__ float red[144];
    __shared__ float prep[36];
    __shared__ int ptsh[12], ptsw[12];
    const int b = blockIdx.x, t = threadIdx.x;

    h2[t]       = H2[b * 512 + t];
    h2[t + 256] = H2[b * 512 + 256 + t];
    __syncthreads();

    if (t < 144) {
        const int n = t >> 2, q = t & 3;
        float s = 0.f;
        for (int k = q * 128; k < q * 128 + 128; ++k)
            s = fmaf(h2[k], wl3[k * 36 + n], s);
        red[t] = s;
    }
    __syncthreads();
    if (t < 36)
        prep[t] = red[t * 4] + red[t * 4 + 1] + red[t * 4 + 2] + red[t * 4 + 3] + bl3[t];
    __syncthreads();

    if (t < 12) {
        const float m0 = prep[t * 3], m1 = prep[t * 3 + 1], sv = prep[t * 3 + 2];
        const float sig = softplusf(sv + 2.0f) * 128.f + 1e-7f;
        const float n0 = noise[(b * 12 + t) * 2], n1 = noise[(b * 12 + t) * 2 + 1];
        const float sa0 = m0 + sig * n0;
        const float sa1 = m1 + sig * n1;
        int p0 = (int)rintf(sigmoidf_(sa0) * 111.f);
        int p1 = (int)rintf(sigmoidf_(sa1) * 111.f);
        p0 = min(max(p0, 0), 111);
        p1 = min(max(p1, 0), 111);
        const int RM = 1179648;
        outp[RM        + (b * 12 + t) * 2 + 0] = m0;
        outp[RM        + (b * 12 + t) * 2 + 1] = m1;
        outp[RM + 3072 + (b * 12 + t) * 2 + 0] = sig;
        outp[RM + 3072 + (b * 12 + t) * 2 + 1] = sig;
        outp[RM + 6144 + (b * 12 + t) * 2 + 0] = sa0;
        outp[RM + 6144 + (b * 12 + t) * 2 + 1] = sa1;
        ptsh[t] = p0;
        ptsw[t] = p1;
    }
    __syncthreads();

    for (int i = t; i < 9216; i += 256) {
        const int g  = i / 768, r = i - g * 768;
        const int c  = r >> 8, r2 = r & 255;
        const int y  = r2 >> 4, x = r2 & 15;
        outp[b * 9216 + i] = img[((b * 3 + c) * 128 + ptsh[g] + y) * 128 + (ptsw[g] + x)];
    }
}

// ---------------------------------------------------------------------------
extern "C" void kernel_launch(void* const* d_in, const int* in_sizes, int n_in,
                              void* d_out, int out_size, void* d_ws, size_t ws_size,
                              hipStream_t stream)
{
    const float* img  = (const float*)d_in[0];
    const float* nois = (const float*)d_in[1];
    const float* w1 = (const float*)d_in[2];  const float* b1 = (const float*)d_in[3];
    const float* w2 = (const float*)d_in[4];  const float* b2 = (const float*)d_in[5];
    const float* w3 = (const float*)d_in[6];  const float* b3 = (const float*)d_in[7];
    const float* w4 = (const float*)d_in[8];  const float* b4 = (const float*)d_in[9];
    const float* w5 = (const float*)d_in[10]; const float* b5 = (const float*)d_in[11];
    const float* w6 = (const float*)d_in[12]; const float* b6 = (const float*)d_in[13];
    const float* wl1 = (const float*)d_in[14]; const float* bl1 = (const float*)d_in[15];
    const float* wl2 = (const float*)d_in[16]; const float* bl2 = (const float*)d_in[17];
    const float* wl3 = (const float*)d_in[18]; const float* bl3 = (const float*)d_in[19];
    float* out = (float*)d_out;
    float* ws  = (float*)d_ws;

    // workspace (float units). Activation regions span [0 .. 20971520).
    // Weight packs live ABOVE all activations, EXCEPT the tiny w1 frag pack,
    // which sits in [17956864..17957888) -- inside A4l's range but only live
    // before conv4 writes A4l (wrepackm -> conv12 both precede conv4).
    _Float16* P1h = (_Float16*)(ws);               // [128*32*32*32] halves
    _Float16* P1l = (_Float16*)(ws + 2097152);
    _Float16* A3h = (_Float16*)(ws + 4194304);     // [128*32*32*64]
    _Float16* A3l = (_Float16*)(ws + 8388608);
    _Float16* A4h = (_Float16*)(ws + 12582912);    // [128*32*32*64]
    _Float16* A4l = (_Float16*)(ws + 16777216);    // ..20971520
    _Float16* P2h = (_Float16*)(ws);               // [128*16*16*64] (P1 dead)
    _Float16* P2l = (_Float16*)(ws + 1048576);
    _Float16* A5h = (_Float16*)(ws + 4194304);     // [128*16*16*128] (A3 dead)
    _Float16* A5l = (_Float16*)(ws + 6291456);
    float* A6  = ws + 8388608;                     // [128*16*16*128] fp32 (A3 dead)
    float* FP1 = ws + 12582912;                    // [64][128][512] (A4h dead)
    float* H1  = ws + 16777216;                    // [128][512]     (A4l dead)
    float* FP2 = ws + 16842752;                    // [16][128][512]
    float* H2  = ws + 17891328;                    // [128][512]
    _Float16* B1h = (_Float16*)(ws + 17956864);    // 1024 halves (w1 pack)
    _Float16* B1l = (_Float16*)(ws + 17957376);
    _Float16* Bh = (_Float16*)(ws + 20971520);     // 285696 halves (w2..w6)
    _Float16* Bl = (_Float16*)(ws + 21114368);     // ends 21257216 fl = 85 MB

    hipLaunchKernelGGL(k_wrepackm, dim3(1120), dim3(256), 0, stream,
                       w1, w2, w3, w4, w5, w6, Bh, Bl, B1h, B1l);

    // conv1+conv2+pool4: grid = 8x8 tiles x 128 batch
    hipLaunchKernelGGL(k_conv12, dim3(64, 128), dim3(256), 0, stream,
                       img, b1, B1h, B1l, Bh + 0, Bl + 0, b2, P1h, P1l);
    // conv3: M=131072, K=288, COUT=64 (CIN=32 -> BK=32)
    hipLaunchKernelGGL((k_mgemm<32, 64, 32, false, 32>), dim3(1024, 1), dim3(256), 0, stream,
                       P1h, P1l, Bh + 9216, Bl + 9216, b3, A3h, A3l, nullptr);
    // conv4: K=576, BK=64
    hipLaunchKernelGGL((k_mgemm<64, 64, 32, false, 64>), dim3(1024, 1), dim3(256), 0, stream,
                       A3h, A3l, Bh + 27648, Bl + 27648, b4, A4h, A4l, nullptr);
    hipLaunchKernelGGL(k_pool2h, dim3(2048), dim3(256), 0, stream, A4h, A4l, P2h, P2l);
    // conv5: M=32768, K=576, COUT=128, BK=64
    hipLaunchKernelGGL((k_mgemm<64, 128, 16, false, 64>), dim3(256, 2), dim3(256), 0, stream,
                       P2h, P2l, Bh + 64512, Bl + 64512, b5, A5h, A5l, nullptr);
    // conv6: K=1152, fp32 out for FC1, BK=64
    hipLaunchKernelGGL((k_mgemm<128, 128, 16, true, 64>), dim3(256, 2), dim3(256), 0, stream,
                       A5h, A5l, Bh + 138240, Bl + 138240, b6, nullptr, nullptr, A6);
    hipLaunchKernelGGL((k_fc_partial<32768, 512, 4, true>), dim3(8, 64), dim3(256), 0, stream,
                       A6, wl1, FP1);
    hipLaunchKernelGGL(k_fc_reduce<64>, dim3(64), dim3(256), 0, stream, FP1, bl1, H1);
    hipLaunchKernelGGL((k_fc_partial<512, 32, 4, false>), dim3(8, 16), dim3(256), 0, stream,
                       H1, wl2, FP2);
    hipLaunchKernelGGL(k_fc_reduce<16>, dim3(64), dim3(256), 0, stream, FP2, bl2, H2);
    hipLaunchKernelGGL(k_final, dim3(128), dim3(256), 0, stream,
                       H2, wl3, bl3, nois, img, out);
}

// Round 11
// 470.761 us; speedup vs baseline: 1.7834x; 1.1685x over previous
//
#include <hip/hip_runtime.h>
#include <math.h>

typedef _Float16 __attribute__((ext_vector_type(8))) half8_t;
typedef _Float16 __attribute__((ext_vector_type(4))) half4_t;
typedef _Float16 __attribute__((ext_vector_type(2))) half2_t;
typedef float    __attribute__((ext_vector_type(4))) float4_t;

// ---------------------------------------------------------------------------
// Kernel 1: fully-MFMA conv1 + conv2 + maxpool4 (block = 16x16 output tile).
// Phase A: img -> simg (fp32 LDS halo-2) -> im2col into
//   C1h[slot=k/8][pos=18*18][j=k&7] fp16 HI ONLY (R8).
// Phase B: conv1 GEMM transposed: M=32 ch, N=324 pos, K=32, 2-term (wh+wl)*xh.
// Phase C: epilogue -> C1h overwrite, HI ONLY (R10).
// Phase D: conv2 implicit GEMM 2-term (ah*bh + ah*bl) + thread-local 4x4 pool.
// LDS = 6000(simg) + 21504(C1h) = 27.5 KB -> 5 blocks/CU.
// POSP=336 (mult of 8: swizzle bijective, R2); idx per (slot,pos) (R5).
// ---------------------------------------------------------------------------
#define POSP 336

__device__ __forceinline__ int c1idx(int slot, int pos) {
    return ((slot * POSP + pos) * 8) ^ (((pos >> 3) & 7) << 3);
}

__global__ __launch_bounds__(256, 5)
void k_conv12(const float* __restrict__ img, const float* __restrict__ b1,
              const _Float16* __restrict__ B1h, const _Float16* __restrict__ B1l,
              const _Float16* __restrict__ B2h, const _Float16* __restrict__ B2l,
              const float* __restrict__ b2,
              _Float16* __restrict__ P1h, _Float16* __restrict__ P1l)
{
    __shared__ float simg[3 * 20 * 25];                    // input halo-2
    __shared__ __align__(16) _Float16 C1h[4 * POSP * 8];   // A, then conv1 out

    const int t  = threadIdx.x;
    const int bt = blockIdx.x;
    const int b  = blockIdx.y;
    const int ty = bt >> 3, tx = bt & 7;
    const int oy = ty * 16, ox = tx * 16;

    // ---- Phase A1: stage fp32 halo (bounds-checked ONCE, zero-padded) ----
    for (int i = t; i < 1500; i += 256) {
        const int ci = i / 500, r = i - ci * 500;
        const int yy = r / 25, xx = r - yy * 25;
        const int gy = oy - 2 + yy, gx = ox - 2 + xx;
        float v = 0.f;
        if ((unsigned)gy < 128u && (unsigned)gx < 128u)
            v = img[((b * 3 + ci) * 128 + gy) * 128 + gx];
        simg[i] = v;
    }
    __syncthreads();

    // ---- Phase A2: im2col simg -> C1h (hi only; compile-time tap offsets) --
    #pragma unroll
    for (int hf = 0; hf < 2; ++hf) {
        const int pos = hf * 256 + t;
        if (pos < POSP) {
            const bool val = pos < 324;
            int sb = 0;
            if (val) {
                const int py = pos / 18, px = pos - py * 18;
                sb = py * 25 + px;
            }
            #pragma unroll
            for (int s = 0; s < 4; ++s) {
                half8_t vh = {0,0,0,0,0,0,0,0};
                if (val) {
                    #pragma unroll
                    for (int j = 0; j < 8; ++j) {
                        const int k = s * 8 + j;
                        if (k < 27) {
                            const int ci = k / 9, tap = k - ci * 9;   // const
                            const int dy = tap / 3, dx = tap - dy * 3; // const
                            vh[j] = (_Float16)simg[sb + (ci * 20 + dy) * 25 + dx];
                        }
                    }
                }
                *(half8_t*)(&C1h[c1idx(s, pos)]) = vh;
            }
        }
    }
    __syncthreads();

    const int wv   = __builtin_amdgcn_readfirstlane(t >> 6);
    const int lane = t & 63;
    const int fr   = lane >> 4;
    const int ml   = lane & 15;

    // ---- Phase B: conv1 MFMA, transposed, 2-term: D[ch][pos] = w @ xh ----
    half8_t wAh[2], wAl[2];
    #pragma unroll
    for (int mt = 0; mt < 2; ++mt) {
        wAh[mt] = *(const half8_t*)(B1h + (mt * 64 + lane) * 8);
        wAl[mt] = *(const half8_t*)(B1l + (mt * 64 + lane) * 8);
    }
    float4_t acc1[6][2];
    #pragma unroll
    for (int q = 0; q < 6; ++q)
        #pragma unroll
        for (int mt = 0; mt < 2; ++mt)
            acc1[q][mt] = (float4_t){0.f, 0.f, 0.f, 0.f};

    #pragma unroll
    for (int q = 0; q < 6; ++q) {
        const int nt = wv + q * 4;
        if (nt < 21) {
            const int ri = c1idx(fr, nt * 16 + ml);
            const half8_t dh = *(const half8_t*)(&C1h[ri]);
            #pragma unroll
            for (int mt = 0; mt < 2; ++mt) {
                acc1[q][mt] = __builtin_amdgcn_mfma_f32_16x16x32_f16(wAh[mt], dh, acc1[q][mt], 0, 0, 0);
                acc1[q][mt] = __builtin_amdgcn_mfma_f32_16x16x32_f16(wAl[mt], dh, acc1[q][mt], 0, 0, 0);
            }
        }
    }
    __syncthreads();          // all A reads done; buffer reusable

    // ---- Phase C: epilogue -> overwrite C1h (hi only). ----
    const float4_t bA = *(const float4_t*)(b1 + fr * 4);
    const float4_t bB = *(const float4_t*)(b1 + 16 + fr * 4);
    #pragma unroll
    for (int q = 0; q < 6; ++q) {
        const int nt = wv + q * 4;
        if (nt < 21) {
            const int pos = nt * 16 + ml;
            if (pos < 324) {
                const int py = pos / 18, px = pos - py * 18;
                const int gy = oy + py - 1, gx = ox + px - 1;
                const bool ok = (unsigned)gy < 128u && (unsigned)gx < 128u;
                #pragma unroll
                for (int mt = 0; mt < 2; ++mt) {
                    const int slot = mt * 2 + (fr >> 1);
                    const int wi = c1idx(slot, pos) + (fr & 1) * 4;
                    const float4_t bb = mt ? bB : bA;
                    half4_t oh;
                    #pragma unroll
                    for (int r = 0; r < 4; ++r) {
                        const float v = ok ? fmaxf(acc1[q][mt][r] + bb[r], 0.f) : 0.f;
                        oh[r] = (_Float16)v;
                    }
                    *(half4_t*)(&C1h[wi]) = oh;
                }
            }
        }
    }
    __syncthreads();

    // ---- Phase D: conv2 implicit-GEMM 2-term, wave wv owns rows wv*4.. ----
    float4_t acc[4][2];
    #pragma unroll
    for (int i = 0; i < 4; ++i)
        #pragma unroll
        for (int nt = 0; nt < 2; ++nt)
            acc[i][nt] = (float4_t){0.f, 0.f, 0.f, 0.f};

    #pragma unroll 1
    for (int tap = 0; tap < 9; ++tap) {
        const int dy = tap / 3, dx = tap - dy * 3;
        half8_t bh[2], bl[2];
        #pragma unroll
        for (int nt = 0; nt < 2; ++nt) {
            const int bo = ((tap * 2 + nt) * 64 + lane) * 8;
            bh[nt] = *(const half8_t*)(B2h + bo);
            bl[nt] = *(const half8_t*)(B2l + bo);
        }
        half8_t ah[4];
        #pragma unroll
        for (int i = 0; i < 4; ++i) {
            const int pos = (wv * 4 + i + dy) * 18 + ml + dx;
            ah[i] = *(const half8_t*)(&C1h[c1idx(fr, pos)]);
        }
        #pragma unroll
        for (int nt = 0; nt < 2; ++nt)
            #pragma unroll
            for (int i = 0; i < 4; ++i)
                acc[i][nt] = __builtin_amdgcn_mfma_f32_16x16x32_f16(ah[i], bh[nt], acc[i][nt], 0, 0, 0);
        #pragma unroll
        for (int nt = 0; nt < 2; ++nt)
            #pragma unroll
            for (int i = 0; i < 4; ++i)
                acc[i][nt] = __builtin_amdgcn_mfma_f32_16x16x32_f16(ah[i], bl[nt], acc[i][nt], 0, 0, 0);
    }

    // ---- maxpool4 (thread-local) + bias + relu + hi/lo store ----
    const int py = ty * 4 + wv;
    const int px = tx * 4 + fr;
    #pragma unroll
    for (int nt = 0; nt < 2; ++nt) {
        float m = -1e30f;
        #pragma unroll
        for (int i = 0; i < 4; ++i)
            #pragma unroll
            for (int r = 0; r < 4; ++r)
                m = fmaxf(m, acc[i][nt][r]);
        const int oc = nt * 16 + ml;
        const float v = fmaxf(m + b2[oc], 0.f);
        const _Float16 h = (_Float16)v;
        const int base = ((b * 32 + py) * 32 + px) * 32 + oc;
        P1h[base] = h;
        P1l[base] = (_Float16)(v - (float)h);
    }
}

// ---------------------------------------------------------------------------
// Weight repack: fp16 hi/lo MFMA-fragment packs for w2..w6 (+ w1, K padded
// 27->32). Frag order: Bh[((c*NT + ntg)*64 + lane)*8 + j], element B[k][n]:
//   n = ntg*16 + (lane&15), k = c*32 + (lane>>4)*8 + j.
// ---------------------------------------------------------------------------
__global__ void k_wrepackm(const float* __restrict__ w1, const float* __restrict__ w2,
                           const float* __restrict__ w3, const float* __restrict__ w4,
                           const float* __restrict__ w5, const float* __restrict__ w6,
                           _Float16* __restrict__ Bh, _Float16* __restrict__ Bl,
                           _Float16* __restrict__ B1h, _Float16* __restrict__ B1l)
{
    int idx = blockIdx.x * 256 + threadIdx.x;
    if (idx >= 285696) {
        const int i = idx - 285696;
        if (i >= 1024) return;
        const int ntg = i >> 9, rr = i & 511;
        const int lane = rr >> 3, j = rr & 7;
        const int k = (lane >> 4) * 8 + j;
        const int n = ntg * 16 + (lane & 15);
        const float v = (k < 27) ? w1[n * 27 + k] : 0.f;
        const _Float16 h = (_Float16)v;
        B1h[i] = h;
        B1l[i] = (_Float16)(v - (float)h);
        return;
    }
    const float* w; int CIN, COUT, off;
    if (idx < 9216)        { w = w2; CIN = 32;  COUT = 32;  off = 0; }
    else if (idx < 27648)  { idx -= 9216;   w = w3; CIN = 32;  COUT = 64;  off = 9216; }
    else if (idx < 64512)  { idx -= 27648;  w = w4; CIN = 64;  COUT = 64;  off = 27648; }
    else if (idx < 138240) { idx -= 64512;  w = w5; CIN = 64;  COUT = 128; off = 64512; }
    else                   { idx -= 138240; w = w6; CIN = 128; COUT = 128; off = 138240; }
    const int NT  = COUT / 16;
    const int c   = idx / (NT * 512);
    const int r   = idx - c * NT * 512;
    const int ntg = r >> 9;
    const int rr  = r & 511;
    const int lane = rr >> 3, j = rr & 7;
    const int k   = c * 32 + (lane >> 4) * 8 + j;
    const int tap = k / CIN, ci = k - tap * CIN;
    const int oc  = ntg * 16 + (lane & 15);
    const float v = w[(oc * CIN + ci) * 9 + tap];
    const _Float16 h = (_Float16)v;
    Bh[off + idx] = h;
    Bl[off + idx] = (_Float16)(v - (float)h);
}

// ---------------------------------------------------------------------------
// MFMA implicit-GEMM conv3x3. BM=128, BN=64; 4 waves = 2 m-tiles x 4 n-tiles.
// BK=64 for CIN>=64 (two 32-k chunks per barrier pair). conv3 BK=32.
// ---------------------------------------------------------------------------
template<int CIN, int COUT, int HW, bool OUTF32, int BK>
__global__ __launch_bounds__(256, 2)
void k_mgemm(const _Float16* __restrict__ inh, const _Float16* __restrict__ inl,
             const _Float16* __restrict__ Bh, const _Float16* __restrict__ Bl,
             const float* __restrict__ bias,
             _Float16* __restrict__ outh, _Float16* __restrict__ outl,
             float* __restrict__ outf)
{
    constexpr int NCH = CIN * 9 / BK;
    constexpr int SUB = BK / 32;
    constexpr int NT  = COUT / 16;
    constexpr int LOG = (HW == 32) ? 5 : 4;
    constexpr int PS  = BK + ((BK == 64) ? 4 : 8);
    constexpr int NJ  = BK / 16;          // staging iterations
    constexpr int GPR = BK / 8;           // half8 groups per row
    __shared__ _Float16 Ash[128 * PS];
    __shared__ _Float16 Asl[128 * PS];

    const int t    = threadIdx.x;
    const int wv   = t >> 6;
    const int lane = t & 63;
    const int m0   = blockIdx.x * 128;
    const int nb   = blockIdx.y;

    int sm[NJ], sg[NJ], sb[NJ], sy[NJ], sx[NJ];
    #pragma unroll
    for (int j = 0; j < NJ; ++j) {
        const int q = t + 256 * j;
        sm[j] = q / GPR;
        sg[j] = q - sm[j] * GPR;
        const int m  = m0 + sm[j];
        const int yx = m & (HW * HW - 1);
        sb[j] = m >> (2 * LOG);
        sy[j] = yx >> LOG;
        sx[j] = yx & (HW - 1);
    }

    const int mt0 = wv * 2;
    const int fr  = lane >> 4;
    const int ml  = lane & 15;

    float4_t acc[2][4];
    #pragma unroll
    for (int mt = 0; mt < 2; ++mt)
        #pragma unroll
        for (int tn = 0; tn < 4; ++tn)
            acc[mt][tn] = (float4_t){0.f, 0.f, 0.f, 0.f};

    #pragma unroll 1
    for (int ch = 0; ch < NCH; ++ch) {
        const int kb  = ch * BK;
        const int tap = kb / CIN;
        const int c0  = kb - tap * CIN;
        const int dy  = tap / 3 - 1, dx = tap - (tap / 3) * 3 - 1;

        if (ch) __syncthreads();
        #pragma unroll
        for (int j = 0; j < NJ; ++j) {
            const int iy = sy[j] + dy, ix = sx[j] + dx;
            half8_t vh = {0, 0, 0, 0, 0, 0, 0, 0};
            half8_t vl = {0, 0, 0, 0, 0, 0, 0, 0};
            if ((unsigned)iy < (unsigned)HW && (unsigned)ix < (unsigned)HW) {
                const int o = ((sb[j] * HW + iy) * HW + ix) * CIN + c0 + sg[j] * 8;
                vh = *(const half8_t*)(inh + o);
                vl = *(const half8_t*)(inl + o);
            }
            *(half8_t*)(&Ash[sm[j] * PS + sg[j] * 8]) = vh;
            *(half8_t*)(&Asl[sm[j] * PS + sg[j] * 8]) = vl;
        }
        __syncthreads();

        #pragma unroll
        for (int ss = 0; ss < SUB; ++ss) {
            half8_t ah[2], al[2];
            #pragma unroll
            for (int mt = 0; mt < 2; ++mt) {
                const int mr = (mt0 + mt) * 16 + ml;
                ah[mt] = *(const half8_t*)(&Ash[mr * PS + ss * 32 + fr * 8]);
                al[mt] = *(const half8_t*)(&Asl[mr * PS + ss * 32 + fr * 8]);
            }
            half8_t bh[4], bl[4];
            #pragma unroll
            for (int tn = 0; tn < 4; ++tn) {
                const int bo = (((ch * SUB + ss) * NT + nb * 4 + tn) * 64 + lane) * 8;
                bh[tn] = *(const half8_t*)(Bh + bo);
                bl[tn] = *(const half8_t*)(Bl + bo);
            }
            #pragma unroll
            for (int tn = 0; tn < 4; ++tn)
                #pragma unroll
                for (int mt = 0; mt < 2; ++mt)
                    acc[mt][tn] = __builtin_amdgcn_mfma_f32_16x16x32_f16(ah[mt], bh[tn], acc[mt][tn], 0, 0, 0);
            #pragma unroll
            for (int tn = 0; tn < 4; ++tn)
                #pragma unroll
                for (int mt = 0; mt < 2; ++mt)
                    acc[mt][tn] = __builtin_amdgcn_mfma_f32_16x16x32_f16(al[mt], bh[tn], acc[mt][tn], 0, 0, 0);
            #pragma unroll
            for (int tn = 0; tn < 4; ++tn)
                #pragma unroll
                for (int mt = 0; mt < 2; ++mt)
                    acc[mt][tn] = __builtin_amdgcn_mfma_f32_16x16x32_f16(ah[mt], bl[tn], acc[mt][tn], 0, 0, 0);
            // (al,bl) term dropped: <= 2^-22 relative contribution.
        }
    }

    // epilogue: C/D frag col=lane&15, row=(lane>>4)*4+reg  [guide m89/m91]
    #pragma unroll
    for (int mt = 0; mt < 2; ++mt)
        #pragma unroll
        for (int tn = 0; tn < 4; ++tn) {
            const int oc = nb * 64 + tn * 16 + ml;
            const float bv = bias[oc];
            #pragma unroll
            for (int r = 0; r < 4; ++r) {
                const int m = m0 + (mt0 + mt) * 16 + fr * 4 + r;
                const float v = fmaxf(acc[mt][tn][r] + bv, 0.f);
                if (OUTF32) {
                    outf[m * COUT + oc] = v;
                } else {
                    const _Float16 h = (_Float16)v;
                    outh[m * COUT + oc] = h;
                    outl[m * COUT + oc] = (_Float16)(v - (float)h);
                }
            }
        }
}

// ---------------------------------------------------------------------------
// MFMA FC1 (R11): H1-partials = A[128 x 32768] @ wl1[32768 x 512], split-K.
// Grid (8 n-blocks, 64 k-chunks); block: BM=128(all batch), BN=64, KCHUNK=512
// in 8 BK=64 stages. A from fp16 hi/lo A6 planes (k = yx*128+c order ->
// contiguous c runs). W read fp32 DIRECTLY from wl1 (perm kref = c*256+yx
// folded into row address; each element read once), converted to fp16 hi/lo
// and transposed into LDS [n][68]. 3-term split = fp32-class. Partials fp32.
// ---------------------------------------------------------------------------
__global__ __launch_bounds__(256, 2)
void k_fc1m(const _Float16* __restrict__ A6h, const _Float16* __restrict__ A6l,
            const float* __restrict__ wl1, float* __restrict__ part)
{
    __shared__ __align__(16) _Float16 Ah[128 * 68];
    __shared__ __align__(16) _Float16 Al[128 * 68];
    __shared__ __align__(16) _Float16 Wh[64 * 68];
    __shared__ __align__(16) _Float16 Wl[64 * 68];

    const int t    = threadIdx.x;
    const int wv   = t >> 6;
    const int lane = t & 63;
    const int fr   = lane >> 4;
    const int ml   = lane & 15;
    const int n0   = blockIdx.x * 64;
    const int kc   = blockIdx.y;

    float4_t acc[2][4];
    #pragma unroll
    for (int mt = 0; mt < 2; ++mt)
        #pragma unroll
        for (int tn = 0; tn < 4; ++tn)
            acc[mt][tn] = (float4_t){0.f, 0.f, 0.f, 0.f};

    #pragma unroll 1
    for (int it = 0; it < 8; ++it) {
        const int kb = kc * 512 + it * 64;
        const int yx = kb >> 7;           // 64-k window never crosses yx
        const int c0 = kb & 127;

        if (it) __syncthreads();
        // stage A [128 b][64 k] hi/lo (coalesced 128B runs per b)
        #pragma unroll
        for (int q = 0; q < 4; ++q) {
            const int lin = q * 256 + t;
            const int bb = lin >> 3, g = lin & 7;
            const int src = (bb * 256 + yx) * 128 + c0 + g * 8;
            *(half8_t*)(&Ah[bb * 68 + g * 8]) = *(const half8_t*)(A6h + src);
            *(half8_t*)(&Al[bb * 68 + g * 8]) = *(const half8_t*)(A6l + src);
        }
        // stage W: wl1 row kref=(c0+kk)*256+yx, 64 n fp32 -> hi/lo [n][68]
        {
            const int kk = t >> 2;
            const float* wrow = wl1 + ((c0 + kk) * 256 + yx) * 512 + n0;
            #pragma unroll
            for (int q = 0; q < 4; ++q) {
                const int nq = (t & 3) + q * 4;
                const float4 v = *(const float4*)(wrow + nq * 4);
                #pragma unroll
                for (int e = 0; e < 4; ++e) {
                    const int n = nq * 4 + e;
                    const float w = (&v.x)[e];
                    const _Float16 h = (_Float16)w;
                    Wh[n * 68 + kk] = h;
                    Wl[n * 68 + kk] = (_Float16)(w - (float)h);
                }
            }
        }
        __syncthreads();

        #pragma unroll
        for (int ss = 0; ss < 2; ++ss) {
            half8_t ah[2], al[2];
            #pragma unroll
            for (int mt = 0; mt < 2; ++mt) {
                const int bb = (wv * 2 + mt) * 16 + ml;
                ah[mt] = *(const half8_t*)(&Ah[bb * 68 + ss * 32 + fr * 8]);
                al[mt] = *(const half8_t*)(&Al[bb * 68 + ss * 32 + fr * 8]);
            }
            half8_t bh[4], bl[4];
            #pragma unroll
            for (int tn = 0; tn < 4; ++tn) {
                const int nn = tn * 16 + ml;
                bh[tn] = *(const half8_t*)(&Wh[nn * 68 + ss * 32 + fr * 8]);
                bl[tn] = *(const half8_t*)(&Wl[nn * 68 + ss * 32 + fr * 8]);
            }
            #pragma unroll
            for (int tn = 0; tn < 4; ++tn)
                #pragma unroll
                for (int mt = 0; mt < 2; ++mt)
                    acc[mt][tn] = __builtin_amdgcn_mfma_f32_16x16x32_f16(ah[mt], bh[tn], acc[mt][tn], 0, 0, 0);
            #pragma unroll
            for (int tn = 0; tn < 4; ++tn)
                #pragma unroll
                for (int mt = 0; mt < 2; ++mt)
                    acc[mt][tn] = __builtin_amdgcn_mfma_f32_16x16x32_f16(al[mt], bh[tn], acc[mt][tn], 0, 0, 0);
            #pragma unroll
            for (int tn = 0; tn < 4; ++tn)
                #pragma unroll
                for (int mt = 0; mt < 2; ++mt)
                    acc[mt][tn] = __builtin_amdgcn_mfma_f32_16x16x32_f16(ah[mt], bl[tn], acc[mt][tn], 0, 0, 0);
        }
    }

    // partials (no bias/relu -- reduce applies them)
    const long pb = (long)kc * 65536;
    #pragma unroll
    for (int mt = 0; mt < 2; ++mt)
        #pragma unroll
        for (int tn = 0; tn < 4; ++tn) {
            const int nn = n0 + tn * 16 + ml;
            #pragma unroll
            for (int r = 0; r < 4; ++r) {
                const int m = (wv * 2 + mt) * 16 + fr * 4 + r;
                part[pb + m * 512 + nn] = acc[mt][tn][r];
            }
        }
}

// ---------------------------------------------------------------------------
// 2x2 maxpool on dual fp16 planes, NHWC [128][32][32][64] -> [128][16][16][64]
// ---------------------------------------------------------------------------
__global__ __launch_bounds__(256)
void k_pool2h(const _Float16* __restrict__ inh, const _Float16* __restrict__ inl,
              _Float16* __restrict__ outh, _Float16* __restrict__ outl)
{
    const int g = blockIdx.x * 256 + threadIdx.x;
    const int c4 = g & 15, xo = (g >> 4) & 15, yo = (g >> 8) & 15, b = g >> 12;
    const int base = ((b * 32 + yo * 2) * 32 + xo * 2) * 64 + c4 * 4;
    const int offs[4] = {0, 64, 2048, 2112};
    float mx[4] = {-1e30f, -1e30f, -1e30f, -1e30f};
    #pragma unroll
    for (int cnd = 0; cnd < 4; ++cnd) {
        const half4_t h = *(const half4_t*)(inh + base + offs[cnd]);
        const half4_t l = *(const half4_t*)(inl + base + offs[cnd]);
        #pragma unroll
        for (int e = 0; e < 4; ++e)
            mx[e] = fmaxf(mx[e], (float)h[e] + (float)l[e]);
    }
    half4_t oh, ol;
    #pragma unroll
    for (int e = 0; e < 4; ++e) {
        const _Float16 h = (_Float16)mx[e];
        oh[e] = h;
        ol[e] = (_Float16)(mx[e] - (float)h);
    }
    const int ob = ((b * 16 + yo) * 16 + xo) * 64 + c4 * 4;
    *(half4_t*)(outh + ob) = oh;
    *(half4_t*)(outl + ob) = ol;
}

// ---------------------------------------------------------------------------
// Split-K FC partial (fp32): A[128 x K] @ B[K x 512] -> part[ky][128][512]
// (now used for FC2 only)
// ---------------------------------------------------------------------------
template<int LDA, int KCHUNK, int TN, bool PERM>
__global__ __launch_bounds__(256, 2)
void k_fc_partial(const float* __restrict__ A, const float* __restrict__ Bw,
                  float* __restrict__ part)
{
    constexpr int BN = 16 * TN;
    constexpr int SA = 140;
    constexpr int SB = (BN == 128) ? 140 : 68;
    __shared__ __align__(16) float As[32 * SA];
    __shared__ __align__(16) float Bs[32 * SB];
    const int t  = threadIdx.x;
    const int tm = t >> 4, tn = t & 15;
    const int n0 = blockIdx.x * BN;
    const int k0 = blockIdx.y * KCHUNK;

    float acc[8][TN];
    #pragma unroll
    for (int r = 0; r < 8; ++r)
        #pragma unroll
        for (int c = 0; c < TN; ++c) acc[r][c] = 0.f;

    #pragma unroll 1
    for (int ks = 0; ks < KCHUNK / 32; ++ks) {
        if (ks) __syncthreads();
        const int kb = k0 + ks * 32;
        for (int i = t; i < 4096; i += 256) {
            const int m = i >> 5, kk = i & 31;
            As[kk * SA + m + ((m >> 5) << 2)] = A[m * LDA + kb + kk];
        }
        for (int i = t; i < 32 * BN; i += 256) {
            const int kk = i / BN, n = i - kk * BN;
            const int krow = kb + kk;
            const int kref = PERM ? ((krow & 127) * 256 + (krow >> 7)) : krow;
            Bs[kk * SB + n + ((n >> 5) << 2)] = Bw[kref * 512 + n0 + n];
        }
        __syncthreads();
        #pragma unroll 2
        for (int kk = 0; kk < 32; ++kk) {
            const float* ap = &As[kk * SA + tm * 8 + ((tm >> 2) << 2)];
            const float* bp = &Bs[kk * SB + tn * TN + (((tn * TN) >> 5) << 2)];
            float a[8], bb[TN];
            #pragma unroll
            for (int q = 0; q < 8; q += 4) {
                const float4 v = *(const float4*)(ap + q);
                a[q] = v.x; a[q + 1] = v.y; a[q + 2] = v.z; a[q + 3] = v.w;
            }
            #pragma unroll
            for (int q = 0; q < TN; q += 4) {
                const float4 v = *(const float4*)(bp + q);
                bb[q] = v.x; bb[q + 1] = v.y; bb[q + 2] = v.z; bb[q + 3] = v.w;
            }
            #pragma unroll
            for (int r = 0; r < 8; ++r)
                #pragma unroll
                for (int c = 0; c < TN; ++c)
                    acc[r][c] = fmaf(a[r], bb[c], acc[r][c]);
        }
    }

    const long pb = (long)blockIdx.y * 65536;
    #pragma unroll
    for (int r = 0; r < 8; ++r)
        #pragma unroll
        for (int c = 0; c < TN; ++c)
            part[pb + (tm * 8 + r) * 512 + n0 + tn * TN + c] = acc[r][c];
}

template<int NS>
__global__ __launch_bounds__(256)
void k_fc_reduce(const float* __restrict__ part, const float* __restrict__ bias,
                 float* __restrict__ H)
{
    const int f = (blockIdx.x * 256 + threadIdx.x) * 4;
    const int m = f >> 9, n = f & 511;
    float s0 = 0.f, s1 = 0.f, s2 = 0.f, s3 = 0.f;
    #pragma unroll 4
    for (int q = 0; q < NS; ++q) {
        const float* p = &part[(q * 128 + m) * 512 + n];
        s0 += p[0]; s1 += p[1]; s2 += p[2]; s3 += p[3];
    }
    H[f]     = fmaxf(s0 + bias[n],     0.f);
    H[f + 1] = fmaxf(s1 + bias[n + 1], 0.f);
    H[f + 2] = fmaxf(s2 + bias[n + 2], 0.f);
    H[f + 3] = fmaxf(s3 + bias[n + 3], 0.f);
}

// ---------------------------------------------------------------------------
// Final: FC3 + sampling + patch gather
// ---------------------------------------------------------------------------
__device__ __forceinline__ float softplusf(float x) {
    return (x > 20.f) ? x : log1pf(expf(x));
}
__device__ __forceinline__ float sigmoidf_(float x) {
    return 1.f / (1.f + expf(-x));
}

__global__ __launch_bounds__(256)
void k_final(const float* __restrict__ H2, const float* __restrict__ wl3,
             const float* __restrict__ bl3, const float* __restrict__ noise,
             const float* __restrict__ img, float* __restrict__ outp)
{
    __shared__ float h2[512];
    __shared__ float red[144];
    __shared__ float prep[36];
    __shared__ int ptsh[12], ptsw[12];
    const int b = blockIdx.x, t = threadIdx.x;

    h2[t]       = H2[b * 512 + t];
    h2[t + 256] = H2[b * 512 + 256 + t];
    __syncthreads();

    if (t < 144) {
        const int n = t >> 2, q = t & 3;
        float s = 0.f;
        for (int k = q * 128; k < q * 128 + 128; ++k)
            s = fmaf(h2[k], wl3[k * 36 + n], s);
        red[t] = s;
    }
    __syncthreads();
    if (t < 36)
        prep[t] = red[t * 4] + red[t * 4 + 1] + red[t * 4 + 2] + red[t * 4 + 3] + bl3[t];
    __syncthreads();

    if (t < 12) {
        const float m0 = prep[t * 3], m1 = prep[t * 3 + 1], sv = prep[t * 3 + 2];
        const float sig = softplusf(sv + 2.0f) * 128.f + 1e-7f;
        const float n0 = noise[(b * 12 + t) * 2], n1 = noise[(b * 12 + t) * 2 + 1];
        const float sa0 = m0 + sig * n0;
        const float sa1 = m1 + sig * n1;
        int p0 = (int)rintf(sigmoidf_(sa0) * 111.f);
        int p1 = (int)rintf(sigmoidf_(sa1) * 111.f);
        p0 = min(max(p0, 0), 111);
        p1 = min(max(p1, 0), 111);
        const int RM = 1179648;
        outp[RM        + (b * 12 + t) * 2 + 0] = m0;
        outp[RM        + (b * 12 + t) * 2 + 1] = m1;
        outp[RM + 3072 + (b * 12 + t) * 2 + 0] = sig;
        outp[RM + 3072 + (b * 12 + t) * 2 + 1] = sig;
        outp[RM + 6144 + (b * 12 + t) * 2 + 0] = sa0;
        outp[RM + 6144 + (b * 12 + t) * 2 + 1] = sa1;
        ptsh[t] = p0;
        ptsw[t] = p1;
    }
    __syncthreads();

    for (int i = t; i < 9216; i += 256) {
        const int g  = i / 768, r = i - g * 768;
        const int c  = r >> 8, r2 = r & 255;
        const int y  = r2 >> 4, x = r2 & 15;
        outp[b * 9216 + i] = img[((b * 3 + c) * 128 + ptsh[g] + y) * 128 + (ptsw[g] + x)];
    }
}

// ---------------------------------------------------------------------------
extern "C" void kernel_launch(void* const* d_in, const int* in_sizes, int n_in,
                              void* d_out, int out_size, void* d_ws, size_t ws_size,
                              hipStream_t stream)
{
    const float* img  = (const float*)d_in[0];
    const float* nois = (const float*)d_in[1];
    const float* w1 = (const float*)d_in[2];  const float* b1 = (const float*)d_in[3];
    const float* w2 = (const float*)d_in[4];  const float* b2 = (const float*)d_in[5];
    const float* w3 = (const float*)d_in[6];  const float* b3 = (const float*)d_in[7];
    const float* w4 = (const float*)d_in[8];  const float* b4 = (const float*)d_in[9];
    const float* w5 = (const float*)d_in[10]; const float* b5 = (const float*)d_in[11];
    const float* w6 = (const float*)d_in[12]; const float* b6 = (const float*)d_in[13];
    const float* wl1 = (const float*)d_in[14]; const float* bl1 = (const float*)d_in[15];
    const float* wl2 = (const float*)d_in[16]; const float* bl2 = (const float*)d_in[17];
    const float* wl3 = (const float*)d_in[18]; const float* bl3 = (const float*)d_in[19];
    float* out = (float*)d_out;
    float* ws  = (float*)d_ws;

    // workspace (float units). Activation regions span [0 .. 20971520).
    _Float16* P1h = (_Float16*)(ws);               // [128*32*32*32] halves
    _Float16* P1l = (_Float16*)(ws + 2097152);
    _Float16* A3h = (_Float16*)(ws + 4194304);     // [128*32*32*64]
    _Float16* A3l = (_Float16*)(ws + 8388608);
    _Float16* A4h = (_Float16*)(ws + 12582912);    // [128*32*32*64]
    _Float16* A4l = (_Float16*)(ws + 16777216);    // ..20971520
    _Float16* P2h = (_Float16*)(ws);               // [128*16*16*64] (P1 dead)
    _Float16* P2l = (_Float16*)(ws + 1048576);
    _Float16* A5h = (_Float16*)(ws + 4194304);     // [128*16*16*128] (A3 dead)
    _Float16* A5l = (_Float16*)(ws + 6291456);
    _Float16* A6h = (_Float16*)(ws + 8388608);     // [32768*128] halves (R11)
    _Float16* A6l = (_Float16*)(ws + 10485760);
    float* FP1 = ws + 12582912;                    // [64][128][512] (A4h dead)
    float* H1  = ws + 16777216;                    // [128][512]     (A4l dead)
    float* FP2 = ws + 16842752;                    // [16][128][512]
    float* H2  = ws + 17891328;                    // [128][512]
    _Float16* B1h = (_Float16*)(ws + 17956864);    // 1024 halves (w1 pack)
    _Float16* B1l = (_Float16*)(ws + 17957376);
    _Float16* Bh = (_Float16*)(ws + 20971520);     // 285696 halves (w2..w6)
    _Float16* Bl = (_Float16*)(ws + 21114368);     // ends 21257216 fl = 85 MB

    hipLaunchKernelGGL(k_wrepackm, dim3(1120), dim3(256), 0, stream,
                       w1, w2, w3, w4, w5, w6, Bh, Bl, B1h, B1l);

    // conv1+conv2+pool4: grid = 8x8 tiles x 128 batch
    hipLaunchKernelGGL(k_conv12, dim3(64, 128), dim3(256), 0, stream,
                       img, b1, B1h, B1l, Bh + 0, Bl + 0, b2, P1h, P1l);
    // conv3: M=131072, K=288, COUT=64 (CIN=32 -> BK=32)
    hipLaunchKernelGGL((k_mgemm<32, 64, 32, false, 32>), dim3(1024, 1), dim3(256), 0, stream,
                       P1h, P1l, Bh + 9216, Bl + 9216, b3, A3h, A3l, nullptr);
    // conv4: K=576, BK=64
    hipLaunchKernelGGL((k_mgemm<64, 64, 32, false, 64>), dim3(1024, 1), dim3(256), 0, stream,
                       A3h, A3l, Bh + 27648, Bl + 27648, b4, A4h, A4l, nullptr);
    hipLaunchKernelGGL(k_pool2h, dim3(2048), dim3(256), 0, stream, A4h, A4l, P2h, P2l);
    // conv5: M=32768, K=576, COUT=128, BK=64
    hipLaunchKernelGGL((k_mgemm<64, 128, 16, false, 64>), dim3(256, 2), dim3(256), 0, stream,
                       P2h, P2l, Bh + 64512, Bl + 64512, b5, A5h, A5l, nullptr);
    // conv6: K=1152, fp16 hi/lo out for MFMA FC1 (R11), BK=64
    hipLaunchKernelGGL((k_mgemm<128, 128, 16, false, 64>), dim3(256, 2), dim3(256), 0, stream,
                       A5h, A5l, Bh + 138240, Bl + 138240, b6, A6h, A6l, nullptr);
    // FC1 on MFMA: grid (8 n-blocks, 64 k-chunks)
    hipLaunchKernelGGL(k_fc1m, dim3(8, 64), dim3(256), 0, stream,
                       A6h, A6l, wl1, FP1);
    hipLaunchKernelGGL(k_fc_reduce<64>, dim3(64), dim3(256), 0, stream, FP1, bl1, H1);
    hipLaunchKernelGGL((k_fc_partial<512, 32, 4, false>), dim3(8, 16), dim3(256), 0, stream,
                       H1, wl2, FP2);
    hipLaunchKernelGGL(k_fc_reduce<16>, dim3(64), dim3(256), 0, stream, FP2, bl2, H2);
    hipLaunchKernelGGL(k_final, dim3(128), dim3(256), 0, stream,
                       H2, wl3, bl3, nois, img, out);
}